// Round 14
// baseline (235.535 us; speedup 1.0000x reference)
//
#include <hip/hip_runtime.h>
#include <math.h>

#define BN_ 2
#define NN 1024
#define DDIM 256
#define HH 8
#define HDIM 32
#define FFD 1024
#define EPSV 1e-5f
#define SCALEV 0.17677669529663687f

typedef __attribute__((ext_vector_type(8))) short s16x8;
typedef __attribute__((ext_vector_type(4))) short s16x4;
typedef __attribute__((ext_vector_type(4))) float f32x4;
typedef __attribute__((ext_vector_type(2))) _Float16 h2;
typedef __attribute__((ext_vector_type(8))) _Float16 f16x8;

__device__ __forceinline__ float gelu_f(float x){
  return 0.5f*x*(1.0f+erff(x*0.70710678118654752f));
}
__device__ __forceinline__ unsigned int pack_bf16(float lo, float hi){
  unsigned int ul = __float_as_uint(lo), uh = __float_as_uint(hi);
  ul += 0x7fff + ((ul>>16)&1);
  uh += 0x7fff + ((uh>>16)&1);
  return (ul>>16) | (uh & 0xffff0000u);
}
__device__ __forceinline__ unsigned short f2bf(float x){
  unsigned int u = __float_as_uint(x);
  u += 0x7fff + ((u>>16)&1);
  return (unsigned short)(u>>16);
}
__device__ __forceinline__ float bf2f(unsigned short u){
  return __uint_as_float(((unsigned int)u)<<16);
}
__device__ __forceinline__ unsigned int packtr(float lo, float hi){
  return __builtin_amdgcn_perm(__float_as_uint(hi), __float_as_uint(lo), 0x07060302u);
}
__device__ __forceinline__ f32x4 mfma16(s16x8 a, s16x8 b, f32x4 c){
  return __builtin_amdgcn_mfma_f32_16x16x32_bf16(a,b,c,0,0,0);
}
__device__ __forceinline__ f32x4 mfma16h(f16x8 a, f16x8 b, f32x4 c){
  return __builtin_amdgcn_mfma_f32_16x16x32_f16(a,b,c,0,0,0);
}

// ---------------- LayerNorm: f32 in, bf16 out --------------------------------
__global__ __launch_bounds__(256) void ln_kernel(const float* __restrict__ x,
    const float* __restrict__ g, const float* __restrict__ b,
    unsigned short* __restrict__ out){
  int row = blockIdx.x, tid = threadIdx.x;
  float val = x[(size_t)row*DDIM + tid];
  float s = val;
  #pragma unroll
  for (int o=32;o;o>>=1) s += __shfl_xor(s,o);
  __shared__ float sb[4], sb2[4];
  if ((tid&63)==0) sb[tid>>6]=s;
  __syncthreads();
  float mean = (sb[0]+sb[1]+sb[2]+sb[3]) * (1.0f/DDIM);
  float d = val-mean;
  float vs = d*d;
  #pragma unroll
  for (int o=32;o;o>>=1) vs += __shfl_xor(vs,o);
  if ((tid&63)==0) sb2[tid>>6]=vs;
  __syncthreads();
  float var = (sb2[0]+sb2[1]+sb2[2]+sb2[3]) * (1.0f/DDIM);
  out[(size_t)row*DDIM + tid] = f2bf(d*rsqrtf(var+EPSV)*g[tid]+b[tid]);
}

// ---------------- RoPE tables -------------------------------------------------
__global__ __launch_bounds__(256) void rope_table(float* __restrict__ sint, float* __restrict__ cost){
  int idx = blockIdx.x*256+threadIdx.x;   // 16384
  int i = idx >> 4, d = idx & 15;
  float freq = (float)i * powf(10000.0f, -(float)d/16.0f);
  sint[idx]=sinf(freq); cost[idx]=cosf(freq);
}

// ---------------- weight convert+transpose f32(K,NC) -> bf16 WT(NC,K) --------
__global__ __launch_bounds__(256) void wt_convert(const float* __restrict__ in,
    unsigned short* __restrict__ out, int K, int NC, int scaleCols, float scaleVal){
  __shared__ float tile[32][33];
  int tn0 = blockIdx.x*32;
  int tk0 = blockIdx.y*32;
  size_t loff = (size_t)blockIdx.z * K * NC;
  int t = threadIdx.x;
  int col = t & 31, rr = t >> 5;
  #pragma unroll
  for (int i=0;i<4;++i){
    int row = rr + i*8;
    tile[row][col] = in[loff + (size_t)(tk0+row)*NC + tn0+col];
  }
  __syncthreads();
  #pragma unroll
  for (int i=0;i<4;++i){
    int row = rr + i*8;
    int n = tn0 + row;
    float s = (n < scaleCols) ? scaleVal : 1.0f;
    out[loff + (size_t)n*K + tk0 + col] = f2bf(tile[col][row]*s);
  }
}

// ------------- split qkv + rope (bf16 in/out) --------------------------------
__global__ __launch_bounds__(256) void rope_apply_bf(const unsigned short* __restrict__ qkv,
    const float* __restrict__ sint, const float* __restrict__ cost,
    unsigned short* __restrict__ q, unsigned short* __restrict__ k,
    unsigned short* __restrict__ v){
  int row = blockIdx.x;                 // b*1024 + i
  int b = row>>10, i = row&1023;
  int tid = threadIdx.x; int h = tid>>5, d = tid&31;
  const unsigned short* base = qkv + (size_t)row*768;
  size_t oidx = (((size_t)((b<<3)+h)<<10) + i)*32 + d;
  v[oidx] = base[512 + h*32 + d];
  int dd = (d<16) ? d : d-16;
  float s = sint[i*16+dd], c = cost[i*16+dd];
  float q1 = bf2f(base[h*32+dd]), q2 = bf2f(base[h*32+dd+16]);
  q[oidx] = f2bf((d<16) ? (q1*c - q2*s) : (q2*c + q1*s));
  float k1 = bf2f(base[256+h*32+dd]), k2 = bf2f(base[256+h*32+dd+16]);
  k[oidx] = f2bf((d<16) ? (k1*c - k2*s) : (k2*c + k1*s));
}

// ------------- V transpose: v[bh][j][d] -> vt[bh][d][j] ----------------------
__global__ __launch_bounds__(256) void v_transpose(const unsigned short* __restrict__ v,
    unsigned short* __restrict__ vt){
  __shared__ unsigned short t[64][34];
  int bh = blockIdx.x >> 4;
  int j0 = (blockIdx.x & 15) << 6;
  int tid = threadIdx.x;
  const unsigned short* vb = v + ((size_t)bh<<15) + (size_t)j0*32;
  {
    int j = tid >> 2, dg = (tid & 3) * 8;
    s16x8 r = *(const s16x8*)(vb + (size_t)j*32 + dg);
    #pragma unroll
    for (int e=0;e<8;++e) t[j][dg+e] = (unsigned short)r[e];
  }
  __syncthreads();
  {
    int d = tid >> 3, jg = (tid & 7) * 8;
    s16x8 r;
    #pragma unroll
    for (int e=0;e<8;++e) r[e] = (short)t[jg+e][d];
    *(s16x8*)(vt + (((size_t)bh*32 + d)<<10) + j0 + jg) = r;
  }
}

// ------------- rel precompute: per-node separable parts (fp16) + W2T (f16) ---
__global__ __launch_bounds__(256) void rel_pre(const float* __restrict__ coords,
    const float* __restrict__ vel, const float* __restrict__ W1,
    const float* __restrict__ b1, const float* __restrict__ W2,
    _Float16* __restrict__ A, _Float16* __restrict__ A2,
    _Float16* __restrict__ W2T, _Float16* __restrict__ Wd){
  if (blockIdx.x == 512){
    int t = threadIdx.x;
    #pragma unroll
    for (int e=0;e<4;++e){
      int idx = t*4+e;              // n*64 + k
      int n = idx>>6, kk = idx&63;
      W2T[idx] = (n<8) ? (_Float16)W2[kk*8+n] : (_Float16)0.f;
    }
    if (t < 64) Wd[t] = (_Float16)W1[128+t];
    return;
  }
  int gid = blockIdx.x*256 + threadIdx.x;  // 2048*64
  int node = gid >> 6, r = gid & 63;
  float c0 = coords[node*2], c1 = coords[node*2+1];
  float v0 = vel[node*2],    v1 = vel[node*2+1];
  float bv = c0*W1[r] + c1*W1[64+r] + v0*W1[192+r] + v1*W1[256+r];
  A[gid] = (_Float16)(b1[r] + bv);
  A2[gid] = (_Float16)bv;
}

// ------------- rel fused v8: 4 i's per block, packed-f16, no LDS -------------
// Block = (b, i-quad); grid 512. Wave w covers j in [w*256,+256) as 16 subtiles
// of 16 j. Lane l: j = j0+(l&15), r in {lg*8..+7, 32+lg*8..+7}.
// t0/t1/cj loads per subtile serve all 4 i's.
__global__ __launch_bounds__(256, 4) void rel_fused8(const float* __restrict__ coords,
    const _Float16* __restrict__ A, const _Float16* __restrict__ A2,
    const _Float16* __restrict__ W2T, const _Float16* __restrict__ Wd,
    const float* __restrict__ b2, unsigned short* __restrict__ relbf){
  const int tid = threadIdx.x;
  const int bid = blockIdx.x;            // 512
  const int b = bid >> 8;
  const int ia = (bid & 255) * 4;        // rows ia..ia+3
  const int w = tid>>6, l = tid&63, lc = l&15, lg = l>>4;
  const int nodea = (b<<10) + ia;

  float2 ci[4];
  #pragma unroll
  for (int r=0;r<4;++r) ci[r] = *(const float2*)(coords + (size_t)(nodea+r)*2);

  union u4h { uint4 u; h2 h[4]; };
  u4h aA[4], aB[4], wA, wB;
  #pragma unroll
  for (int r=0;r<4;++r){
    aA[r].u = *(const uint4*)(A + (size_t)(nodea+r)*64 + lg*8);
    aB[r].u = *(const uint4*)(A + (size_t)(nodea+r)*64 + 32 + lg*8);
  }
  wA.u = *(const uint4*)(Wd + lg*8);
  wB.u = *(const uint4*)(Wd + 32 + lg*8);

  const f16x8 bf0 = *(const f16x8*)&W2T[lc*64 + lg*8];
  const f16x8 bf1 = *(const f16x8*)&W2T[lc*64 + 32 + lg*8];
  const float b2v = (lc<8) ? b2[lc] : 0.f;

  const h2 c2 = {(_Float16)0.0099735570f, (_Float16)0.0099735570f};
  const h2 c1 = {(_Float16)-0.0664904395f, (_Float16)-0.0664904395f};
  const h2 c0 = {(_Float16)0.3989422804f, (_Float16)0.3989422804f};
  const h2 ch = {(_Float16)0.5f, (_Float16)0.5f};

  const float* cb = coords + (size_t)((b<<10) + w*256 + lc)*2;
  const _Float16* ab = A2 + (size_t)((b<<10) + w*256 + lc)*64 + lg*8;
  unsigned short* oba = relbf + ((size_t)b<<23) + ((size_t)ia<<10)
                      + ((size_t)(lc&7)<<20) + (unsigned)(w*256 + lg*4);

  for (int st=0; st<16; ++st){
    u4h t0, t1;
    t0.u = *(const uint4*)(ab + st*1024);
    t1.u = *(const uint4*)(ab + st*1024 + 32);
    float2 cj = *(const float2*)(cb + st*32);
    #pragma unroll
    for (int r=0;r<4;++r){
      float dx = ci[r].x-cj.x, dy = ci[r].y-cj.y;
      _Float16 dh = (_Float16)sqrtf(fmaf(dx,dx,dy*dy));
      h2 d2 = {dh, dh};
      union { h2 h[4]; f16x8 v; } g0, g1;
      #pragma unroll
      for (int e=0;e<4;++e){
        h2 t = (aA[r].h[e] - t0.h[e]) + d2*wA.h[e];
        h2 u = t*t;
        h2 p = u*c2 + c1;
        p = u*p + c0;
        g0.h[e] = u*p + ch*t;
        h2 s = (aB[r].h[e] - t1.h[e]) + d2*wB.h[e];
        h2 v2 = s*s;
        h2 q = v2*c2 + c1;
        q = v2*q + c0;
        g1.h[e] = v2*q + ch*s;
      }
      f32x4 z; z[0]=0.f; z[1]=0.f; z[2]=0.f; z[3]=0.f;
      z = mfma16h(g0.v, bf0, z);
      z = mfma16h(g1.v, bf1, z);
      if (lc < 8){
        unsigned short* op = oba + (size_t)r*1024 + st*16;
        *(unsigned int*)op     = pack_bf16(z[0]+b2v, z[1]+b2v);
        *(unsigned int*)(op+2) = pack_bf16(z[2]+b2v, z[3]+b2v);
      }
    }
  }
}

// ------------- attn v3: swapped-operand MFMA flash, V pre-transposed ---------
__global__ __launch_bounds__(256) void attn_mfma3(
    const unsigned short* __restrict__ q, const unsigned short* __restrict__ kk,
    const unsigned short* __restrict__ vt, const unsigned short* __restrict__ relbf,
    unsigned short* __restrict__ out){
  int bh = blockIdx.x >> 6;
  int i0 = (blockIdx.x & 63) * 16;
  int tid = threadIdx.x;
  int w = tid>>6, l = tid&63, lc = l&15, lg = l>>4;

  __shared__ __align__(16) float accL[4][2][16][17];
  __shared__ float mL[4][16];
  __shared__ float lL[4][16];

  const unsigned short* qb = q + ((size_t)(bh<<10) + i0)*32;
  const unsigned short* kb = kk + ((size_t)bh<<15);
  const unsigned short* vtb = vt + ((size_t)bh<<15);      // [d][j] rows of 1024
  const unsigned short* relrow = relbf + ((size_t)bh<<20) + ((size_t)(i0+lc)<<10);

  s16x8 qf = *(const s16x8*)(qb + (size_t)lc*32 + lg*8);

  float m = -1e30f, lsum = 0.f;
  f32x4 acc0, acc1;
  acc0[0]=0.f; acc0[1]=0.f; acc0[2]=0.f; acc0[3]=0.f;
  acc1 = acc0;

  for (int t=0; t<16; ++t){
    const int jt = w*256 + t*16;
    s16x8 kf = *(const s16x8*)(kb + (size_t)(jt+lc)*32 + lg*8);
    f32x4 z; z[0]=0.f; z[1]=0.f; z[2]=0.f; z[3]=0.f;
    f32x4 s = mfma16(kf, qf, z);     // S^T[j=jt+lg*4+r][i=i0+lc]
    ushort4 rl = *(const ushort4*)(relrow + jt + lg*4);
    s[0] += bf2f(rl.x); s[1] += bf2f(rl.y);
    s[2] += bf2f(rl.z); s[3] += bf2f(rl.w);
    float mx = fmaxf(fmaxf(s[0],s[1]), fmaxf(s[2],s[3]));
    mx = fmaxf(mx, __shfl_xor(mx,16));
    mx = fmaxf(mx, __shfl_xor(mx,32));
    float mn = fmaxf(m, mx);
    float scale = __expf(m - mn);
    m = mn;
    float p0 = __expf(s[0]-mn), p1 = __expf(s[1]-mn);
    float p2 = __expf(s[2]-mn), p3 = __expf(s[3]-mn);
    lsum = lsum*scale + (p0+p1+p2+p3);
    acc0[0]*=scale; acc0[1]*=scale; acc0[2]*=scale; acc0[3]*=scale;
    acc1[0]*=scale; acc1[1]*=scale; acc1[2]*=scale; acc1[3]*=scale;
#if __has_builtin(__builtin_amdgcn_mfma_f32_16x16x16bf16_1k)
    union { unsigned int u[2]; s16x4 v; } pu;
    pu.u[0] = packtr(p0,p1); pu.u[1] = packtr(p2,p3);
    // V^T A-frags from vt rows: m=lc -> d, k=lg*4+e -> j (contiguous b64)
    s16x4 vf0 = *(const s16x4*)(vtb + (size_t)lc*1024 + jt + lg*4);
    s16x4 vf1 = *(const s16x4*)(vtb + (size_t)(16+lc)*1024 + jt + lg*4);
    acc0 = __builtin_amdgcn_mfma_f32_16x16x16bf16_1k(vf0, pu.v, acc0, 0,0,0);
    acc1 = __builtin_amdgcn_mfma_f32_16x16x16bf16_1k(vf1, pu.v, acc1, 0,0,0);
#else
    unsigned int dw0 = packtr(p0,p1), dw1 = packtr(p2,p3);
    int src0 = lc + (((lg*2)&3)<<4);
    int src1 = lc + (((lg*2+1)&3)<<4);
    unsigned int u0 = __shfl(dw0, src0), u1 = __shfl(dw1, src0);
    unsigned int u2 = __shfl(dw0, src1), u3 = __shfl(dw1, src1);
    if (lg >= 2){ u0=0; u1=0; u2=0; u3=0; }
    union { unsigned int u[4]; s16x8 v; } pb;
    pb.u[0]=u0; pb.u[1]=u1; pb.u[2]=u2; pb.u[3]=u3;
    s16x8 vf0 = *(const s16x8*)(vtb + (size_t)lc*1024 + jt + lg*8);
    s16x8 vf1 = *(const s16x8*)(vtb + (size_t)(16+lc)*1024 + jt + lg*8);
    acc0 = mfma16(vf0, pb.v, acc0);
    acc1 = mfma16(vf1, pb.v, acc1);
#endif
  }
  lsum += __shfl_xor(lsum, 16);
  lsum += __shfl_xor(lsum, 32);
  if (lg == 0){ mL[w][lc] = m; lL[w][lc] = lsum; }
  #pragma unroll
  for (int r=0;r<4;++r){
    accL[w][0][lg*4+r][lc] = acc0[r];
    accL[w][1][lg*4+r][lc] = acc1[r];
  }
  __syncthreads();
  int ii = tid & 15, dd = tid >> 4;
  float m0 = mL[0][ii], m1 = mL[1][ii], m2 = mL[2][ii], m3 = mL[3][ii];
  float ms = fmaxf(fmaxf(m0,m1), fmaxf(m2,m3));
  float e0 = __expf(m0-ms), e1 = __expf(m1-ms), e2 = __expf(m2-ms), e3 = __expf(m3-ms);
  float lt = lL[0][ii]*e0 + lL[1][ii]*e1 + lL[2][ii]*e2 + lL[3][ii]*e3;
  float a0 = accL[0][0][dd][ii]*e0 + accL[1][0][dd][ii]*e1
           + accL[2][0][dd][ii]*e2 + accL[3][0][dd][ii]*e3;
  float a1 = accL[0][1][dd][ii]*e0 + accL[1][1][dd][ii]*e1
           + accL[2][1][dd][ii]*e2 + accL[3][1][dd][ii]*e3;
  float inv = 1.0f/lt;
  int b = bh>>3, hh = bh&7;
  size_t ob2 = ((size_t)((b<<10)+i0+ii))*256 + hh*32;
  out[ob2 + dd]      = f2bf(a0*inv);
  out[ob2 + 16 + dd] = f2bf(a1*inv);
}

// ------------- MFMA GEMM: C[M,NC] = A[M,K] @ W[K,NC], A bf16, WT bf16(NC,K) --
template<int K, int NC, int EPI, int BM, int BNt>
__global__ __launch_bounds__(256) void gemm_mfma(
    const unsigned short* __restrict__ Aa, const unsigned short* __restrict__ WT,
    const float* __restrict__ bias, const float* __restrict__ resid,
    void* __restrict__ outv){
  constexpr int WMm = BM/2, WNn = BNt/2;
  constexpr int FM = WMm/16, FN = WNn/16;
  constexpr int LP = 40;
  __shared__ __align__(16) unsigned short As[BM*LP];
  __shared__ __align__(16) unsigned short Bs[BNt*LP];
  const int tid = threadIdx.x;
  const int w = tid>>6, l = tid&63, lc = l&15, lg = l>>4;
  const int wm = w&1, wn = w>>1;
  const int n0 = blockIdx.x*BNt, m0 = blockIdx.y*BM;
  f32x4 acc[FM][FN];
  #pragma unroll
  for (int a=0;a<FM;++a)
    #pragma unroll
    for (int c=0;c<FN;++c){ acc[a][c][0]=0.f; acc[a][c][1]=0.f; acc[a][c][2]=0.f; acc[a][c][3]=0.f; }

  for (int k0=0; k0<K; k0+=32){
    __syncthreads();
    if constexpr (BM==64){
      int row = tid>>2, cg = tid&3;
      *(s16x8*)&As[row*LP+cg*8] = *(const s16x8*)&Aa[(size_t)(m0+row)*K + k0 + cg*8];
    } else {
      int row = tid>>3, cg = tid&7;
      *(ushort4*)&As[row*LP+cg*4] = *(const ushort4*)&Aa[(size_t)(m0+row)*K + k0 + cg*4];
    }
    if constexpr (BNt==64){
      int row = tid>>2, cg = tid&3;
      *(s16x8*)&Bs[row*LP+cg*8] = *(const s16x8*)&WT[(size_t)(n0+row)*K + k0 + cg*8];
    } else {
      int row = tid>>3, cg = tid&7;
      *(ushort4*)&Bs[row*LP+cg*4] = *(const ushort4*)&WT[(size_t)(n0+row)*K + k0 + cg*4];
    }
    __syncthreads();
    s16x8 af[FM], bv[FN];
    #pragma unroll
    for (int a=0;a<FM;++a) af[a] = *(const s16x8*)&As[(wm*WMm + a*16 + lc)*LP + lg*8];
    #pragma unroll
    for (int c=0;c<FN;++c) bv[c] = *(const s16x8*)&Bs[(wn*WNn + c*16 + lc)*LP + lg*8];
    #pragma unroll
    for (int a=0;a<FM;++a)
      #pragma unroll
      for (int c=0;c<FN;++c) acc[a][c] = mfma16(af[a], bv[c], acc[a][c]);
  }
  #pragma unroll
  for (int a=0;a<FM;++a){
    #pragma unroll
    for (int c=0;c<FN;++c){
      int n = n0 + wn*WNn + c*16 + lc;
      float bvv = (EPI!=0) ? bias[n] : 0.f;
      #pragma unroll
      for (int r=0;r<4;++r){
        int m = m0 + wm*WMm + a*16 + lg*4 + r;
        float vv = acc[a][c][r];
        if constexpr (EPI==0){
          ((unsigned short*)outv)[(size_t)m*NC + n] = f2bf(vv);
        } else if constexpr (EPI==1){
          ((float*)outv)[(size_t)m*NC + n] = vv + bvv + resid[(size_t)m*NC + n];
        } else {
          ((unsigned short*)outv)[(size_t)m*NC + n] = f2bf(gelu_f(vv + bvv));
        }
      }
    }
  }
}

extern "C" void kernel_launch(void* const* d_in, const int* in_sizes, int n_in,
                              void* d_out, int out_size, void* d_ws, size_t ws_size,
                              hipStream_t stream){
  const float* x_in  = (const float*)d_in[0];
  const float* coords= (const float*)d_in[1];
  const float* vel   = (const float*)d_in[2];
  const float* ln1_g = (const float*)d_in[3];
  const float* ln1_b = (const float*)d_in[4];
  const float* Wqkv  = (const float*)d_in[5];
  const float* relW1 = (const float*)d_in[6];
  const float* relb1 = (const float*)d_in[7];
  const float* relW2 = (const float*)d_in[8];
  const float* relb2 = (const float*)d_in[9];
  const float* Wout  = (const float*)d_in[10];
  const float* bout  = (const float*)d_in[11];
  const float* ln2_g = (const float*)d_in[12];
  const float* ln2_b = (const float*)d_in[13];
  const float* Wf1   = (const float*)d_in[14];
  const float* bf1   = (const float*)d_in[15];
  const float* Wf2   = (const float*)d_in[16];
  const float* bf2   = (const float*)d_in[17];

  float* x = (float*)d_out;
  unsigned short* us = (unsigned short*)d_ws;
  unsigned short* hbf   = us;                    // 524288
  unsigned short* qkvbf = hbf   + 524288;        // 1572864
  unsigned short* qbf   = qkvbf + 1572864;       // 524288
  unsigned short* kbf   = qbf   + 524288;        // 524288
  unsigned short* vbf   = kbf   + 524288;        // 524288
  unsigned short* attbf = vbf   + 524288;        // 524288
  unsigned short* midbf = attbf + 524288;        // 2097152
  unsigned short* relbf = midbf + 2097152;       // 16777216
  unsigned short* WqkvT = relbf + 16777216;      // 393216
  unsigned short* WoutT = WqkvT + 393216;        // 131072
  unsigned short* Wf1T  = WoutT + 131072;        // 524288
  unsigned short* Wf2T  = Wf1T  + 524288;        // 524288
  _Float16* W2Th = (_Float16*)(Wf2T + 524288);   // 1024
  _Float16* Wdh  = W2Th + 1024;                  // 64
  _Float16* Ah   = Wdh + 64;                     // 131072
  _Float16* A2h  = Ah + 131072;                  // 131072
  float* sint  = (float*)(A2h + 131072);         // 16384
  float* cost  = sint + 16384;                   // 16384
  // VT aliases the (dead-after-rope) qkvbf region: 524288 shorts
  unsigned short* vtbuf = qkvbf;

  hipMemcpyAsync(x, x_in, sizeof(float)*524288, hipMemcpyDeviceToDevice, stream);
  rope_table<<<64,256,0,stream>>>(sint,cost);
  wt_convert<<<dim3(24,8,2),256,0,stream>>>(Wqkv, WqkvT, 256, 768, 256, SCALEV);
  wt_convert<<<dim3(8,8,2),256,0,stream>>>(Wout, WoutT, 256, 256, 0, 1.0f);
  wt_convert<<<dim3(32,8,2),256,0,stream>>>(Wf1, Wf1T, 256, 1024, 0, 1.0f);
  wt_convert<<<dim3(8,32,2),256,0,stream>>>(Wf2, Wf2T, 1024, 256, 0, 1.0f);

  for (int l=0;l<2;++l){
    ln_kernel<<<2048,256,0,stream>>>(x, ln1_g+l*256, ln1_b+l*256, hbf);
    gemm_mfma<256,768,0,64,64><<<dim3(12,32),256,0,stream>>>(
        hbf, WqkvT + (size_t)l*196608, nullptr, nullptr, qkvbf);
    rope_apply_bf<<<2048,256,0,stream>>>(qkvbf, sint, cost, qbf, kbf, vbf);
    v_transpose<<<256,256,0,stream>>>(vbf, vtbuf);
    rel_pre<<<513,256,0,stream>>>(coords, vel, relW1+l*320, relb1+l*64,
                                  relW2+l*512, Ah, A2h, W2Th, Wdh);
    rel_fused8<<<512,256,0,stream>>>(coords, Ah, A2h, W2Th, Wdh,
                                     relb2+l*8, relbf);
    attn_mfma3<<<1024,256,0,stream>>>(qbf, kbf, vtbuf, relbf, attbf);
    gemm_mfma<256,256,1,32,32><<<dim3(8,64),256,0,stream>>>(
        attbf, WoutT + (size_t)l*65536, bout+l*256, x, x);
    ln_kernel<<<2048,256,0,stream>>>(x, ln2_g+l*256, ln2_b+l*256, hbf);
    gemm_mfma<256,1024,2,64,64><<<dim3(16,32),256,0,stream>>>(
        hbf, Wf1T + (size_t)l*262144, bf1+l*1024, nullptr, midbf);
    gemm_mfma<1024,256,1,32,32><<<dim3(8,64),256,0,stream>>>(
        midbf, Wf2T + (size_t)l*262144, bf2+l*256, x, x);
  }
}

// Round 15
// 228.217 us; speedup vs baseline: 1.0321x; 1.0321x over previous
//
#include <hip/hip_runtime.h>
#include <math.h>

#define BN_ 2
#define NN 1024
#define DDIM 256
#define HH 8
#define HDIM 32
#define FFD 1024
#define EPSV 1e-5f
#define SCALEV 0.17677669529663687f

typedef __attribute__((ext_vector_type(8))) short s16x8;
typedef __attribute__((ext_vector_type(4))) short s16x4;
typedef __attribute__((ext_vector_type(4))) float f32x4;
typedef __attribute__((ext_vector_type(2))) _Float16 h2;
typedef __attribute__((ext_vector_type(8))) _Float16 f16x8;

__device__ __forceinline__ float gelu_f(float x){
  return 0.5f*x*(1.0f+erff(x*0.70710678118654752f));
}
__device__ __forceinline__ unsigned int pack_bf16(float lo, float hi){
  unsigned int ul = __float_as_uint(lo), uh = __float_as_uint(hi);
  ul += 0x7fff + ((ul>>16)&1);
  uh += 0x7fff + ((uh>>16)&1);
  return (ul>>16) | (uh & 0xffff0000u);
}
__device__ __forceinline__ unsigned short f2bf(float x){
  unsigned int u = __float_as_uint(x);
  u += 0x7fff + ((u>>16)&1);
  return (unsigned short)(u>>16);
}
__device__ __forceinline__ float bf2f(unsigned short u){
  return __uint_as_float(((unsigned int)u)<<16);
}
__device__ __forceinline__ unsigned int packtr(float lo, float hi){
  return __builtin_amdgcn_perm(__float_as_uint(hi), __float_as_uint(lo), 0x07060302u);
}
__device__ __forceinline__ f32x4 mfma16(s16x8 a, s16x8 b, f32x4 c){
  return __builtin_amdgcn_mfma_f32_16x16x32_bf16(a,b,c,0,0,0);
}
__device__ __forceinline__ f32x4 mfma16h(f16x8 a, f16x8 b, f32x4 c){
  return __builtin_amdgcn_mfma_f32_16x16x32_f16(a,b,c,0,0,0);
}

// ---------------- LayerNorm: f32 in, bf16 out --------------------------------
__global__ __launch_bounds__(256) void ln_kernel(const float* __restrict__ x,
    const float* __restrict__ g, const float* __restrict__ b,
    unsigned short* __restrict__ out){
  int row = blockIdx.x, tid = threadIdx.x;
  float val = x[(size_t)row*DDIM + tid];
  float s = val;
  #pragma unroll
  for (int o=32;o;o>>=1) s += __shfl_xor(s,o);
  __shared__ float sb[4], sb2[4];
  if ((tid&63)==0) sb[tid>>6]=s;
  __syncthreads();
  float mean = (sb[0]+sb[1]+sb[2]+sb[3]) * (1.0f/DDIM);
  float d = val-mean;
  float vs = d*d;
  #pragma unroll
  for (int o=32;o;o>>=1) vs += __shfl_xor(vs,o);
  if ((tid&63)==0) sb2[tid>>6]=vs;
  __syncthreads();
  float var = (sb2[0]+sb2[1]+sb2[2]+sb2[3]) * (1.0f/DDIM);
  out[(size_t)row*DDIM + tid] = f2bf(d*rsqrtf(var+EPSV)*g[tid]+b[tid]);
}

// ---------------- RoPE tables -------------------------------------------------
__global__ __launch_bounds__(256) void rope_table(float* __restrict__ sint, float* __restrict__ cost){
  int idx = blockIdx.x*256+threadIdx.x;   // 16384
  int i = idx >> 4, d = idx & 15;
  float freq = (float)i * powf(10000.0f, -(float)d/16.0f);
  sint[idx]=sinf(freq); cost[idx]=cosf(freq);
}

// ---------------- weight convert+transpose f32(K,NC) -> bf16 WT(NC,K) --------
__global__ __launch_bounds__(256) void wt_convert(const float* __restrict__ in,
    unsigned short* __restrict__ out, int K, int NC, int scaleCols, float scaleVal){
  __shared__ float tile[32][33];
  int tn0 = blockIdx.x*32;
  int tk0 = blockIdx.y*32;
  size_t loff = (size_t)blockIdx.z * K * NC;
  int t = threadIdx.x;
  int col = t & 31, rr = t >> 5;
  #pragma unroll
  for (int i=0;i<4;++i){
    int row = rr + i*8;
    tile[row][col] = in[loff + (size_t)(tk0+row)*NC + tn0+col];
  }
  __syncthreads();
  #pragma unroll
  for (int i=0;i<4;++i){
    int row = rr + i*8;
    int n = tn0 + row;
    float s = (n < scaleCols) ? scaleVal : 1.0f;
    out[loff + (size_t)n*K + tk0 + col] = f2bf(tile[col][row]*s);
  }
}

// ------------- split qkv + rope (bf16 in/out) --------------------------------
__global__ __launch_bounds__(256) void rope_apply_bf(const unsigned short* __restrict__ qkv,
    const float* __restrict__ sint, const float* __restrict__ cost,
    unsigned short* __restrict__ q, unsigned short* __restrict__ k,
    unsigned short* __restrict__ v){
  int row = blockIdx.x;                 // b*1024 + i
  int b = row>>10, i = row&1023;
  int tid = threadIdx.x; int h = tid>>5, d = tid&31;
  const unsigned short* base = qkv + (size_t)row*768;
  size_t oidx = (((size_t)((b<<3)+h)<<10) + i)*32 + d;
  v[oidx] = base[512 + h*32 + d];
  int dd = (d<16) ? d : d-16;
  float s = sint[i*16+dd], c = cost[i*16+dd];
  float q1 = bf2f(base[h*32+dd]), q2 = bf2f(base[h*32+dd+16]);
  q[oidx] = f2bf((d<16) ? (q1*c - q2*s) : (q2*c + q1*s));
  float k1 = bf2f(base[256+h*32+dd]), k2 = bf2f(base[256+h*32+dd+16]);
  k[oidx] = f2bf((d<16) ? (k1*c - k2*s) : (k2*c + k1*s));
}

// ------------- V transpose: v[bh][j][d] -> vt[bh][d][j] ----------------------
__global__ __launch_bounds__(256) void v_transpose(const unsigned short* __restrict__ v,
    unsigned short* __restrict__ vt){
  __shared__ unsigned short t[64][34];
  int bh = blockIdx.x >> 4;
  int j0 = (blockIdx.x & 15) << 6;
  int tid = threadIdx.x;
  const unsigned short* vb = v + ((size_t)bh<<15) + (size_t)j0*32;
  {
    int j = tid >> 2, dg = (tid & 3) * 8;
    s16x8 r = *(const s16x8*)(vb + (size_t)j*32 + dg);
    #pragma unroll
    for (int e=0;e<8;++e) t[j][dg+e] = (unsigned short)r[e];
  }
  __syncthreads();
  {
    int d = tid >> 3, jg = (tid & 7) * 8;
    s16x8 r;
    #pragma unroll
    for (int e=0;e<8;++e) r[e] = (short)t[jg+e][d];
    *(s16x8*)(vt + (((size_t)bh*32 + d)<<10) + j0 + jg) = r;
  }
}

// ------------- rel precompute: per-node separable parts (fp16) + W2T (f16) ---
__global__ __launch_bounds__(256) void rel_pre(const float* __restrict__ coords,
    const float* __restrict__ vel, const float* __restrict__ W1,
    const float* __restrict__ b1, const float* __restrict__ W2,
    _Float16* __restrict__ A, _Float16* __restrict__ A2,
    _Float16* __restrict__ W2T, _Float16* __restrict__ Wd){
  if (blockIdx.x == 512){
    int t = threadIdx.x;
    #pragma unroll
    for (int e=0;e<4;++e){
      int idx = t*4+e;              // n*64 + k
      int n = idx>>6, kk = idx&63;
      W2T[idx] = (n<8) ? (_Float16)W2[kk*8+n] : (_Float16)0.f;
    }
    if (t < 64) Wd[t] = (_Float16)W1[128+t];
    return;
  }
  int gid = blockIdx.x*256 + threadIdx.x;  // 2048*64
  int node = gid >> 6, r = gid & 63;
  float c0 = coords[node*2], c1 = coords[node*2+1];
  float v0 = vel[node*2],    v1 = vel[node*2+1];
  float bv = c0*W1[r] + c1*W1[64+r] + v0*W1[192+r] + v1*W1[256+r];
  A[gid] = (_Float16)(b1[r] + bv);
  A2[gid] = (_Float16)bv;
}

// ------------- rel fused v7: packed-f16 gelu + f16 MFMA, 2 i's/block ---------
__global__ __launch_bounds__(256, 4) void rel_fused7(const float* __restrict__ coords,
    const _Float16* __restrict__ A, const _Float16* __restrict__ A2,
    const _Float16* __restrict__ W2T, const _Float16* __restrict__ Wd,
    const float* __restrict__ b2, unsigned short* __restrict__ relbf){
  const int tid = threadIdx.x;
  const int bid = blockIdx.x;            // 1024
  const int b = bid >> 9;
  const int ia = (bid & 511) * 2;        // rows ia, ia+1
  const int w = tid>>6, l = tid&63, lc = l&15, lg = l>>4;
  const int nodea = (b<<10) + ia;
  float2 cia = *(const float2*)(coords + (size_t)nodea*2);
  float2 cib = *(const float2*)(coords + (size_t)nodea*2 + 2);

  union u4h { uint4 u; h2 h[4]; };
  u4h aA, aB, bA, bB, wA, wB;
  aA.u = *(const uint4*)(A + (size_t)nodea*64 + lg*8);
  aB.u = *(const uint4*)(A + (size_t)nodea*64 + 32 + lg*8);
  bA.u = *(const uint4*)(A + (size_t)(nodea+1)*64 + lg*8);
  bB.u = *(const uint4*)(A + (size_t)(nodea+1)*64 + 32 + lg*8);
  wA.u = *(const uint4*)(Wd + lg*8);
  wB.u = *(const uint4*)(Wd + 32 + lg*8);

  const f16x8 bf0 = *(const f16x8*)&W2T[lc*64 + lg*8];
  const f16x8 bf1 = *(const f16x8*)&W2T[lc*64 + 32 + lg*8];
  const float b2v = (lc<8) ? b2[lc] : 0.f;

  const h2 c2 = {(_Float16)0.0099735570f, (_Float16)0.0099735570f};
  const h2 c1 = {(_Float16)-0.0664904395f, (_Float16)-0.0664904395f};
  const h2 c0 = {(_Float16)0.3989422804f, (_Float16)0.3989422804f};
  const h2 ch = {(_Float16)0.5f, (_Float16)0.5f};

  const float* cb = coords + (size_t)((b<<10) + w*256 + lc)*2;
  const _Float16* ab = A2 + (size_t)((b<<10) + w*256 + lc)*64 + lg*8;
  unsigned short* oba = relbf + ((size_t)b<<23) + ((size_t)ia<<10)
                      + ((size_t)(lc&7)<<20) + (unsigned)(w*256 + lg*4);

  for (int st=0; st<16; ++st){
    u4h t0, t1;
    t0.u = *(const uint4*)(ab + st*1024);
    t1.u = *(const uint4*)(ab + st*1024 + 32);
    float2 cj = *(const float2*)(cb + st*32);
    // ---- i_a ----
    {
      float dx = cia.x-cj.x, dy = cia.y-cj.y;
      _Float16 dh = (_Float16)sqrtf(fmaf(dx,dx,dy*dy));
      h2 d2 = {dh, dh};
      union { h2 h[4]; f16x8 v; } g0, g1;
      #pragma unroll
      for (int e=0;e<4;++e){
        h2 t = (aA.h[e] - t0.h[e]) + d2*wA.h[e];
        h2 u = t*t;
        h2 p = u*c2 + c1;
        p = u*p + c0;
        g0.h[e] = u*p + ch*t;
        h2 s = (aB.h[e] - t1.h[e]) + d2*wB.h[e];
        h2 v = s*s;
        h2 q = v*c2 + c1;
        q = v*q + c0;
        g1.h[e] = v*q + ch*s;
      }
      f32x4 z; z[0]=0.f; z[1]=0.f; z[2]=0.f; z[3]=0.f;
      z = mfma16h(g0.v, bf0, z);
      z = mfma16h(g1.v, bf1, z);
      if (lc < 8){
        unsigned short* op = oba + st*16;
        *(unsigned int*)op     = pack_bf16(z[0]+b2v, z[1]+b2v);
        *(unsigned int*)(op+2) = pack_bf16(z[2]+b2v, z[3]+b2v);
      }
    }
    // ---- i_b (same t0/t1/cj loads) ----
    {
      float dx = cib.x-cj.x, dy = cib.y-cj.y;
      _Float16 dh = (_Float16)sqrtf(fmaf(dx,dx,dy*dy));
      h2 d2 = {dh, dh};
      union { h2 h[4]; f16x8 v; } g0, g1;
      #pragma unroll
      for (int e=0;e<4;++e){
        h2 t = (bA.h[e] - t0.h[e]) + d2*wA.h[e];
        h2 u = t*t;
        h2 p = u*c2 + c1;
        p = u*p + c0;
        g0.h[e] = u*p + ch*t;
        h2 s = (bB.h[e] - t1.h[e]) + d2*wB.h[e];
        h2 v = s*s;
        h2 q = v*c2 + c1;
        q = v*q + c0;
        g1.h[e] = v*q + ch*s;
      }
      f32x4 z; z[0]=0.f; z[1]=0.f; z[2]=0.f; z[3]=0.f;
      z = mfma16h(g0.v, bf0, z);
      z = mfma16h(g1.v, bf1, z);
      if (lc < 8){
        unsigned short* op = oba + 1024 + st*16;
        *(unsigned int*)op     = pack_bf16(z[0]+b2v, z[1]+b2v);
        *(unsigned int*)(op+2) = pack_bf16(z[2]+b2v, z[3]+b2v);
      }
    }
  }
}

// ------------- attn v3: swapped-operand MFMA flash, V pre-transposed ---------
__global__ __launch_bounds__(256) void attn_mfma3(
    const unsigned short* __restrict__ q, const unsigned short* __restrict__ kk,
    const unsigned short* __restrict__ vt, const unsigned short* __restrict__ relbf,
    unsigned short* __restrict__ out){
  int bh = blockIdx.x >> 6;
  int i0 = (blockIdx.x & 63) * 16;
  int tid = threadIdx.x;
  int w = tid>>6, l = tid&63, lc = l&15, lg = l>>4;

  __shared__ __align__(16) float accL[4][2][16][17];
  __shared__ float mL[4][16];
  __shared__ float lL[4][16];

  const unsigned short* qb = q + ((size_t)(bh<<10) + i0)*32;
  const unsigned short* kb = kk + ((size_t)bh<<15);
  const unsigned short* vtb = vt + ((size_t)bh<<15);      // [d][j] rows of 1024
  const unsigned short* relrow = relbf + ((size_t)bh<<20) + ((size_t)(i0+lc)<<10);

  s16x8 qf = *(const s16x8*)(qb + (size_t)lc*32 + lg*8);

  float m = -1e30f, lsum = 0.f;
  f32x4 acc0, acc1;
  acc0[0]=0.f; acc0[1]=0.f; acc0[2]=0.f; acc0[3]=0.f;
  acc1 = acc0;

  for (int t=0; t<16; ++t){
    const int jt = w*256 + t*16;
    s16x8 kf = *(const s16x8*)(kb + (size_t)(jt+lc)*32 + lg*8);
    f32x4 z; z[0]=0.f; z[1]=0.f; z[2]=0.f; z[3]=0.f;
    f32x4 s = mfma16(kf, qf, z);     // S^T[j=jt+lg*4+r][i=i0+lc]
    ushort4 rl = *(const ushort4*)(relrow + jt + lg*4);
    s[0] += bf2f(rl.x); s[1] += bf2f(rl.y);
    s[2] += bf2f(rl.z); s[3] += bf2f(rl.w);
    float mx = fmaxf(fmaxf(s[0],s[1]), fmaxf(s[2],s[3]));
    mx = fmaxf(mx, __shfl_xor(mx,16));
    mx = fmaxf(mx, __shfl_xor(mx,32));
    float mn = fmaxf(m, mx);
    float scale = __expf(m - mn);
    m = mn;
    float p0 = __expf(s[0]-mn), p1 = __expf(s[1]-mn);
    float p2 = __expf(s[2]-mn), p3 = __expf(s[3]-mn);
    lsum = lsum*scale + (p0+p1+p2+p3);
    acc0[0]*=scale; acc0[1]*=scale; acc0[2]*=scale; acc0[3]*=scale;
    acc1[0]*=scale; acc1[1]*=scale; acc1[2]*=scale; acc1[3]*=scale;
#if __has_builtin(__builtin_amdgcn_mfma_f32_16x16x16bf16_1k)
    union { unsigned int u[2]; s16x4 v; } pu;
    pu.u[0] = packtr(p0,p1); pu.u[1] = packtr(p2,p3);
    s16x4 vf0 = *(const s16x4*)(vtb + (size_t)lc*1024 + jt + lg*4);
    s16x4 vf1 = *(const s16x4*)(vtb + (size_t)(16+lc)*1024 + jt + lg*4);
    acc0 = __builtin_amdgcn_mfma_f32_16x16x16bf16_1k(vf0, pu.v, acc0, 0,0,0);
    acc1 = __builtin_amdgcn_mfma_f32_16x16x16bf16_1k(vf1, pu.v, acc1, 0,0,0);
#else
    unsigned int dw0 = packtr(p0,p1), dw1 = packtr(p2,p3);
    int src0 = lc + (((lg*2)&3)<<4);
    int src1 = lc + (((lg*2+1)&3)<<4);
    unsigned int u0 = __shfl(dw0, src0), u1 = __shfl(dw1, src0);
    unsigned int u2 = __shfl(dw0, src1), u3 = __shfl(dw1, src1);
    if (lg >= 2){ u0=0; u1=0; u2=0; u3=0; }
    union { unsigned int u[4]; s16x8 v; } pb;
    pb.u[0]=u0; pb.u[1]=u1; pb.u[2]=u2; pb.u[3]=u3;
    s16x8 vf0 = *(const s16x8*)(vtb + (size_t)lc*1024 + jt + lg*8);
    s16x8 vf1 = *(const s16x8*)(vtb + (size_t)(16+lc)*1024 + jt + lg*8);
    acc0 = mfma16(vf0, pb.v, acc0);
    acc1 = mfma16(vf1, pb.v, acc1);
#endif
  }
  lsum += __shfl_xor(lsum, 16);
  lsum += __shfl_xor(lsum, 32);
  if (lg == 0){ mL[w][lc] = m; lL[w][lc] = lsum; }
  #pragma unroll
  for (int r=0;r<4;++r){
    accL[w][0][lg*4+r][lc] = acc0[r];
    accL[w][1][lg*4+r][lc] = acc1[r];
  }
  __syncthreads();
  int ii = tid & 15, dd = tid >> 4;
  float m0 = mL[0][ii], m1 = mL[1][ii], m2 = mL[2][ii], m3 = mL[3][ii];
  float ms = fmaxf(fmaxf(m0,m1), fmaxf(m2,m3));
  float e0 = __expf(m0-ms), e1 = __expf(m1-ms), e2 = __expf(m2-ms), e3 = __expf(m3-ms);
  float lt = lL[0][ii]*e0 + lL[1][ii]*e1 + lL[2][ii]*e2 + lL[3][ii]*e3;
  float a0 = accL[0][0][dd][ii]*e0 + accL[1][0][dd][ii]*e1
           + accL[2][0][dd][ii]*e2 + accL[3][0][dd][ii]*e3;
  float a1 = accL[0][1][dd][ii]*e0 + accL[1][1][dd][ii]*e1
           + accL[2][1][dd][ii]*e2 + accL[3][1][dd][ii]*e3;
  float inv = 1.0f/lt;
  int b = bh>>3, hh = bh&7;
  size_t ob2 = ((size_t)((b<<10)+i0+ii))*256 + hh*32;
  out[ob2 + dd]      = f2bf(a0*inv);
  out[ob2 + 16 + dd] = f2bf(a1*inv);
}

// ------------- MFMA GEMM: C[M,NC] = A[M,K] @ W[K,NC], A bf16, WT bf16(NC,K) --
template<int K, int NC, int EPI, int BM, int BNt>
__global__ __launch_bounds__(256) void gemm_mfma(
    const unsigned short* __restrict__ Aa, const unsigned short* __restrict__ WT,
    const float* __restrict__ bias, const float* __restrict__ resid,
    void* __restrict__ outv){
  constexpr int WMm = BM/2, WNn = BNt/2;
  constexpr int FM = WMm/16, FN = WNn/16;
  constexpr int LP = 40;
  __shared__ __align__(16) unsigned short As[BM*LP];
  __shared__ __align__(16) unsigned short Bs[BNt*LP];
  const int tid = threadIdx.x;
  const int w = tid>>6, l = tid&63, lc = l&15, lg = l>>4;
  const int wm = w&1, wn = w>>1;
  const int n0 = blockIdx.x*BNt, m0 = blockIdx.y*BM;
  f32x4 acc[FM][FN];
  #pragma unroll
  for (int a=0;a<FM;++a)
    #pragma unroll
    for (int c=0;c<FN;++c){ acc[a][c][0]=0.f; acc[a][c][1]=0.f; acc[a][c][2]=0.f; acc[a][c][3]=0.f; }

  for (int k0=0; k0<K; k0+=32){
    __syncthreads();
    if constexpr (BM==64){
      int row = tid>>2, cg = tid&3;
      *(s16x8*)&As[row*LP+cg*8] = *(const s16x8*)&Aa[(size_t)(m0+row)*K + k0 + cg*8];
    } else {
      int row = tid>>3, cg = tid&7;
      *(ushort4*)&As[row*LP+cg*4] = *(const ushort4*)&Aa[(size_t)(m0+row)*K + k0 + cg*4];
    }
    if constexpr (BNt==64){
      int row = tid>>2, cg = tid&3;
      *(s16x8*)&Bs[row*LP+cg*8] = *(const s16x8*)&WT[(size_t)(n0+row)*K + k0 + cg*8];
    } else {
      int row = tid>>3, cg = tid&7;
      *(ushort4*)&Bs[row*LP+cg*4] = *(const ushort4*)&WT[(size_t)(n0+row)*K + k0 + cg*4];
    }
    __syncthreads();
    s16x8 af[FM], bv[FN];
    #pragma unroll
    for (int a=0;a<FM;++a) af[a] = *(const s16x8*)&As[(wm*WMm + a*16 + lc)*LP + lg*8];
    #pragma unroll
    for (int c=0;c<FN;++c) bv[c] = *(const s16x8*)&Bs[(wn*WNn + c*16 + lc)*LP + lg*8];
    #pragma unroll
    for (int a=0;a<FM;++a)
      #pragma unroll
      for (int c=0;c<FN;++c) acc[a][c] = mfma16(af[a], bv[c], acc[a][c]);
  }
  #pragma unroll
  for (int a=0;a<FM;++a){
    #pragma unroll
    for (int c=0;c<FN;++c){
      int n = n0 + wn*WNn + c*16 + lc;
      float bvv = (EPI!=0) ? bias[n] : 0.f;
      #pragma unroll
      for (int r=0;r<4;++r){
        int m = m0 + wm*WMm + a*16 + lg*4 + r;
        float vv = acc[a][c][r];
        if constexpr (EPI==0){
          ((unsigned short*)outv)[(size_t)m*NC + n] = f2bf(vv);
        } else if constexpr (EPI==1){
          ((float*)outv)[(size_t)m*NC + n] = vv + bvv + resid[(size_t)m*NC + n];
        } else {
          ((unsigned short*)outv)[(size_t)m*NC + n] = f2bf(gelu_f(vv + bvv));
        }
      }
    }
  }
}

extern "C" void kernel_launch(void* const* d_in, const int* in_sizes, int n_in,
                              void* d_out, int out_size, void* d_ws, size_t ws_size,
                              hipStream_t stream){
  const float* x_in  = (const float*)d_in[0];
  const float* coords= (const float*)d_in[1];
  const float* vel   = (const float*)d_in[2];
  const float* ln1_g = (const float*)d_in[3];
  const float* ln1_b = (const float*)d_in[4];
  const float* Wqkv  = (const float*)d_in[5];
  const float* relW1 = (const float*)d_in[6];
  const float* relb1 = (const float*)d_in[7];
  const float* relW2 = (const float*)d_in[8];
  const float* relb2 = (const float*)d_in[9];
  const float* Wout  = (const float*)d_in[10];
  const float* bout  = (const float*)d_in[11];
  const float* ln2_g = (const float*)d_in[12];
  const float* ln2_b = (const float*)d_in[13];
  const float* Wf1   = (const float*)d_in[14];
  const float* bf1   = (const float*)d_in[15];
  const float* Wf2   = (const float*)d_in[16];
  const float* bf2   = (const float*)d_in[17];

  float* x = (float*)d_out;
  unsigned short* us = (unsigned short*)d_ws;
  unsigned short* hbf   = us;                    // 524288
  unsigned short* qkvbf = hbf   + 524288;        // 1572864
  unsigned short* qbf   = qkvbf + 1572864;       // 524288
  unsigned short* kbf   = qbf   + 524288;        // 524288
  unsigned short* vbf   = kbf   + 524288;        // 524288
  unsigned short* attbf = vbf   + 524288;        // 524288
  unsigned short* midbf = attbf + 524288;        // 2097152
  unsigned short* relbf = midbf + 2097152;       // 16777216
  unsigned short* WqkvT = relbf + 16777216;      // 393216
  unsigned short* WoutT = WqkvT + 393216;        // 131072
  unsigned short* Wf1T  = WoutT + 131072;        // 524288
  unsigned short* Wf2T  = Wf1T  + 524288;        // 524288
  _Float16* W2Th = (_Float16*)(Wf2T + 524288);   // 1024
  _Float16* Wdh  = W2Th + 1024;                  // 64
  _Float16* Ah   = Wdh + 64;                     // 131072
  _Float16* A2h  = Ah + 131072;                  // 131072
  float* sint  = (float*)(A2h + 131072);         // 16384
  float* cost  = sint + 16384;                   // 16384
  // VT aliases the (dead-after-rope) tail of qkvbf: needs 524288 shorts
  unsigned short* vtbuf = qkvbf + 1048576;

  rope_table<<<64,256,0,stream>>>(sint,cost);
  wt_convert<<<dim3(24,8,2),256,0,stream>>>(Wqkv, WqkvT, 256, 768, 256, SCALEV);
  wt_convert<<<dim3(8,8,2),256,0,stream>>>(Wout, WoutT, 256, 256, 0, 1.0f);
  wt_convert<<<dim3(32,8,2),256,0,stream>>>(Wf1, Wf1T, 256, 1024, 0, 1.0f);
  wt_convert<<<dim3(8,32,2),256,0,stream>>>(Wf2, Wf2T, 1024, 256, 0, 1.0f);

  for (int l=0;l<2;++l){
    const float* xr = (l==0) ? x_in : x;   // residual source; x first written by att-GEMM l=0
    ln_kernel<<<2048,256,0,stream>>>(xr, ln1_g+l*256, ln1_b+l*256, hbf);
    gemm_mfma<256,768,0,64,64><<<dim3(12,32),256,0,stream>>>(
        hbf, WqkvT + (size_t)l*196608, nullptr, nullptr, qkvbf);
    rope_apply_bf<<<2048,256,0,stream>>>(qkvbf, sint, cost, qbf, kbf, vbf);
    v_transpose<<<256,256,0,stream>>>(vbf, vtbuf);
    rel_pre<<<513,256,0,stream>>>(coords, vel, relW1+l*320, relb1+l*64,
                                  relW2+l*512, Ah, A2h, W2Th, Wdh);
    rel_fused7<<<1024,256,0,stream>>>(coords, Ah, A2h, W2Th, Wdh,
                                      relb2+l*8, relbf);
    attn_mfma3<<<1024,256,0,stream>>>(qbf, kbf, vtbuf, relbf, attbf);
    gemm_mfma<256,256,1,32,32><<<dim3(8,64),256,0,stream>>>(
        attbf, WoutT + (size_t)l*65536, bout+l*256, xr, x);
    ln_kernel<<<2048,256,0,stream>>>(x, ln2_g+l*256, ln2_b+l*256, hbf);
    gemm_mfma<256,1024,2,64,64><<<dim3(16,32),256,0,stream>>>(
        hbf, Wf1T + (size_t)l*262144, bf1+l*1024, nullptr, midbf);
    gemm_mfma<1024,256,1,32,32><<<dim3(8,64),256,0,stream>>>(
        midbf, Wf2T + (size_t)l*262144, bf2+l*256, x, x);
  }
}

// Round 16
// 202.422 us; speedup vs baseline: 1.1636x; 1.1274x over previous
//
#include <hip/hip_runtime.h>
#include <math.h>

#define BN_ 2
#define NN 1024
#define DDIM 256
#define HH 8
#define HDIM 32
#define FFD 1024
#define EPSV 1e-5f
#define SCALEV 0.17677669529663687f

typedef __attribute__((ext_vector_type(8))) short s16x8;
typedef __attribute__((ext_vector_type(4))) short s16x4;
typedef __attribute__((ext_vector_type(4))) float f32x4;
typedef __attribute__((ext_vector_type(2))) _Float16 h2;
typedef __attribute__((ext_vector_type(8))) _Float16 f16x8;

__device__ __forceinline__ float gelu_f(float x){
  return 0.5f*x*(1.0f+erff(x*0.70710678118654752f));
}
__device__ __forceinline__ unsigned int pack_bf16(float lo, float hi){
  unsigned int ul = __float_as_uint(lo), uh = __float_as_uint(hi);
  ul += 0x7fff + ((ul>>16)&1);
  uh += 0x7fff + ((uh>>16)&1);
  return (ul>>16) | (uh & 0xffff0000u);
}
__device__ __forceinline__ unsigned short f2bf(float x){
  unsigned int u = __float_as_uint(x);
  u += 0x7fff + ((u>>16)&1);
  return (unsigned short)(u>>16);
}
__device__ __forceinline__ float bf2f(unsigned short u){
  return __uint_as_float(((unsigned int)u)<<16);
}
__device__ __forceinline__ unsigned int packtr(float lo, float hi){
  return __builtin_amdgcn_perm(__float_as_uint(hi), __float_as_uint(lo), 0x07060302u);
}
__device__ __forceinline__ f32x4 mfma16(s16x8 a, s16x8 b, f32x4 c){
  return __builtin_amdgcn_mfma_f32_16x16x32_bf16(a,b,c,0,0,0);
}
__device__ __forceinline__ f32x4 mfma16h(f16x8 a, f16x8 b, f32x4 c){
  return __builtin_amdgcn_mfma_f32_16x16x32_f16(a,b,c,0,0,0);
}

// ---------------- LayerNorm: f32 in, bf16 out --------------------------------
__global__ __launch_bounds__(256) void ln_kernel(const float* __restrict__ x,
    const float* __restrict__ g, const float* __restrict__ b,
    unsigned short* __restrict__ out){
  int row = blockIdx.x, tid = threadIdx.x;
  float val = x[(size_t)row*DDIM + tid];
  float s = val;
  #pragma unroll
  for (int o=32;o;o>>=1) s += __shfl_xor(s,o);
  __shared__ float sb[4], sb2[4];
  if ((tid&63)==0) sb[tid>>6]=s;
  __syncthreads();
  float mean = (sb[0]+sb[1]+sb[2]+sb[3]) * (1.0f/DDIM);
  float d = val-mean;
  float vs = d*d;
  #pragma unroll
  for (int o=32;o;o>>=1) vs += __shfl_xor(vs,o);
  if ((tid&63)==0) sb2[tid>>6]=vs;
  __syncthreads();
  float var = (sb2[0]+sb2[1]+sb2[2]+sb2[3]) * (1.0f/DDIM);
  out[(size_t)row*DDIM + tid] = f2bf(d*rsqrtf(var+EPSV)*g[tid]+b[tid]);
}

// ---------------- RoPE tables -------------------------------------------------
__global__ __launch_bounds__(256) void rope_table(float* __restrict__ sint, float* __restrict__ cost){
  int idx = blockIdx.x*256+threadIdx.x;   // 16384
  int i = idx >> 4, d = idx & 15;
  float freq = (float)i * powf(10000.0f, -(float)d/16.0f);
  sint[idx]=sinf(freq); cost[idx]=cosf(freq);
}

// ---------------- weight convert+transpose f32(K,NC) -> bf16 WT(NC,K) --------
__global__ __launch_bounds__(256) void wt_convert(const float* __restrict__ in,
    unsigned short* __restrict__ out, int K, int NC, int scaleCols, float scaleVal){
  __shared__ float tile[32][33];
  int tn0 = blockIdx.x*32;
  int tk0 = blockIdx.y*32;
  size_t loff = (size_t)blockIdx.z * K * NC;
  int t = threadIdx.x;
  int col = t & 31, rr = t >> 5;
  #pragma unroll
  for (int i=0;i<4;++i){
    int row = rr + i*8;
    tile[row][col] = in[loff + (size_t)(tk0+row)*NC + tn0+col];
  }
  __syncthreads();
  #pragma unroll
  for (int i=0;i<4;++i){
    int row = rr + i*8;
    int n = tn0 + row;
    float s = (n < scaleCols) ? scaleVal : 1.0f;
    out[loff + (size_t)n*K + tk0 + col] = f2bf(tile[col][row]*s);
  }
}

// ------------- split qkv + rope (bf16 in/out) --------------------------------
__global__ __launch_bounds__(256) void rope_apply_bf(const unsigned short* __restrict__ qkv,
    const float* __restrict__ sint, const float* __restrict__ cost,
    unsigned short* __restrict__ q, unsigned short* __restrict__ k,
    unsigned short* __restrict__ v){
  int row = blockIdx.x;                 // b*1024 + i
  int b = row>>10, i = row&1023;
  int tid = threadIdx.x; int h = tid>>5, d = tid&31;
  const unsigned short* base = qkv + (size_t)row*768;
  size_t oidx = (((size_t)((b<<3)+h)<<10) + i)*32 + d;
  v[oidx] = base[512 + h*32 + d];
  int dd = (d<16) ? d : d-16;
  float s = sint[i*16+dd], c = cost[i*16+dd];
  float q1 = bf2f(base[h*32+dd]), q2 = bf2f(base[h*32+dd+16]);
  q[oidx] = f2bf((d<16) ? (q1*c - q2*s) : (q2*c + q1*s));
  float k1 = bf2f(base[256+h*32+dd]), k2 = bf2f(base[256+h*32+dd+16]);
  k[oidx] = f2bf((d<16) ? (k1*c - k2*s) : (k2*c + k1*s));
}

// ------------- rel precompute: per-node separable parts (fp16) + W2T (f16) ---
__global__ __launch_bounds__(256) void rel_pre(const float* __restrict__ coords,
    const float* __restrict__ vel, const float* __restrict__ W1,
    const float* __restrict__ b1, const float* __restrict__ W2,
    _Float16* __restrict__ A, _Float16* __restrict__ A2,
    _Float16* __restrict__ W2T, _Float16* __restrict__ Wd){
  if (blockIdx.x == 512){
    int t = threadIdx.x;
    #pragma unroll
    for (int e=0;e<4;++e){
      int idx = t*4+e;              // n*64 + k
      int n = idx>>6, kk = idx&63;
      W2T[idx] = (n<8) ? (_Float16)W2[kk*8+n] : (_Float16)0.f;
    }
    if (t < 64) Wd[t] = (_Float16)W1[128+t];
    return;
  }
  int gid = blockIdx.x*256 + threadIdx.x;  // 2048*64
  int node = gid >> 6, r = gid & 63;
  float c0 = coords[node*2], c1 = coords[node*2+1];
  float v0 = vel[node*2],    v1 = vel[node*2+1];
  float bv = c0*W1[r] + c1*W1[64+r] + v0*W1[192+r] + v1*W1[256+r];
  A[gid] = (_Float16)(b1[r] + bv);
  A2[gid] = (_Float16)bv;
}

// ------------- rel fused v7: packed-f16 gelu + f16 MFMA, 2 i's/block ---------
__global__ __launch_bounds__(256, 4) void rel_fused7(const float* __restrict__ coords,
    const _Float16* __restrict__ A, const _Float16* __restrict__ A2,
    const _Float16* __restrict__ W2T, const _Float16* __restrict__ Wd,
    const float* __restrict__ b2, unsigned short* __restrict__ relbf){
  const int tid = threadIdx.x;
  const int bid = blockIdx.x;            // 1024
  const int b = bid >> 9;
  const int ia = (bid & 511) * 2;        // rows ia, ia+1
  const int w = tid>>6, l = tid&63, lc = l&15, lg = l>>4;
  const int nodea = (b<<10) + ia;
  float2 cia = *(const float2*)(coords + (size_t)nodea*2);
  float2 cib = *(const float2*)(coords + (size_t)nodea*2 + 2);

  union u4h { uint4 u; h2 h[4]; };
  u4h aA, aB, bA, bB, wA, wB;
  aA.u = *(const uint4*)(A + (size_t)nodea*64 + lg*8);
  aB.u = *(const uint4*)(A + (size_t)nodea*64 + 32 + lg*8);
  bA.u = *(const uint4*)(A + (size_t)(nodea+1)*64 + lg*8);
  bB.u = *(const uint4*)(A + (size_t)(nodea+1)*64 + 32 + lg*8);
  wA.u = *(const uint4*)(Wd + lg*8);
  wB.u = *(const uint4*)(Wd + 32 + lg*8);

  const f16x8 bf0 = *(const f16x8*)&W2T[lc*64 + lg*8];
  const f16x8 bf1 = *(const f16x8*)&W2T[lc*64 + 32 + lg*8];
  const float b2v = (lc<8) ? b2[lc] : 0.f;

  const h2 c2 = {(_Float16)0.0099735570f, (_Float16)0.0099735570f};
  const h2 c1 = {(_Float16)-0.0664904395f, (_Float16)-0.0664904395f};
  const h2 c0 = {(_Float16)0.3989422804f, (_Float16)0.3989422804f};
  const h2 ch = {(_Float16)0.5f, (_Float16)0.5f};

  const float* cb = coords + (size_t)((b<<10) + w*256 + lc)*2;
  const _Float16* ab = A2 + (size_t)((b<<10) + w*256 + lc)*64 + lg*8;
  unsigned short* oba = relbf + ((size_t)b<<23) + ((size_t)ia<<10)
                      + ((size_t)(lc&7)<<20) + (unsigned)(w*256 + lg*4);

  for (int st=0; st<16; ++st){
    u4h t0, t1;
    t0.u = *(const uint4*)(ab + st*1024);
    t1.u = *(const uint4*)(ab + st*1024 + 32);
    float2 cj = *(const float2*)(cb + st*32);
    // ---- i_a ----
    {
      float dx = cia.x-cj.x, dy = cia.y-cj.y;
      _Float16 dh = (_Float16)sqrtf(fmaf(dx,dx,dy*dy));
      h2 d2 = {dh, dh};
      union { h2 h[4]; f16x8 v; } g0, g1;
      #pragma unroll
      for (int e=0;e<4;++e){
        h2 t = (aA.h[e] - t0.h[e]) + d2*wA.h[e];
        h2 u = t*t;
        h2 p = u*c2 + c1;
        p = u*p + c0;
        g0.h[e] = u*p + ch*t;
        h2 s = (aB.h[e] - t1.h[e]) + d2*wB.h[e];
        h2 v = s*s;
        h2 q = v*c2 + c1;
        q = v*q + c0;
        g1.h[e] = v*q + ch*s;
      }
      f32x4 z; z[0]=0.f; z[1]=0.f; z[2]=0.f; z[3]=0.f;
      z = mfma16h(g0.v, bf0, z);
      z = mfma16h(g1.v, bf1, z);
      if (lc < 8){
        unsigned short* op = oba + st*16;
        *(unsigned int*)op     = pack_bf16(z[0]+b2v, z[1]+b2v);
        *(unsigned int*)(op+2) = pack_bf16(z[2]+b2v, z[3]+b2v);
      }
    }
    // ---- i_b (same t0/t1/cj loads) ----
    {
      float dx = cib.x-cj.x, dy = cib.y-cj.y;
      _Float16 dh = (_Float16)sqrtf(fmaf(dx,dx,dy*dy));
      h2 d2 = {dh, dh};
      union { h2 h[4]; f16x8 v; } g0, g1;
      #pragma unroll
      for (int e=0;e<4;++e){
        h2 t = (bA.h[e] - t0.h[e]) + d2*wA.h[e];
        h2 u = t*t;
        h2 p = u*c2 + c1;
        p = u*p + c0;
        g0.h[e] = u*p + ch*t;
        h2 s = (bB.h[e] - t1.h[e]) + d2*wB.h[e];
        h2 v = s*s;
        h2 q = v*c2 + c1;
        q = v*q + c0;
        g1.h[e] = v*q + ch*s;
      }
      f32x4 z; z[0]=0.f; z[1]=0.f; z[2]=0.f; z[3]=0.f;
      z = mfma16h(g0.v, bf0, z);
      z = mfma16h(g1.v, bf1, z);
      if (lc < 8){
        unsigned short* op = oba + 1024 + st*16;
        *(unsigned int*)op     = pack_bf16(z[0]+b2v, z[1]+b2v);
        *(unsigned int*)(op+2) = pack_bf16(z[2]+b2v, z[3]+b2v);
      }
    }
  }
}

// ------------- attn v2: swapped-operand MFMA flash, per-lane softmax state ---
__global__ __launch_bounds__(256) void attn_mfma2(
    const unsigned short* __restrict__ q, const unsigned short* __restrict__ kk,
    const unsigned short* __restrict__ vv, const unsigned short* __restrict__ relbf,
    unsigned short* __restrict__ out){
  int bh = blockIdx.x >> 6;
  int i0 = (blockIdx.x & 63) * 16;
  int tid = threadIdx.x;
  int w = tid>>6, l = tid&63, lc = l&15, lg = l>>4;

  __shared__ __align__(16) float accL[4][2][16][17];
  __shared__ float mL[4][16];
  __shared__ float lL[4][16];

  const unsigned short* qb = q + ((size_t)(bh<<10) + i0)*32;
  const unsigned short* kb = kk + ((size_t)bh<<15);
  const unsigned short* vb = vv + ((size_t)bh<<15);
  const unsigned short* relrow = relbf + ((size_t)bh<<20) + ((size_t)(i0+lc)<<10);

  s16x8 qf = *(const s16x8*)(qb + (size_t)lc*32 + lg*8);

  float m = -1e30f, lsum = 0.f;
  f32x4 acc0, acc1;
  acc0[0]=0.f; acc0[1]=0.f; acc0[2]=0.f; acc0[3]=0.f;
  acc1 = acc0;

  for (int t=0; t<16; ++t){
    const int jt = w*256 + t*16;
    s16x8 kf = *(const s16x8*)(kb + (size_t)(jt+lc)*32 + lg*8);
    f32x4 z; z[0]=0.f; z[1]=0.f; z[2]=0.f; z[3]=0.f;
    f32x4 s = mfma16(kf, qf, z);     // S^T[j=jt+lg*4+r][i=i0+lc]
    ushort4 rl = *(const ushort4*)(relrow + jt + lg*4);
    s[0] += bf2f(rl.x); s[1] += bf2f(rl.y);
    s[2] += bf2f(rl.z); s[3] += bf2f(rl.w);
    float mx = fmaxf(fmaxf(s[0],s[1]), fmaxf(s[2],s[3]));
    mx = fmaxf(mx, __shfl_xor(mx,16));
    mx = fmaxf(mx, __shfl_xor(mx,32));
    float mn = fmaxf(m, mx);
    float scale = __expf(m - mn);
    m = mn;
    float p0 = __expf(s[0]-mn), p1 = __expf(s[1]-mn);
    float p2 = __expf(s[2]-mn), p3 = __expf(s[3]-mn);
    lsum = lsum*scale + (p0+p1+p2+p3);
    acc0[0]*=scale; acc0[1]*=scale; acc0[2]*=scale; acc0[3]*=scale;
    acc1[0]*=scale; acc1[1]*=scale; acc1[2]*=scale; acc1[3]*=scale;
#if __has_builtin(__builtin_amdgcn_mfma_f32_16x16x16bf16_1k)
    union { unsigned int u[2]; s16x4 v; } pu;
    pu.u[0] = packtr(p0,p1); pu.u[1] = packtr(p2,p3);
    const unsigned short* vp = vb + (size_t)(jt + lg*4)*32 + lc;
    s16x4 vf0, vf1;
    vf0[0]=(short)vp[0];  vf0[1]=(short)vp[32];  vf0[2]=(short)vp[64];  vf0[3]=(short)vp[96];
    vf1[0]=(short)vp[16]; vf1[1]=(short)vp[48];  vf1[2]=(short)vp[80];  vf1[3]=(short)vp[112];
    acc0 = __builtin_amdgcn_mfma_f32_16x16x16bf16_1k(vf0, pu.v, acc0, 0,0,0);
    acc1 = __builtin_amdgcn_mfma_f32_16x16x16bf16_1k(vf1, pu.v, acc1, 0,0,0);
#else
    unsigned int dw0 = packtr(p0,p1), dw1 = packtr(p2,p3);
    int src0 = lc + (((lg*2)&3)<<4);
    int src1 = lc + (((lg*2+1)&3)<<4);
    unsigned int u0 = __shfl(dw0, src0), u1 = __shfl(dw1, src0);
    unsigned int u2 = __shfl(dw0, src1), u3 = __shfl(dw1, src1);
    if (lg >= 2){ u0=0; u1=0; u2=0; u3=0; }
    union { unsigned int u[4]; s16x8 v; } pb;
    pb.u[0]=u0; pb.u[1]=u1; pb.u[2]=u2; pb.u[3]=u3;
    s16x8 vf0, vf1;
    #pragma unroll
    for (int e=0;e<8;++e){
      int j = (jt + lg*8 + e) & 1023;
      vf0[e] = (short)vb[(size_t)j*32 + lc];
      vf1[e] = (short)vb[(size_t)j*32 + 16 + lc];
    }
    acc0 = mfma16(vf0, pb.v, acc0);
    acc1 = mfma16(vf1, pb.v, acc1);
#endif
  }
  lsum += __shfl_xor(lsum, 16);
  lsum += __shfl_xor(lsum, 32);
  if (lg == 0){ mL[w][lc] = m; lL[w][lc] = lsum; }
  #pragma unroll
  for (int r=0;r<4;++r){
    accL[w][0][lg*4+r][lc] = acc0[r];
    accL[w][1][lg*4+r][lc] = acc1[r];
  }
  __syncthreads();
  int ii = tid & 15, dd = tid >> 4;
  float m0 = mL[0][ii], m1 = mL[1][ii], m2 = mL[2][ii], m3 = mL[3][ii];
  float ms = fmaxf(fmaxf(m0,m1), fmaxf(m2,m3));
  float e0 = __expf(m0-ms), e1 = __expf(m1-ms), e2 = __expf(m2-ms), e3 = __expf(m3-ms);
  float lt = lL[0][ii]*e0 + lL[1][ii]*e1 + lL[2][ii]*e2 + lL[3][ii]*e3;
  float a0 = accL[0][0][dd][ii]*e0 + accL[1][0][dd][ii]*e1
           + accL[2][0][dd][ii]*e2 + accL[3][0][dd][ii]*e3;
  float a1 = accL[0][1][dd][ii]*e0 + accL[1][1][dd][ii]*e1
           + accL[2][1][dd][ii]*e2 + accL[3][1][dd][ii]*e3;
  float inv = 1.0f/lt;
  int b = bh>>3, hh = bh&7;
  size_t ob2 = ((size_t)((b<<10)+i0+ii))*256 + hh*32;
  out[ob2 + dd]      = f2bf(a0*inv);
  out[ob2 + 16 + dd] = f2bf(a1*inv);
}

// ------------- MFMA GEMM: C[M,NC] = A[M,K] @ W[K,NC], A bf16, WT bf16(NC,K) --
template<int K, int NC, int EPI, int BM, int BNt>
__global__ __launch_bounds__(256) void gemm_mfma(
    const unsigned short* __restrict__ Aa, const unsigned short* __restrict__ WT,
    const float* __restrict__ bias, const float* __restrict__ resid,
    void* __restrict__ outv){
  constexpr int WMm = BM/2, WNn = BNt/2;
  constexpr int FM = WMm/16, FN = WNn/16;
  constexpr int LP = 40;
  __shared__ __align__(16) unsigned short As[BM*LP];
  __shared__ __align__(16) unsigned short Bs[BNt*LP];
  const int tid = threadIdx.x;
  const int w = tid>>6, l = tid&63, lc = l&15, lg = l>>4;
  const int wm = w&1, wn = w>>1;
  const int n0 = blockIdx.x*BNt, m0 = blockIdx.y*BM;
  f32x4 acc[FM][FN];
  #pragma unroll
  for (int a=0;a<FM;++a)
    #pragma unroll
    for (int c=0;c<FN;++c){ acc[a][c][0]=0.f; acc[a][c][1]=0.f; acc[a][c][2]=0.f; acc[a][c][3]=0.f; }

  for (int k0=0; k0<K; k0+=32){
    __syncthreads();
    if constexpr (BM==64){
      int row = tid>>2, cg = tid&3;
      *(s16x8*)&As[row*LP+cg*8] = *(const s16x8*)&Aa[(size_t)(m0+row)*K + k0 + cg*8];
    } else {
      int row = tid>>3, cg = tid&7;
      *(ushort4*)&As[row*LP+cg*4] = *(const ushort4*)&Aa[(size_t)(m0+row)*K + k0 + cg*4];
    }
    if constexpr (BNt==64){
      int row = tid>>2, cg = tid&3;
      *(s16x8*)&Bs[row*LP+cg*8] = *(const s16x8*)&WT[(size_t)(n0+row)*K + k0 + cg*8];
    } else {
      int row = tid>>3, cg = tid&7;
      *(ushort4*)&Bs[row*LP+cg*4] = *(const ushort4*)&WT[(size_t)(n0+row)*K + k0 + cg*4];
    }
    __syncthreads();
    s16x8 af[FM], bv[FN];
    #pragma unroll
    for (int a=0;a<FM;++a) af[a] = *(const s16x8*)&As[(wm*WMm + a*16 + lc)*LP + lg*8];
    #pragma unroll
    for (int c=0;c<FN;++c) bv[c] = *(const s16x8*)&Bs[(wn*WNn + c*16 + lc)*LP + lg*8];
    #pragma unroll
    for (int a=0;a<FM;++a)
      #pragma unroll
      for (int c=0;c<FN;++c) acc[a][c] = mfma16(af[a], bv[c], acc[a][c]);
  }
  #pragma unroll
  for (int a=0;a<FM;++a){
    #pragma unroll
    for (int c=0;c<FN;++c){
      int n = n0 + wn*WNn + c*16 + lc;
      float bvv = (EPI!=0) ? bias[n] : 0.f;
      #pragma unroll
      for (int r=0;r<4;++r){
        int m = m0 + wm*WMm + a*16 + lg*4 + r;
        float vv = acc[a][c][r];
        if constexpr (EPI==0){
          ((unsigned short*)outv)[(size_t)m*NC + n] = f2bf(vv);
        } else if constexpr (EPI==1){
          ((float*)outv)[(size_t)m*NC + n] = vv + bvv + resid[(size_t)m*NC + n];
        } else {
          ((unsigned short*)outv)[(size_t)m*NC + n] = f2bf(gelu_f(vv + bvv));
        }
      }
    }
  }
}

extern "C" void kernel_launch(void* const* d_in, const int* in_sizes, int n_in,
                              void* d_out, int out_size, void* d_ws, size_t ws_size,
                              hipStream_t stream){
  const float* x_in  = (const float*)d_in[0];
  const float* coords= (const float*)d_in[1];
  const float* vel   = (const float*)d_in[2];
  const float* ln1_g = (const float*)d_in[3];
  const float* ln1_b = (const float*)d_in[4];
  const float* Wqkv  = (const float*)d_in[5];
  const float* relW1 = (const float*)d_in[6];
  const float* relb1 = (const float*)d_in[7];
  const float* relW2 = (const float*)d_in[8];
  const float* relb2 = (const float*)d_in[9];
  const float* Wout  = (const float*)d_in[10];
  const float* bout  = (const float*)d_in[11];
  const float* ln2_g = (const float*)d_in[12];
  const float* ln2_b = (const float*)d_in[13];
  const float* Wf1   = (const float*)d_in[14];
  const float* bf1   = (const float*)d_in[15];
  const float* Wf2   = (const float*)d_in[16];
  const float* bf2   = (const float*)d_in[17];

  float* x = (float*)d_out;
  unsigned short* us = (unsigned short*)d_ws;
  unsigned short* hbf   = us;                    // 524288
  unsigned short* qkvbf = hbf   + 524288;        // 1572864
  unsigned short* qbf   = qkvbf + 1572864;       // 524288
  unsigned short* kbf   = qbf   + 524288;        // 524288
  unsigned short* vbf   = kbf   + 524288;        // 524288
  unsigned short* attbf = vbf   + 524288;        // 524288
  unsigned short* midbf = attbf + 524288;        // 2097152
  unsigned short* relbf = midbf + 2097152;       // 16777216
  unsigned short* WqkvT = relbf + 16777216;      // 393216
  unsigned short* WoutT = WqkvT + 393216;        // 131072
  unsigned short* Wf1T  = WoutT + 131072;        // 524288
  unsigned short* Wf2T  = Wf1T  + 524288;        // 524288
  _Float16* W2Th = (_Float16*)(Wf2T + 524288);   // 1024
  _Float16* Wdh  = W2Th + 1024;                  // 64
  _Float16* Ah   = Wdh + 64;                     // 131072
  _Float16* A2h  = Ah + 131072;                  // 131072
  float* sint  = (float*)(A2h + 131072);         // 16384
  float* cost  = sint + 16384;                   // 16384

  rope_table<<<64,256,0,stream>>>(sint,cost);
  wt_convert<<<dim3(24,8,2),256,0,stream>>>(Wqkv, WqkvT, 256, 768, 256, SCALEV);
  wt_convert<<<dim3(8,8,2),256,0,stream>>>(Wout, WoutT, 256, 256, 0, 1.0f);
  wt_convert<<<dim3(32,8,2),256,0,stream>>>(Wf1, Wf1T, 256, 1024, 0, 1.0f);
  wt_convert<<<dim3(8,32,2),256,0,stream>>>(Wf2, Wf2T, 1024, 256, 0, 1.0f);

  for (int l=0;l<2;++l){
    const float* xr = (l==0) ? x_in : x;   // residual source; x first written by att-GEMM l=0
    ln_kernel<<<2048,256,0,stream>>>(xr, ln1_g+l*256, ln1_b+l*256, hbf);
    gemm_mfma<256,768,0,64,64><<<dim3(12,32),256,0,stream>>>(
        hbf, WqkvT + (size_t)l*196608, nullptr, nullptr, qkvbf);
    rope_apply_bf<<<2048,256,0,stream>>>(qkvbf, sint, cost, qbf, kbf, vbf);
    rel_pre<<<513,256,0,stream>>>(coords, vel, relW1+l*320, relb1+l*64,
                                  relW2+l*512, Ah, A2h, W2Th, Wdh);
    rel_fused7<<<1024,256,0,stream>>>(coords, Ah, A2h, W2Th, Wdh,
                                      relb2+l*8, relbf);
    attn_mfma2<<<1024,256,0,stream>>>(qbf, kbf, vbf, relbf, attbf);
    gemm_mfma<256,256,1,32,32><<<dim3(8,64),256,0,stream>>>(
        attbf, WoutT + (size_t)l*65536, bout+l*256, xr, x);
    ln_kernel<<<2048,256,0,stream>>>(x, ln2_g+l*256, ln2_b+l*256, hbf);
    gemm_mfma<256,1024,2,64,64><<<dim3(16,32),256,0,stream>>>(
        hbf, Wf1T + (size_t)l*262144, bf1+l*1024, nullptr, midbf);
    gemm_mfma<1024,256,1,32,32><<<dim3(8,64),256,0,stream>>>(
        midbf, Wf2T + (size_t)l*262144, bf2+l*256, x, x);
  }
}

// Round 17
// 201.289 us; speedup vs baseline: 1.1701x; 1.0056x over previous
//
#include <hip/hip_runtime.h>
#include <math.h>

#define BN_ 2
#define NN 1024
#define DDIM 256
#define HH 8
#define HDIM 32
#define FFD 1024
#define EPSV 1e-5f
#define SCALEV 0.17677669529663687f

typedef __attribute__((ext_vector_type(8))) short s16x8;
typedef __attribute__((ext_vector_type(4))) short s16x4;
typedef __attribute__((ext_vector_type(4))) float f32x4;
typedef __attribute__((ext_vector_type(2))) _Float16 h2;
typedef __attribute__((ext_vector_type(8))) _Float16 f16x8;

__device__ __forceinline__ float gelu_f(float x){
  return 0.5f*x*(1.0f+erff(x*0.70710678118654752f));
}
__device__ __forceinline__ unsigned int pack_bf16(float lo, float hi){
  unsigned int ul = __float_as_uint(lo), uh = __float_as_uint(hi);
  ul += 0x7fff + ((ul>>16)&1);
  uh += 0x7fff + ((uh>>16)&1);
  return (ul>>16) | (uh & 0xffff0000u);
}
__device__ __forceinline__ unsigned short f2bf(float x){
  unsigned int u = __float_as_uint(x);
  u += 0x7fff + ((u>>16)&1);
  return (unsigned short)(u>>16);
}
__device__ __forceinline__ float bf2f(unsigned short u){
  return __uint_as_float(((unsigned int)u)<<16);
}
__device__ __forceinline__ unsigned int packtr(float lo, float hi){
  return __builtin_amdgcn_perm(__float_as_uint(hi), __float_as_uint(lo), 0x07060302u);
}
__device__ __forceinline__ f32x4 mfma16(s16x8 a, s16x8 b, f32x4 c){
  return __builtin_amdgcn_mfma_f32_16x16x32_bf16(a,b,c,0,0,0);
}
__device__ __forceinline__ f32x4 mfma16h(f16x8 a, f16x8 b, f32x4 c){
  return __builtin_amdgcn_mfma_f32_16x16x32_f16(a,b,c,0,0,0);
}

// ---------------- LayerNorm: f32 in, bf16 out --------------------------------
__global__ __launch_bounds__(256) void ln_kernel(const float* __restrict__ x,
    const float* __restrict__ g, const float* __restrict__ b,
    unsigned short* __restrict__ out){
  int row = blockIdx.x, tid = threadIdx.x;
  float val = x[(size_t)row*DDIM + tid];
  float s = val;
  #pragma unroll
  for (int o=32;o;o>>=1) s += __shfl_xor(s,o);
  __shared__ float sb[4], sb2[4];
  if ((tid&63)==0) sb[tid>>6]=s;
  __syncthreads();
  float mean = (sb[0]+sb[1]+sb[2]+sb[3]) * (1.0f/DDIM);
  float d = val-mean;
  float vs = d*d;
  #pragma unroll
  for (int o=32;o;o>>=1) vs += __shfl_xor(vs,o);
  if ((tid&63)==0) sb2[tid>>6]=vs;
  __syncthreads();
  float var = (sb2[0]+sb2[1]+sb2[2]+sb2[3]) * (1.0f/DDIM);
  out[(size_t)row*DDIM + tid] = f2bf(d*rsqrtf(var+EPSV)*g[tid]+b[tid]);
}

// ---------------- RoPE tables -------------------------------------------------
__global__ __launch_bounds__(256) void rope_table(float* __restrict__ sint, float* __restrict__ cost){
  int idx = blockIdx.x*256+threadIdx.x;   // 16384
  int i = idx >> 4, d = idx & 15;
  float freq = (float)i * powf(10000.0f, -(float)d/16.0f);
  sint[idx]=sinf(freq); cost[idx]=cosf(freq);
}

// ---------------- weight convert+transpose f32(K,NC) -> bf16 WT(NC,K) --------
__global__ __launch_bounds__(256) void wt_convert(const float* __restrict__ in,
    unsigned short* __restrict__ out, int K, int NC, int scaleCols, float scaleVal){
  __shared__ float tile[32][33];
  int tn0 = blockIdx.x*32;
  int tk0 = blockIdx.y*32;
  size_t loff = (size_t)blockIdx.z * K * NC;
  int t = threadIdx.x;
  int col = t & 31, rr = t >> 5;
  #pragma unroll
  for (int i=0;i<4;++i){
    int row = rr + i*8;
    tile[row][col] = in[loff + (size_t)(tk0+row)*NC + tn0+col];
  }
  __syncthreads();
  #pragma unroll
  for (int i=0;i<4;++i){
    int row = rr + i*8;
    int n = tn0 + row;
    float s = (n < scaleCols) ? scaleVal : 1.0f;
    out[loff + (size_t)n*K + tk0 + col] = f2bf(tile[col][row]*s);
  }
}

// ------------- split qkv + rope (bf16 in/out) --------------------------------
__global__ __launch_bounds__(256) void rope_apply_bf(const unsigned short* __restrict__ qkv,
    const float* __restrict__ sint, const float* __restrict__ cost,
    unsigned short* __restrict__ q, unsigned short* __restrict__ k,
    unsigned short* __restrict__ v){
  int row = blockIdx.x;                 // b*1024 + i
  int b = row>>10, i = row&1023;
  int tid = threadIdx.x; int h = tid>>5, d = tid&31;
  const unsigned short* base = qkv + (size_t)row*768;
  size_t oidx = (((size_t)((b<<3)+h)<<10) + i)*32 + d;
  v[oidx] = base[512 + h*32 + d];
  int dd = (d<16) ? d : d-16;
  float s = sint[i*16+dd], c = cost[i*16+dd];
  float q1 = bf2f(base[h*32+dd]), q2 = bf2f(base[h*32+dd+16]);
  q[oidx] = f2bf((d<16) ? (q1*c - q2*s) : (q2*c + q1*s));
  float k1 = bf2f(base[256+h*32+dd]), k2 = bf2f(base[256+h*32+dd+16]);
  k[oidx] = f2bf((d<16) ? (k1*c - k2*s) : (k2*c + k1*s));
}

// ------------- rel precompute: per-node separable parts (fp16) + W2T (f16) ---
__global__ __launch_bounds__(256) void rel_pre(const float* __restrict__ coords,
    const float* __restrict__ vel, const float* __restrict__ W1,
    const float* __restrict__ b1, const float* __restrict__ W2,
    _Float16* __restrict__ A, _Float16* __restrict__ A2,
    _Float16* __restrict__ W2T, _Float16* __restrict__ Wd){
  if (blockIdx.x == 512){
    int t = threadIdx.x;
    #pragma unroll
    for (int e=0;e<4;++e){
      int idx = t*4+e;              // n*64 + k
      int n = idx>>6, kk = idx&63;
      W2T[idx] = (n<8) ? (_Float16)W2[kk*8+n] : (_Float16)0.f;
    }
    if (t < 64) Wd[t] = (_Float16)W1[128+t];
    return;
  }
  int gid = blockIdx.x*256 + threadIdx.x;  // 2048*64
  int node = gid >> 6, r = gid & 63;
  float c0 = coords[node*2], c1 = coords[node*2+1];
  float v0 = vel[node*2],    v1 = vel[node*2+1];
  float bv = c0*W1[r] + c1*W1[64+r] + v0*W1[192+r] + v1*W1[256+r];
  A[gid] = (_Float16)(b1[r] + bv);
  A2[gid] = (_Float16)bv;
}

// ------------- rel fused v9: 2 i's per block, j-half split, packed-f16 -------
// Grid 2048 = b(2) x ipair(512) x jhalf(2): 8 blocks/CU for latency cover.
// Wave w covers j in [jh*512 + w*128, +128) as 8 subtiles of 16.
// Lane l: j = j0+(l&15), r in {lg*8..+7, 32+lg*8..+7}. No LDS/barriers.
__global__ __launch_bounds__(256, 4) void rel_fused9(const float* __restrict__ coords,
    const _Float16* __restrict__ A, const _Float16* __restrict__ A2,
    const _Float16* __restrict__ W2T, const _Float16* __restrict__ Wd,
    const float* __restrict__ b2, unsigned short* __restrict__ relbf){
  const int tid = threadIdx.x;
  const int bid = blockIdx.x;            // 2048
  const int b  = bid >> 10;
  const int ia = ((bid >> 1) & 511) * 2; // rows ia, ia+1
  const int jh = bid & 1;
  const int w = tid>>6, l = tid&63, lc = l&15, lg = l>>4;
  const int nodea = (b<<10) + ia;
  float2 cia = *(const float2*)(coords + (size_t)nodea*2);
  float2 cib = *(const float2*)(coords + (size_t)nodea*2 + 2);

  union u4h { uint4 u; h2 h[4]; };
  u4h aA, aB, bA, bB, wA, wB;
  aA.u = *(const uint4*)(A + (size_t)nodea*64 + lg*8);
  aB.u = *(const uint4*)(A + (size_t)nodea*64 + 32 + lg*8);
  bA.u = *(const uint4*)(A + (size_t)(nodea+1)*64 + lg*8);
  bB.u = *(const uint4*)(A + (size_t)(nodea+1)*64 + 32 + lg*8);
  wA.u = *(const uint4*)(Wd + lg*8);
  wB.u = *(const uint4*)(Wd + 32 + lg*8);

  const f16x8 bf0 = *(const f16x8*)&W2T[lc*64 + lg*8];
  const f16x8 bf1 = *(const f16x8*)&W2T[lc*64 + 32 + lg*8];
  const float b2v = (lc<8) ? b2[lc] : 0.f;

  const h2 c2 = {(_Float16)0.0099735570f, (_Float16)0.0099735570f};
  const h2 c1 = {(_Float16)-0.0664904395f, (_Float16)-0.0664904395f};
  const h2 c0 = {(_Float16)0.3989422804f, (_Float16)0.3989422804f};
  const h2 ch = {(_Float16)0.5f, (_Float16)0.5f};

  const int jbase = jh*512 + w*128;
  const float* cb = coords + (size_t)((b<<10) + jbase + lc)*2;
  const _Float16* ab = A2 + (size_t)((b<<10) + jbase + lc)*64 + lg*8;
  unsigned short* oba = relbf + ((size_t)b<<23) + ((size_t)ia<<10)
                      + ((size_t)(lc&7)<<20) + (unsigned)(jbase + lg*4);

  for (int st=0; st<8; ++st){
    u4h t0, t1;
    t0.u = *(const uint4*)(ab + st*1024);
    t1.u = *(const uint4*)(ab + st*1024 + 32);
    float2 cj = *(const float2*)(cb + st*32);
    // ---- i_a ----
    {
      float dx = cia.x-cj.x, dy = cia.y-cj.y;
      _Float16 dh = (_Float16)sqrtf(fmaf(dx,dx,dy*dy));
      h2 d2 = {dh, dh};
      union { h2 h[4]; f16x8 v; } g0, g1;
      #pragma unroll
      for (int e=0;e<4;++e){
        h2 t = (aA.h[e] - t0.h[e]) + d2*wA.h[e];
        h2 u = t*t;
        h2 p = u*c2 + c1;
        p = u*p + c0;
        g0.h[e] = u*p + ch*t;
        h2 s = (aB.h[e] - t1.h[e]) + d2*wB.h[e];
        h2 v = s*s;
        h2 q = v*c2 + c1;
        q = v*q + c0;
        g1.h[e] = v*q + ch*s;
      }
      f32x4 z; z[0]=0.f; z[1]=0.f; z[2]=0.f; z[3]=0.f;
      z = mfma16h(g0.v, bf0, z);
      z = mfma16h(g1.v, bf1, z);
      if (lc < 8){
        unsigned short* op = oba + st*16;
        *(unsigned int*)op     = pack_bf16(z[0]+b2v, z[1]+b2v);
        *(unsigned int*)(op+2) = pack_bf16(z[2]+b2v, z[3]+b2v);
      }
    }
    // ---- i_b (same t0/t1/cj loads) ----
    {
      float dx = cib.x-cj.x, dy = cib.y-cj.y;
      _Float16 dh = (_Float16)sqrtf(fmaf(dx,dx,dy*dy));
      h2 d2 = {dh, dh};
      union { h2 h[4]; f16x8 v; } g0, g1;
      #pragma unroll
      for (int e=0;e<4;++e){
        h2 t = (bA.h[e] - t0.h[e]) + d2*wA.h[e];
        h2 u = t*t;
        h2 p = u*c2 + c1;
        p = u*p + c0;
        g0.h[e] = u*p + ch*t;
        h2 s = (bB.h[e] - t1.h[e]) + d2*wB.h[e];
        h2 v = s*s;
        h2 q = v*c2 + c1;
        q = v*q + c0;
        g1.h[e] = v*q + ch*s;
      }
      f32x4 z; z[0]=0.f; z[1]=0.f; z[2]=0.f; z[3]=0.f;
      z = mfma16h(g0.v, bf0, z);
      z = mfma16h(g1.v, bf1, z);
      if (lc < 8){
        unsigned short* op = oba + 1024 + st*16;
        *(unsigned int*)op     = pack_bf16(z[0]+b2v, z[1]+b2v);
        *(unsigned int*)(op+2) = pack_bf16(z[2]+b2v, z[3]+b2v);
      }
    }
  }
}

// ------------- attn v2: swapped-operand MFMA flash, per-lane softmax state ---
__global__ __launch_bounds__(256) void attn_mfma2(
    const unsigned short* __restrict__ q, const unsigned short* __restrict__ kk,
    const unsigned short* __restrict__ vv, const unsigned short* __restrict__ relbf,
    unsigned short* __restrict__ out){
  int bh = blockIdx.x >> 6;
  int i0 = (blockIdx.x & 63) * 16;
  int tid = threadIdx.x;
  int w = tid>>6, l = tid&63, lc = l&15, lg = l>>4;

  __shared__ __align__(16) float accL[4][2][16][17];
  __shared__ float mL[4][16];
  __shared__ float lL[4][16];

  const unsigned short* qb = q + ((size_t)(bh<<10) + i0)*32;
  const unsigned short* kb = kk + ((size_t)bh<<15);
  const unsigned short* vb = vv + ((size_t)bh<<15);
  const unsigned short* relrow = relbf + ((size_t)bh<<20) + ((size_t)(i0+lc)<<10);

  s16x8 qf = *(const s16x8*)(qb + (size_t)lc*32 + lg*8);

  float m = -1e30f, lsum = 0.f;
  f32x4 acc0, acc1;
  acc0[0]=0.f; acc0[1]=0.f; acc0[2]=0.f; acc0[3]=0.f;
  acc1 = acc0;

  for (int t=0; t<16; ++t){
    const int jt = w*256 + t*16;
    s16x8 kf = *(const s16x8*)(kb + (size_t)(jt+lc)*32 + lg*8);
    f32x4 z; z[0]=0.f; z[1]=0.f; z[2]=0.f; z[3]=0.f;
    f32x4 s = mfma16(kf, qf, z);     // S^T[j=jt+lg*4+r][i=i0+lc]
    ushort4 rl = *(const ushort4*)(relrow + jt + lg*4);
    s[0] += bf2f(rl.x); s[1] += bf2f(rl.y);
    s[2] += bf2f(rl.z); s[3] += bf2f(rl.w);
    float mx = fmaxf(fmaxf(s[0],s[1]), fmaxf(s[2],s[3]));
    mx = fmaxf(mx, __shfl_xor(mx,16));
    mx = fmaxf(mx, __shfl_xor(mx,32));
    float mn = fmaxf(m, mx);
    float scale = __expf(m - mn);
    m = mn;
    float p0 = __expf(s[0]-mn), p1 = __expf(s[1]-mn);
    float p2 = __expf(s[2]-mn), p3 = __expf(s[3]-mn);
    lsum = lsum*scale + (p0+p1+p2+p3);
    acc0[0]*=scale; acc0[1]*=scale; acc0[2]*=scale; acc0[3]*=scale;
    acc1[0]*=scale; acc1[1]*=scale; acc1[2]*=scale; acc1[3]*=scale;
#if __has_builtin(__builtin_amdgcn_mfma_f32_16x16x16bf16_1k)
    union { unsigned int u[2]; s16x4 v; } pu;
    pu.u[0] = packtr(p0,p1); pu.u[1] = packtr(p2,p3);
    const unsigned short* vp = vb + (size_t)(jt + lg*4)*32 + lc;
    s16x4 vf0, vf1;
    vf0[0]=(short)vp[0];  vf0[1]=(short)vp[32];  vf0[2]=(short)vp[64];  vf0[3]=(short)vp[96];
    vf1[0]=(short)vp[16]; vf1[1]=(short)vp[48];  vf1[2]=(short)vp[80];  vf1[3]=(short)vp[112];
    acc0 = __builtin_amdgcn_mfma_f32_16x16x16bf16_1k(vf0, pu.v, acc0, 0,0,0);
    acc1 = __builtin_amdgcn_mfma_f32_16x16x16bf16_1k(vf1, pu.v, acc1, 0,0,0);
#else
    unsigned int dw0 = packtr(p0,p1), dw1 = packtr(p2,p3);
    int src0 = lc + (((lg*2)&3)<<4);
    int src1 = lc + (((lg*2+1)&3)<<4);
    unsigned int u0 = __shfl(dw0, src0), u1 = __shfl(dw1, src0);
    unsigned int u2 = __shfl(dw0, src1), u3 = __shfl(dw1, src1);
    if (lg >= 2){ u0=0; u1=0; u2=0; u3=0; }
    union { unsigned int u[4]; s16x8 v; } pb;
    pb.u[0]=u0; pb.u[1]=u1; pb.u[2]=u2; pb.u[3]=u3;
    s16x8 vf0, vf1;
    #pragma unroll
    for (int e=0;e<8;++e){
      int j = (jt + lg*8 + e) & 1023;
      vf0[e] = (short)vb[(size_t)j*32 + lc];
      vf1[e] = (short)vb[(size_t)j*32 + 16 + lc];
    }
    acc0 = mfma16(vf0, pb.v, acc0);
    acc1 = mfma16(vf1, pb.v, acc1);
#endif
  }
  lsum += __shfl_xor(lsum, 16);
  lsum += __shfl_xor(lsum, 32);
  if (lg == 0){ mL[w][lc] = m; lL[w][lc] = lsum; }
  #pragma unroll
  for (int r=0;r<4;++r){
    accL[w][0][lg*4+r][lc] = acc0[r];
    accL[w][1][lg*4+r][lc] = acc1[r];
  }
  __syncthreads();
  int ii = tid & 15, dd = tid >> 4;
  float m0 = mL[0][ii], m1 = mL[1][ii], m2 = mL[2][ii], m3 = mL[3][ii];
  float ms = fmaxf(fmaxf(m0,m1), fmaxf(m2,m3));
  float e0 = __expf(m0-ms), e1 = __expf(m1-ms), e2 = __expf(m2-ms), e3 = __expf(m3-ms);
  float lt = lL[0][ii]*e0 + lL[1][ii]*e1 + lL[2][ii]*e2 + lL[3][ii]*e3;
  float a0 = accL[0][0][dd][ii]*e0 + accL[1][0][dd][ii]*e1
           + accL[2][0][dd][ii]*e2 + accL[3][0][dd][ii]*e3;
  float a1 = accL[0][1][dd][ii]*e0 + accL[1][1][dd][ii]*e1
           + accL[2][1][dd][ii]*e2 + accL[3][1][dd][ii]*e3;
  float inv = 1.0f/lt;
  int b = bh>>3, hh = bh&7;
  size_t ob2 = ((size_t)((b<<10)+i0+ii))*256 + hh*32;
  out[ob2 + dd]      = f2bf(a0*inv);
  out[ob2 + 16 + dd] = f2bf(a1*inv);
}

// ------------- MFMA GEMM: C[M,NC] = A[M,K] @ W[K,NC], A bf16, WT bf16(NC,K) --
template<int K, int NC, int EPI, int BM, int BNt>
__global__ __launch_bounds__(256) void gemm_mfma(
    const unsigned short* __restrict__ Aa, const unsigned short* __restrict__ WT,
    const float* __restrict__ bias, const float* __restrict__ resid,
    void* __restrict__ outv){
  constexpr int WMm = BM/2, WNn = BNt/2;
  constexpr int FM = WMm/16, FN = WNn/16;
  constexpr int LP = 40;
  __shared__ __align__(16) unsigned short As[BM*LP];
  __shared__ __align__(16) unsigned short Bs[BNt*LP];
  const int tid = threadIdx.x;
  const int w = tid>>6, l = tid&63, lc = l&15, lg = l>>4;
  const int wm = w&1, wn = w>>1;
  const int n0 = blockIdx.x*BNt, m0 = blockIdx.y*BM;
  f32x4 acc[FM][FN];
  #pragma unroll
  for (int a=0;a<FM;++a)
    #pragma unroll
    for (int c=0;c<FN;++c){ acc[a][c][0]=0.f; acc[a][c][1]=0.f; acc[a][c][2]=0.f; acc[a][c][3]=0.f; }

  for (int k0=0; k0<K; k0+=32){
    __syncthreads();
    if constexpr (BM==64){
      int row = tid>>2, cg = tid&3;
      *(s16x8*)&As[row*LP+cg*8] = *(const s16x8*)&Aa[(size_t)(m0+row)*K + k0 + cg*8];
    } else {
      int row = tid>>3, cg = tid&7;
      *(ushort4*)&As[row*LP+cg*4] = *(const ushort4*)&Aa[(size_t)(m0+row)*K + k0 + cg*4];
    }
    if constexpr (BNt==64){
      int row = tid>>2, cg = tid&3;
      *(s16x8*)&Bs[row*LP+cg*8] = *(const s16x8*)&WT[(size_t)(n0+row)*K + k0 + cg*8];
    } else {
      int row = tid>>3, cg = tid&7;
      *(ushort4*)&Bs[row*LP+cg*4] = *(const ushort4*)&WT[(size_t)(n0+row)*K + k0 + cg*4];
    }
    __syncthreads();
    s16x8 af[FM], bv[FN];
    #pragma unroll
    for (int a=0;a<FM;++a) af[a] = *(const s16x8*)&As[(wm*WMm + a*16 + lc)*LP + lg*8];
    #pragma unroll
    for (int c=0;c<FN;++c) bv[c] = *(const s16x8*)&Bs[(wn*WNn + c*16 + lc)*LP + lg*8];
    #pragma unroll
    for (int a=0;a<FM;++a)
      #pragma unroll
      for (int c=0;c<FN;++c) acc[a][c] = mfma16(af[a], bv[c], acc[a][c]);
  }
  #pragma unroll
  for (int a=0;a<FM;++a){
    #pragma unroll
    for (int c=0;c<FN;++c){
      int n = n0 + wn*WNn + c*16 + lc;
      float bvv = (EPI!=0) ? bias[n] : 0.f;
      #pragma unroll
      for (int r=0;r<4;++r){
        int m = m0 + wm*WMm + a*16 + lg*4 + r;
        float vv = acc[a][c][r];
        if constexpr (EPI==0){
          ((unsigned short*)outv)[(size_t)m*NC + n] = f2bf(vv);
        } else if constexpr (EPI==1){
          ((float*)outv)[(size_t)m*NC + n] = vv + bvv + resid[(size_t)m*NC + n];
        } else {
          ((unsigned short*)outv)[(size_t)m*NC + n] = f2bf(gelu_f(vv + bvv));
        }
      }
    }
  }
}

extern "C" void kernel_launch(void* const* d_in, const int* in_sizes, int n_in,
                              void* d_out, int out_size, void* d_ws, size_t ws_size,
                              hipStream_t stream){
  const float* x_in  = (const float*)d_in[0];
  const float* coords= (const float*)d_in[1];
  const float* vel   = (const float*)d_in[2];
  const float* ln1_g = (const float*)d_in[3];
  const float* ln1_b = (const float*)d_in[4];
  const float* Wqkv  = (const float*)d_in[5];
  const float* relW1 = (const float*)d_in[6];
  const float* relb1 = (const float*)d_in[7];
  const float* relW2 = (const float*)d_in[8];
  const float* relb2 = (const float*)d_in[9];
  const float* Wout  = (const float*)d_in[10];
  const float* bout  = (const float*)d_in[11];
  const float* ln2_g = (const float*)d_in[12];
  const float* ln2_b = (const float*)d_in[13];
  const float* Wf1   = (const float*)d_in[14];
  const float* bf1   = (const float*)d_in[15];
  const float* Wf2   = (const float*)d_in[16];
  const float* bf2   = (const float*)d_in[17];

  float* x = (float*)d_out;
  unsigned short* us = (unsigned short*)d_ws;
  unsigned short* hbf   = us;                    // 524288
  unsigned short* qkvbf = hbf   + 524288;        // 1572864
  unsigned short* qbf   = qkvbf + 1572864;       // 524288
  unsigned short* kbf   = qbf   + 524288;        // 524288
  unsigned short* vbf   = kbf   + 524288;        // 524288
  unsigned short* attbf = vbf   + 524288;        // 524288
  unsigned short* midbf = attbf + 524288;        // 2097152
  unsigned short* relbf = midbf + 2097152;       // 16777216
  unsigned short* WqkvT = relbf + 16777216;      // 393216
  unsigned short* WoutT = WqkvT + 393216;        // 131072
  unsigned short* Wf1T  = WoutT + 131072;        // 524288
  unsigned short* Wf2T  = Wf1T  + 524288;        // 524288
  _Float16* W2Th = (_Float16*)(Wf2T + 524288);   // 1024
  _Float16* Wdh  = W2Th + 1024;                  // 64
  _Float16* Ah   = Wdh + 64;                     // 131072
  _Float16* A2h  = Ah + 131072;                  // 131072
  float* sint  = (float*)(A2h + 131072);         // 16384
  float* cost  = sint + 16384;                   // 16384

  rope_table<<<64,256,0,stream>>>(sint,cost);
  wt_convert<<<dim3(24,8,2),256,0,stream>>>(Wqkv, WqkvT, 256, 768, 256, SCALEV);
  wt_convert<<<dim3(8,8,2),256,0,stream>>>(Wout, WoutT, 256, 256, 0, 1.0f);
  wt_convert<<<dim3(32,8,2),256,0,stream>>>(Wf1, Wf1T, 256, 1024, 0, 1.0f);
  wt_convert<<<dim3(8,32,2),256,0,stream>>>(Wf2, Wf2T, 1024, 256, 0, 1.0f);

  for (int l=0;l<2;++l){
    const float* xr = (l==0) ? x_in : x;   // residual source; x first written by att-GEMM l=0
    ln_kernel<<<2048,256,0,stream>>>(xr, ln1_g+l*256, ln1_b+l*256, hbf);
    gemm_mfma<256,768,0,64,64><<<dim3(12,32),256,0,stream>>>(
        hbf, WqkvT + (size_t)l*196608, nullptr, nullptr, qkvbf);
    rope_apply_bf<<<2048,256,0,stream>>>(qkvbf, sint, cost, qbf, kbf, vbf);
    rel_pre<<<513,256,0,stream>>>(coords, vel, relW1+l*320, relb1+l*64,
                                  relW2+l*512, Ah, A2h, W2Th, Wdh);
    rel_fused9<<<2048,256,0,stream>>>(coords, Ah, A2h, W2Th, Wdh,
                                      relb2+l*8, relbf);
    attn_mfma2<<<1024,256,0,stream>>>(qbf, kbf, vbf, relbf, attbf);
    gemm_mfma<256,256,1,32,32><<<dim3(8,64),256,0,stream>>>(
        attbf, WoutT + (size_t)l*65536, bout+l*256, xr, x);
    ln_kernel<<<2048,256,0,stream>>>(x, ln2_g+l*256, ln2_b+l*256, hbf);
    gemm_mfma<256,1024,2,64,64><<<dim3(16,32),256,0,stream>>>(
        hbf, Wf1T + (size_t)l*262144, bf1+l*1024, nullptr, midbf);
    gemm_mfma<1024,256,1,32,32><<<dim3(8,64),256,0,stream>>>(
        midbf, Wf2T + (size_t)l*262144, bf2+l*256, x, x);
  }
}

// Round 18
// 200.923 us; speedup vs baseline: 1.1723x; 1.0018x over previous
//
#include <hip/hip_runtime.h>
#include <math.h>

#define BN_ 2
#define NN 1024
#define DDIM 256
#define HH 8
#define HDIM 32
#define FFD 1024
#define EPSV 1e-5f
#define SCALEV 0.17677669529663687f

typedef __attribute__((ext_vector_type(8))) short s16x8;
typedef __attribute__((ext_vector_type(4))) short s16x4;
typedef __attribute__((ext_vector_type(4))) float f32x4;
typedef __attribute__((ext_vector_type(2))) _Float16 h2;
typedef __attribute__((ext_vector_type(8))) _Float16 f16x8;

__device__ __forceinline__ float gelu_f(float x){
  return 0.5f*x*(1.0f+erff(x*0.70710678118654752f));
}
__device__ __forceinline__ unsigned int pack_bf16(float lo, float hi){
  unsigned int ul = __float_as_uint(lo), uh = __float_as_uint(hi);
  ul += 0x7fff + ((ul>>16)&1);
  uh += 0x7fff + ((uh>>16)&1);
  return (ul>>16) | (uh & 0xffff0000u);
}
__device__ __forceinline__ unsigned short f2bf(float x){
  unsigned int u = __float_as_uint(x);
  u += 0x7fff + ((u>>16)&1);
  return (unsigned short)(u>>16);
}
__device__ __forceinline__ float bf2f(unsigned short u){
  return __uint_as_float(((unsigned int)u)<<16);
}
__device__ __forceinline__ unsigned int packtr(float lo, float hi){
  return __builtin_amdgcn_perm(__float_as_uint(hi), __float_as_uint(lo), 0x07060302u);
}
__device__ __forceinline__ f32x4 mfma16(s16x8 a, s16x8 b, f32x4 c){
  return __builtin_amdgcn_mfma_f32_16x16x32_bf16(a,b,c,0,0,0);
}
__device__ __forceinline__ f32x4 mfma16h(f16x8 a, f16x8 b, f32x4 c){
  return __builtin_amdgcn_mfma_f32_16x16x32_f16(a,b,c,0,0,0);
}

// ---------------- LayerNorm: f32 in, bf16 out --------------------------------
__global__ __launch_bounds__(256) void ln_kernel(const float* __restrict__ x,
    const float* __restrict__ g, const float* __restrict__ b,
    unsigned short* __restrict__ out){
  int row = blockIdx.x, tid = threadIdx.x;
  float val = x[(size_t)row*DDIM + tid];
  float s = val;
  #pragma unroll
  for (int o=32;o;o>>=1) s += __shfl_xor(s,o);
  __shared__ float sb[4], sb2[4];
  if ((tid&63)==0) sb[tid>>6]=s;
  __syncthreads();
  float mean = (sb[0]+sb[1]+sb[2]+sb[3]) * (1.0f/DDIM);
  float d = val-mean;
  float vs = d*d;
  #pragma unroll
  for (int o=32;o;o>>=1) vs += __shfl_xor(vs,o);
  if ((tid&63)==0) sb2[tid>>6]=vs;
  __syncthreads();
  float var = (sb2[0]+sb2[1]+sb2[2]+sb2[3]) * (1.0f/DDIM);
  out[(size_t)row*DDIM + tid] = f2bf(d*rsqrtf(var+EPSV)*g[tid]+b[tid]);
}

// ---------------- RoPE tables -------------------------------------------------
__global__ __launch_bounds__(256) void rope_table(float* __restrict__ sint, float* __restrict__ cost){
  int idx = blockIdx.x*256+threadIdx.x;   // 16384
  int i = idx >> 4, d = idx & 15;
  float freq = (float)i * powf(10000.0f, -(float)d/16.0f);
  sint[idx]=sinf(freq); cost[idx]=cosf(freq);
}

// ---------------- weight convert+transpose f32(K,NC) -> bf16 WT(NC,K) --------
__global__ __launch_bounds__(256) void wt_convert(const float* __restrict__ in,
    unsigned short* __restrict__ out, int K, int NC, int scaleCols, float scaleVal){
  __shared__ float tile[32][33];
  int tn0 = blockIdx.x*32;
  int tk0 = blockIdx.y*32;
  size_t loff = (size_t)blockIdx.z * K * NC;
  int t = threadIdx.x;
  int col = t & 31, rr = t >> 5;
  #pragma unroll
  for (int i=0;i<4;++i){
    int row = rr + i*8;
    tile[row][col] = in[loff + (size_t)(tk0+row)*NC + tn0+col];
  }
  __syncthreads();
  #pragma unroll
  for (int i=0;i<4;++i){
    int row = rr + i*8;
    int n = tn0 + row;
    float s = (n < scaleCols) ? scaleVal : 1.0f;
    out[loff + (size_t)n*K + tk0 + col] = f2bf(tile[col][row]*s);
  }
}

// ------------- split qkv + rope (bf16 in/out) --------------------------------
__global__ __launch_bounds__(256) void rope_apply_bf(const unsigned short* __restrict__ qkv,
    const float* __restrict__ sint, const float* __restrict__ cost,
    unsigned short* __restrict__ q, unsigned short* __restrict__ k,
    unsigned short* __restrict__ v){
  int row = blockIdx.x;                 // b*1024 + i
  int b = row>>10, i = row&1023;
  int tid = threadIdx.x; int h = tid>>5, d = tid&31;
  const unsigned short* base = qkv + (size_t)row*768;
  size_t oidx = (((size_t)((b<<3)+h)<<10) + i)*32 + d;
  v[oidx] = base[512 + h*32 + d];
  int dd = (d<16) ? d : d-16;
  float s = sint[i*16+dd], c = cost[i*16+dd];
  float q1 = bf2f(base[h*32+dd]), q2 = bf2f(base[h*32+dd+16]);
  q[oidx] = f2bf((d<16) ? (q1*c - q2*s) : (q2*c + q1*s));
  float k1 = bf2f(base[256+h*32+dd]), k2 = bf2f(base[256+h*32+dd+16]);
  k[oidx] = f2bf((d<16) ? (k1*c - k2*s) : (k2*c + k1*s));
}

// ------------- rel precompute: per-node separable parts (fp16) + W2T (f16) ---
__global__ __launch_bounds__(256) void rel_pre(const float* __restrict__ coords,
    const float* __restrict__ vel, const float* __restrict__ W1,
    const float* __restrict__ b1, const float* __restrict__ W2,
    _Float16* __restrict__ A, _Float16* __restrict__ A2,
    _Float16* __restrict__ W2T, _Float16* __restrict__ Wd){
  if (blockIdx.x == 512){
    int t = threadIdx.x;
    #pragma unroll
    for (int e=0;e<4;++e){
      int idx = t*4+e;              // n*64 + k
      int n = idx>>6, kk = idx&63;
      W2T[idx] = (n<8) ? (_Float16)W2[kk*8+n] : (_Float16)0.f;
    }
    if (t < 64) Wd[t] = (_Float16)W1[128+t];
    return;
  }
  int gid = blockIdx.x*256 + threadIdx.x;  // 2048*64
  int node = gid >> 6, r = gid & 63;
  float c0 = coords[node*2], c1 = coords[node*2+1];
  float v0 = vel[node*2],    v1 = vel[node*2+1];
  float bv = c0*W1[r] + c1*W1[64+r] + v0*W1[192+r] + v1*W1[256+r];
  A[gid] = (_Float16)(b1[r] + bv);
  A2[gid] = (_Float16)bv;
}

// ------------- rel fused v9: 2 i's per block, j-half split, packed-f16 -------
__global__ __launch_bounds__(256, 4) void rel_fused9(const float* __restrict__ coords,
    const _Float16* __restrict__ A, const _Float16* __restrict__ A2,
    const _Float16* __restrict__ W2T, const _Float16* __restrict__ Wd,
    const float* __restrict__ b2, unsigned short* __restrict__ relbf){
  const int tid = threadIdx.x;
  const int bid = blockIdx.x;            // 2048
  const int b  = bid >> 10;
  const int ia = ((bid >> 1) & 511) * 2; // rows ia, ia+1
  const int jh = bid & 1;
  const int w = tid>>6, l = tid&63, lc = l&15, lg = l>>4;
  const int nodea = (b<<10) + ia;
  float2 cia = *(const float2*)(coords + (size_t)nodea*2);
  float2 cib = *(const float2*)(coords + (size_t)nodea*2 + 2);

  union u4h { uint4 u; h2 h[4]; };
  u4h aA, aB, bA, bB, wA, wB;
  aA.u = *(const uint4*)(A + (size_t)nodea*64 + lg*8);
  aB.u = *(const uint4*)(A + (size_t)nodea*64 + 32 + lg*8);
  bA.u = *(const uint4*)(A + (size_t)(nodea+1)*64 + lg*8);
  bB.u = *(const uint4*)(A + (size_t)(nodea+1)*64 + 32 + lg*8);
  wA.u = *(const uint4*)(Wd + lg*8);
  wB.u = *(const uint4*)(Wd + 32 + lg*8);

  const f16x8 bf0 = *(const f16x8*)&W2T[lc*64 + lg*8];
  const f16x8 bf1 = *(const f16x8*)&W2T[lc*64 + 32 + lg*8];
  const float b2v = (lc<8) ? b2[lc] : 0.f;

  const h2 c2 = {(_Float16)0.0099735570f, (_Float16)0.0099735570f};
  const h2 c1 = {(_Float16)-0.0664904395f, (_Float16)-0.0664904395f};
  const h2 c0 = {(_Float16)0.3989422804f, (_Float16)0.3989422804f};
  const h2 ch = {(_Float16)0.5f, (_Float16)0.5f};

  const int jbase = jh*512 + w*128;
  const float* cb = coords + (size_t)((b<<10) + jbase + lc)*2;
  const _Float16* ab = A2 + (size_t)((b<<10) + jbase + lc)*64 + lg*8;
  unsigned short* oba = relbf + ((size_t)b<<23) + ((size_t)ia<<10)
                      + ((size_t)(lc&7)<<20) + (unsigned)(jbase + lg*4);

  for (int st=0; st<8; ++st){
    u4h t0, t1;
    t0.u = *(const uint4*)(ab + st*1024);
    t1.u = *(const uint4*)(ab + st*1024 + 32);
    float2 cj = *(const float2*)(cb + st*32);
    // ---- i_a ----
    {
      float dx = cia.x-cj.x, dy = cia.y-cj.y;
      _Float16 dh = (_Float16)sqrtf(fmaf(dx,dx,dy*dy));
      h2 d2 = {dh, dh};
      union { h2 h[4]; f16x8 v; } g0, g1;
      #pragma unroll
      for (int e=0;e<4;++e){
        h2 t = (aA.h[e] - t0.h[e]) + d2*wA.h[e];
        h2 u = t*t;
        h2 p = u*c2 + c1;
        p = u*p + c0;
        g0.h[e] = u*p + ch*t;
        h2 s = (aB.h[e] - t1.h[e]) + d2*wB.h[e];
        h2 v = s*s;
        h2 q = v*c2 + c1;
        q = v*q + c0;
        g1.h[e] = v*q + ch*s;
      }
      f32x4 z; z[0]=0.f; z[1]=0.f; z[2]=0.f; z[3]=0.f;
      z = mfma16h(g0.v, bf0, z);
      z = mfma16h(g1.v, bf1, z);
      if (lc < 8){
        unsigned short* op = oba + st*16;
        *(unsigned int*)op     = pack_bf16(z[0]+b2v, z[1]+b2v);
        *(unsigned int*)(op+2) = pack_bf16(z[2]+b2v, z[3]+b2v);
      }
    }
    // ---- i_b (same t0/t1/cj loads) ----
    {
      float dx = cib.x-cj.x, dy = cib.y-cj.y;
      _Float16 dh = (_Float16)sqrtf(fmaf(dx,dx,dy*dy));
      h2 d2 = {dh, dh};
      union { h2 h[4]; f16x8 v; } g0, g1;
      #pragma unroll
      for (int e=0;e<4;++e){
        h2 t = (bA.h[e] - t0.h[e]) + d2*wA.h[e];
        h2 u = t*t;
        h2 p = u*c2 + c1;
        p = u*p + c0;
        g0.h[e] = u*p + ch*t;
        h2 s = (bB.h[e] - t1.h[e]) + d2*wB.h[e];
        h2 v = s*s;
        h2 q = v*c2 + c1;
        q = v*q + c0;
        g1.h[e] = v*q + ch*s;
      }
      f32x4 z; z[0]=0.f; z[1]=0.f; z[2]=0.f; z[3]=0.f;
      z = mfma16h(g0.v, bf0, z);
      z = mfma16h(g1.v, bf1, z);
      if (lc < 8){
        unsigned short* op = oba + 1024 + st*16;
        *(unsigned int*)op     = pack_bf16(z[0]+b2v, z[1]+b2v);
        *(unsigned int*)(op+2) = pack_bf16(z[2]+b2v, z[3]+b2v);
      }
    }
  }
}

// ------------- attn v4: swapped-operand MFMA flash, 32-j tiles ----------------
// Halves softmax/rescale overhead per j vs v2 (one online-update per 32 j).
__global__ __launch_bounds__(256) void attn_mfma4(
    const unsigned short* __restrict__ q, const unsigned short* __restrict__ kk,
    const unsigned short* __restrict__ vv, const unsigned short* __restrict__ relbf,
    unsigned short* __restrict__ out){
  int bh = blockIdx.x >> 6;
  int i0 = (blockIdx.x & 63) * 16;
  int tid = threadIdx.x;
  int w = tid>>6, l = tid&63, lc = l&15, lg = l>>4;

  __shared__ __align__(16) float accL[4][2][16][17];
  __shared__ float mL[4][16];
  __shared__ float lL[4][16];

  const unsigned short* qb = q + ((size_t)(bh<<10) + i0)*32;
  const unsigned short* kb = kk + ((size_t)bh<<15);
  const unsigned short* vb = vv + ((size_t)bh<<15);
  const unsigned short* relrow = relbf + ((size_t)bh<<20) + ((size_t)(i0+lc)<<10);

  s16x8 qf = *(const s16x8*)(qb + (size_t)lc*32 + lg*8);

  float m = -1e30f, lsum = 0.f;
  f32x4 acc0, acc1;
  acc0[0]=0.f; acc0[1]=0.f; acc0[2]=0.f; acc0[3]=0.f;
  acc1 = acc0;

  for (int t=0; t<8; ++t){
    const int jt = w*256 + t*32;
    s16x8 kf0 = *(const s16x8*)(kb + (size_t)(jt+lc)*32 + lg*8);
    s16x8 kf1 = *(const s16x8*)(kb + (size_t)(jt+16+lc)*32 + lg*8);
    f32x4 z; z[0]=0.f; z[1]=0.f; z[2]=0.f; z[3]=0.f;
    f32x4 s0 = mfma16(kf0, qf, z);   // S^T[j=jt+lg*4+r][i=i0+lc]
    f32x4 s1 = mfma16(kf1, qf, z);   // S^T[j=jt+16+lg*4+r][i]
    ushort4 rl0 = *(const ushort4*)(relrow + jt + lg*4);
    ushort4 rl1 = *(const ushort4*)(relrow + jt + 16 + lg*4);
    s0[0] += bf2f(rl0.x); s0[1] += bf2f(rl0.y);
    s0[2] += bf2f(rl0.z); s0[3] += bf2f(rl0.w);
    s1[0] += bf2f(rl1.x); s1[1] += bf2f(rl1.y);
    s1[2] += bf2f(rl1.z); s1[3] += bf2f(rl1.w);
    float mx = fmaxf(fmaxf(fmaxf(s0[0],s0[1]), fmaxf(s0[2],s0[3])),
                     fmaxf(fmaxf(s1[0],s1[1]), fmaxf(s1[2],s1[3])));
    mx = fmaxf(mx, __shfl_xor(mx,16));
    mx = fmaxf(mx, __shfl_xor(mx,32));
    float mn = fmaxf(m, mx);
    float scale = __expf(m - mn);
    m = mn;
    float p0 = __expf(s0[0]-mn), p1 = __expf(s0[1]-mn);
    float p2 = __expf(s0[2]-mn), p3 = __expf(s0[3]-mn);
    float p4 = __expf(s1[0]-mn), p5 = __expf(s1[1]-mn);
    float p6 = __expf(s1[2]-mn), p7 = __expf(s1[3]-mn);
    lsum = lsum*scale + ((p0+p1)+(p2+p3)) + ((p4+p5)+(p6+p7));
    acc0[0]*=scale; acc0[1]*=scale; acc0[2]*=scale; acc0[3]*=scale;
    acc1[0]*=scale; acc1[1]*=scale; acc1[2]*=scale; acc1[3]*=scale;
#if __has_builtin(__builtin_amdgcn_mfma_f32_16x16x16bf16_1k)
    union { unsigned int u[2]; s16x4 v; } pu0, pu1;
    pu0.u[0] = packtr(p0,p1); pu0.u[1] = packtr(p2,p3);
    pu1.u[0] = packtr(p4,p5); pu1.u[1] = packtr(p6,p7);
    const unsigned short* vp0 = vb + (size_t)(jt + lg*4)*32 + lc;
    const unsigned short* vp1 = vb + (size_t)(jt + 16 + lg*4)*32 + lc;
    s16x4 va0, va1, vb0, vb1;
    va0[0]=(short)vp0[0];  va0[1]=(short)vp0[32];  va0[2]=(short)vp0[64];  va0[3]=(short)vp0[96];
    vb0[0]=(short)vp0[16]; vb0[1]=(short)vp0[48];  vb0[2]=(short)vp0[80];  vb0[3]=(short)vp0[112];
    va1[0]=(short)vp1[0];  va1[1]=(short)vp1[32];  va1[2]=(short)vp1[64];  va1[3]=(short)vp1[96];
    vb1[0]=(short)vp1[16]; vb1[1]=(short)vp1[48];  vb1[2]=(short)vp1[80];  vb1[3]=(short)vp1[112];
    acc0 = __builtin_amdgcn_mfma_f32_16x16x16bf16_1k(va0, pu0.v, acc0, 0,0,0);
    acc1 = __builtin_amdgcn_mfma_f32_16x16x16bf16_1k(vb0, pu0.v, acc1, 0,0,0);
    acc0 = __builtin_amdgcn_mfma_f32_16x16x16bf16_1k(va1, pu1.v, acc0, 0,0,0);
    acc1 = __builtin_amdgcn_mfma_f32_16x16x16bf16_1k(vb1, pu1.v, acc1, 0,0,0);
#else
    {
      unsigned int dw0 = packtr(p0,p1), dw1 = packtr(p2,p3);
      int src0 = lc + (((lg*2)&3)<<4);
      int src1 = lc + (((lg*2+1)&3)<<4);
      unsigned int u0 = __shfl(dw0, src0), u1 = __shfl(dw1, src0);
      unsigned int u2 = __shfl(dw0, src1), u3 = __shfl(dw1, src1);
      if (lg >= 2){ u0=0; u1=0; u2=0; u3=0; }
      union { unsigned int u[4]; s16x8 v; } pb;
      pb.u[0]=u0; pb.u[1]=u1; pb.u[2]=u2; pb.u[3]=u3;
      s16x8 vf0, vf1;
      #pragma unroll
      for (int e=0;e<8;++e){
        int j = (jt + lg*8 + e) & 1023;
        vf0[e] = (short)vb[(size_t)j*32 + lc];
        vf1[e] = (short)vb[(size_t)j*32 + 16 + lc];
      }
      acc0 = mfma16(vf0, pb.v, acc0);
      acc1 = mfma16(vf1, pb.v, acc1);
    }
    {
      unsigned int dw0 = packtr(p4,p5), dw1 = packtr(p6,p7);
      int src0 = lc + (((lg*2)&3)<<4);
      int src1 = lc + (((lg*2+1)&3)<<4);
      unsigned int u0 = __shfl(dw0, src0), u1 = __shfl(dw1, src0);
      unsigned int u2 = __shfl(dw0, src1), u3 = __shfl(dw1, src1);
      if (lg >= 2){ u0=0; u1=0; u2=0; u3=0; }
      union { unsigned int u[4]; s16x8 v; } pb;
      pb.u[0]=u0; pb.u[1]=u1; pb.u[2]=u2; pb.u[3]=u3;
      s16x8 vf0, vf1;
      #pragma unroll
      for (int e=0;e<8;++e){
        int j = (jt + 16 + lg*8 + e) & 1023;
        vf0[e] = (short)vb[(size_t)j*32 + lc];
        vf1[e] = (short)vb[(size_t)j*32 + 16 + lc];
      }
      acc0 = mfma16(vf0, pb.v, acc0);
      acc1 = mfma16(vf1, pb.v, acc1);
    }
#endif
  }
  lsum += __shfl_xor(lsum, 16);
  lsum += __shfl_xor(lsum, 32);
  if (lg == 0){ mL[w][lc] = m; lL[w][lc] = lsum; }
  #pragma unroll
  for (int r=0;r<4;++r){
    accL[w][0][lg*4+r][lc] = acc0[r];
    accL[w][1][lg*4+r][lc] = acc1[r];
  }
  __syncthreads();
  int ii = tid & 15, dd = tid >> 4;
  float m0 = mL[0][ii], m1 = mL[1][ii], m2 = mL[2][ii], m3 = mL[3][ii];
  float ms = fmaxf(fmaxf(m0,m1), fmaxf(m2,m3));
  float e0 = __expf(m0-ms), e1 = __expf(m1-ms), e2 = __expf(m2-ms), e3 = __expf(m3-ms);
  float lt = lL[0][ii]*e0 + lL[1][ii]*e1 + lL[2][ii]*e2 + lL[3][ii]*e3;
  float a0 = accL[0][0][dd][ii]*e0 + accL[1][0][dd][ii]*e1
           + accL[2][0][dd][ii]*e2 + accL[3][0][dd][ii]*e3;
  float a1 = accL[0][1][dd][ii]*e0 + accL[1][1][dd][ii]*e1
           + accL[2][1][dd][ii]*e2 + accL[3][1][dd][ii]*e3;
  float inv = 1.0f/lt;
  int b = bh>>3, hh = bh&7;
  size_t ob2 = ((size_t)((b<<10)+i0+ii))*256 + hh*32;
  out[ob2 + dd]      = f2bf(a0*inv);
  out[ob2 + 16 + dd] = f2bf(a1*inv);
}

// ------------- MFMA GEMM: C[M,NC] = A[M,K] @ W[K,NC], A bf16, WT bf16(NC,K) --
template<int K, int NC, int EPI, int BM, int BNt>
__global__ __launch_bounds__(256) void gemm_mfma(
    const unsigned short* __restrict__ Aa, const unsigned short* __restrict__ WT,
    const float* __restrict__ bias, const float* __restrict__ resid,
    void* __restrict__ outv){
  constexpr int WMm = BM/2, WNn = BNt/2;
  constexpr int FM = WMm/16, FN = WNn/16;
  constexpr int LP = 40;
  __shared__ __align__(16) unsigned short As[BM*LP];
  __shared__ __align__(16) unsigned short Bs[BNt*LP];
  const int tid = threadIdx.x;
  const int w = tid>>6, l = tid&63, lc = l&15, lg = l>>4;
  const int wm = w&1, wn = w>>1;
  const int n0 = blockIdx.x*BNt, m0 = blockIdx.y*BM;
  f32x4 acc[FM][FN];
  #pragma unroll
  for (int a=0;a<FM;++a)
    #pragma unroll
    for (int c=0;c<FN;++c){ acc[a][c][0]=0.f; acc[a][c][1]=0.f; acc[a][c][2]=0.f; acc[a][c][3]=0.f; }

  for (int k0=0; k0<K; k0+=32){
    __syncthreads();
    if constexpr (BM==64){
      int row = tid>>2, cg = tid&3;
      *(s16x8*)&As[row*LP+cg*8] = *(const s16x8*)&Aa[(size_t)(m0+row)*K + k0 + cg*8];
    } else {
      int row = tid>>3, cg = tid&7;
      *(ushort4*)&As[row*LP+cg*4] = *(const ushort4*)&Aa[(size_t)(m0+row)*K + k0 + cg*4];
    }
    if constexpr (BNt==64){
      int row = tid>>2, cg = tid&3;
      *(s16x8*)&Bs[row*LP+cg*8] = *(const s16x8*)&WT[(size_t)(n0+row)*K + k0 + cg*8];
    } else {
      int row = tid>>3, cg = tid&7;
      *(ushort4*)&Bs[row*LP+cg*4] = *(const ushort4*)&WT[(size_t)(n0+row)*K + k0 + cg*4];
    }
    __syncthreads();
    s16x8 af[FM], bv[FN];
    #pragma unroll
    for (int a=0;a<FM;++a) af[a] = *(const s16x8*)&As[(wm*WMm + a*16 + lc)*LP + lg*8];
    #pragma unroll
    for (int c=0;c<FN;++c) bv[c] = *(const s16x8*)&Bs[(wn*WNn + c*16 + lc)*LP + lg*8];
    #pragma unroll
    for (int a=0;a<FM;++a)
      #pragma unroll
      for (int c=0;c<FN;++c) acc[a][c] = mfma16(af[a], bv[c], acc[a][c]);
  }
  #pragma unroll
  for (int a=0;a<FM;++a){
    #pragma unroll
    for (int c=0;c<FN;++c){
      int n = n0 + wn*WNn + c*16 + lc;
      float bvv = (EPI!=0) ? bias[n] : 0.f;
      #pragma unroll
      for (int r=0;r<4;++r){
        int m = m0 + wm*WMm + a*16 + lg*4 + r;
        float vv = acc[a][c][r];
        if constexpr (EPI==0){
          ((unsigned short*)outv)[(size_t)m*NC + n] = f2bf(vv);
        } else if constexpr (EPI==1){
          ((float*)outv)[(size_t)m*NC + n] = vv + bvv + resid[(size_t)m*NC + n];
        } else {
          ((unsigned short*)outv)[(size_t)m*NC + n] = f2bf(gelu_f(vv + bvv));
        }
      }
    }
  }
}

extern "C" void kernel_launch(void* const* d_in, const int* in_sizes, int n_in,
                              void* d_out, int out_size, void* d_ws, size_t ws_size,
                              hipStream_t stream){
  const float* x_in  = (const float*)d_in[0];
  const float* coords= (const float*)d_in[1];
  const float* vel   = (const float*)d_in[2];
  const float* ln1_g = (const float*)d_in[3];
  const float* ln1_b = (const float*)d_in[4];
  const float* Wqkv  = (const float*)d_in[5];
  const float* relW1 = (const float*)d_in[6];
  const float* relb1 = (const float*)d_in[7];
  const float* relW2 = (const float*)d_in[8];
  const float* relb2 = (const float*)d_in[9];
  const float* Wout  = (const float*)d_in[10];
  const float* bout  = (const float*)d_in[11];
  const float* ln2_g = (const float*)d_in[12];
  const float* ln2_b = (const float*)d_in[13];
  const float* Wf1   = (const float*)d_in[14];
  const float* bf1   = (const float*)d_in[15];
  const float* Wf2   = (const float*)d_in[16];
  const float* bf2   = (const float*)d_in[17];

  float* x = (float*)d_out;
  unsigned short* us = (unsigned short*)d_ws;
  unsigned short* hbf   = us;                    // 524288
  unsigned short* qkvbf = hbf   + 524288;        // 1572864
  unsigned short* qbf   = qkvbf + 1572864;       // 524288
  unsigned short* kbf   = qbf   + 524288;        // 524288
  unsigned short* vbf   = kbf   + 524288;        // 524288
  unsigned short* attbf = vbf   + 524288;        // 524288
  unsigned short* midbf = attbf + 524288;        // 2097152
  unsigned short* relbf = midbf + 2097152;       // 16777216
  unsigned short* WqkvT = relbf + 16777216;      // 393216
  unsigned short* WoutT = WqkvT + 393216;        // 131072
  unsigned short* Wf1T  = WoutT + 131072;        // 524288
  unsigned short* Wf2T  = Wf1T  + 524288;        // 524288
  _Float16* W2Th = (_Float16*)(Wf2T + 524288);   // 1024
  _Float16* Wdh  = W2Th + 1024;                  // 64
  _Float16* Ah   = Wdh + 64;                     // 131072
  _Float16* A2h  = Ah + 131072;                  // 131072
  float* sint  = (float*)(A2h + 131072);         // 16384
  float* cost  = sint + 16384;                   // 16384

  rope_table<<<64,256,0,stream>>>(sint,cost);
  wt_convert<<<dim3(24,8,2),256,0,stream>>>(Wqkv, WqkvT, 256, 768, 256, SCALEV);
  wt_convert<<<dim3(8,8,2),256,0,stream>>>(Wout, WoutT, 256, 256, 0, 1.0f);
  wt_convert<<<dim3(32,8,2),256,0,stream>>>(Wf1, Wf1T, 256, 1024, 0, 1.0f);
  wt_convert<<<dim3(8,32,2),256,0,stream>>>(Wf2, Wf2T, 1024, 256, 0, 1.0f);

  for (int l=0;l<2;++l){
    const float* xr = (l==0) ? x_in : x;   // residual source; x first written by att-GEMM l=0
    ln_kernel<<<2048,256,0,stream>>>(xr, ln1_g+l*256, ln1_b+l*256, hbf);
    gemm_mfma<256,768,0,64,64><<<dim3(12,32),256,0,stream>>>(
        hbf, WqkvT + (size_t)l*196608, nullptr, nullptr, qkvbf);
    rope_apply_bf<<<2048,256,0,stream>>>(qkvbf, sint, cost, qbf, kbf, vbf);
    rel_pre<<<513,256,0,stream>>>(coords, vel, relW1+l*320, relb1+l*64,
                                  relW2+l*512, Ah, A2h, W2Th, Wdh);
    rel_fused9<<<2048,256,0,stream>>>(coords, Ah, A2h, W2Th, Wdh,
                                      relb2+l*8, relbf);
    attn_mfma4<<<1024,256,0,stream>>>(qbf, kbf, vbf, relbf, attbf);
    gemm_mfma<256,256,1,32,32><<<dim3(8,64),256,0,stream>>>(
        attbf, WoutT + (size_t)l*65536, bout+l*256, xr, x);
    ln_kernel<<<2048,256,0,stream>>>(x, ln2_g+l*256, ln2_b+l*256, hbf);
    gemm_mfma<256,1024,2,64,64><<<dim3(16,32),256,0,stream>>>(
        hbf, Wf1T + (size_t)l*262144, bf1+l*1024, nullptr, midbf);
    gemm_mfma<1024,256,1,32,32><<<dim3(8,64),256,0,stream>>>(
        midbf, Wf2T + (size_t)l*262144, bf2+l*256, x, x);
  }
}

// Round 19
// 187.927 us; speedup vs baseline: 1.2533x; 1.0692x over previous
//
#include <hip/hip_runtime.h>
#include <math.h>

#define BN_ 2
#define NN 1024
#define DDIM 256
#define HH 8
#define HDIM 32
#define FFD 1024
#define EPSV 1e-5f
#define SCALEV 0.17677669529663687f

typedef __attribute__((ext_vector_type(8))) short s16x8;
typedef __attribute__((ext_vector_type(4))) short s16x4;
typedef __attribute__((ext_vector_type(4))) float f32x4;
typedef __attribute__((ext_vector_type(2))) _Float16 h2;
typedef __attribute__((ext_vector_type(8))) _Float16 f16x8;

__device__ __forceinline__ float gelu_f(float x){
  return 0.5f*x*(1.0f+erff(x*0.70710678118654752f));
}
__device__ __forceinline__ unsigned int pack_bf16(float lo, float hi){
  unsigned int ul = __float_as_uint(lo), uh = __float_as_uint(hi);
  ul += 0x7fff + ((ul>>16)&1);
  uh += 0x7fff + ((uh>>16)&1);
  return (ul>>16) | (uh & 0xffff0000u);
}
__device__ __forceinline__ unsigned short f2bf(float x){
  unsigned int u = __float_as_uint(x);
  u += 0x7fff + ((u>>16)&1);
  return (unsigned short)(u>>16);
}
__device__ __forceinline__ float bf2f(unsigned short u){
  return __uint_as_float(((unsigned int)u)<<16);
}
__device__ __forceinline__ unsigned int packtr(float lo, float hi){
  return __builtin_amdgcn_perm(__float_as_uint(hi), __float_as_uint(lo), 0x07060302u);
}
__device__ __forceinline__ f32x4 mfma16(s16x8 a, s16x8 b, f32x4 c){
  return __builtin_amdgcn_mfma_f32_16x16x32_bf16(a,b,c,0,0,0);
}
__device__ __forceinline__ f32x4 mfma16h(f16x8 a, f16x8 b, f32x4 c){
  return __builtin_amdgcn_mfma_f32_16x16x32_f16(a,b,c,0,0,0);
}

// ---------------- LayerNorm: f32 in, bf16 out --------------------------------
__global__ __launch_bounds__(256) void ln_kernel(const float* __restrict__ x,
    const float* __restrict__ g, const float* __restrict__ b,
    unsigned short* __restrict__ out){
  int row = blockIdx.x, tid = threadIdx.x;
  float val = x[(size_t)row*DDIM + tid];
  float s = val;
  #pragma unroll
  for (int o=32;o;o>>=1) s += __shfl_xor(s,o);
  __shared__ float sb[4], sb2[4];
  if ((tid&63)==0) sb[tid>>6]=s;
  __syncthreads();
  float mean = (sb[0]+sb[1]+sb[2]+sb[3]) * (1.0f/DDIM);
  float d = val-mean;
  float vs = d*d;
  #pragma unroll
  for (int o=32;o;o>>=1) vs += __shfl_xor(vs,o);
  if ((tid&63)==0) sb2[tid>>6]=vs;
  __syncthreads();
  float var = (sb2[0]+sb2[1]+sb2[2]+sb2[3]) * (1.0f/DDIM);
  out[(size_t)row*DDIM + tid] = f2bf(d*rsqrtf(var+EPSV)*g[tid]+b[tid]);
}

// ---------------- RoPE tables -------------------------------------------------
__global__ __launch_bounds__(256) void rope_table(float* __restrict__ sint, float* __restrict__ cost){
  int idx = blockIdx.x*256+threadIdx.x;   // 16384
  int i = idx >> 4, d = idx & 15;
  float freq = (float)i * powf(10000.0f, -(float)d/16.0f);
  sint[idx]=sinf(freq); cost[idx]=cosf(freq);
}

// ---------------- weight convert+transpose f32(K,NC) -> bf16 WT(NC,K) --------
__global__ __launch_bounds__(256) void wt_convert(const float* __restrict__ in,
    unsigned short* __restrict__ out, int K, int NC, int scaleCols, float scaleVal){
  __shared__ float tile[32][33];
  int tn0 = blockIdx.x*32;
  int tk0 = blockIdx.y*32;
  size_t loff = (size_t)blockIdx.z * K * NC;
  int t = threadIdx.x;
  int col = t & 31, rr = t >> 5;
  #pragma unroll
  for (int i=0;i<4;++i){
    int row = rr + i*8;
    tile[row][col] = in[loff + (size_t)(tk0+row)*NC + tn0+col];
  }
  __syncthreads();
  #pragma unroll
  for (int i=0;i<4;++i){
    int row = rr + i*8;
    int n = tn0 + row;
    float s = (n < scaleCols) ? scaleVal : 1.0f;
    out[loff + (size_t)n*K + tk0 + col] = f2bf(tile[col][row]*s);
  }
}

// ------------- split qkv + rope (bf16 in/out) --------------------------------
__global__ __launch_bounds__(256) void rope_apply_bf(const unsigned short* __restrict__ qkv,
    const float* __restrict__ sint, const float* __restrict__ cost,
    unsigned short* __restrict__ q, unsigned short* __restrict__ k,
    unsigned short* __restrict__ v){
  int row = blockIdx.x;                 // b*1024 + i
  int b = row>>10, i = row&1023;
  int tid = threadIdx.x; int h = tid>>5, d = tid&31;
  const unsigned short* base = qkv + (size_t)row*768;
  size_t oidx = (((size_t)((b<<3)+h)<<10) + i)*32 + d;
  v[oidx] = base[512 + h*32 + d];
  int dd = (d<16) ? d : d-16;
  float s = sint[i*16+dd], c = cost[i*16+dd];
  float q1 = bf2f(base[h*32+dd]), q2 = bf2f(base[h*32+dd+16]);
  q[oidx] = f2bf((d<16) ? (q1*c - q2*s) : (q2*c + q1*s));
  float k1 = bf2f(base[256+h*32+dd]), k2 = bf2f(base[256+h*32+dd+16]);
  k[oidx] = f2bf((d<16) ? (k1*c - k2*s) : (k2*c + k1*s));
}

// ------------- rel precompute: per-node separable parts (fp16) + W2T (f16) ---
__global__ __launch_bounds__(256) void rel_pre(const float* __restrict__ coords,
    const float* __restrict__ vel, const float* __restrict__ W1,
    const float* __restrict__ b1, const float* __restrict__ W2,
    _Float16* __restrict__ A, _Float16* __restrict__ A2,
    _Float16* __restrict__ W2T, _Float16* __restrict__ Wd){
  if (blockIdx.x == 512){
    int t = threadIdx.x;
    #pragma unroll
    for (int e=0;e<4;++e){
      int idx = t*4+e;              // n*64 + k
      int n = idx>>6, kk = idx&63;
      W2T[idx] = (n<8) ? (_Float16)W2[kk*8+n] : (_Float16)0.f;
    }
    if (t < 64) Wd[t] = (_Float16)W1[128+t];
    return;
  }
  int gid = blockIdx.x*256 + threadIdx.x;  // 2048*64
  int node = gid >> 6, r = gid & 63;
  float c0 = coords[node*2], c1 = coords[node*2+1];
  float v0 = vel[node*2],    v1 = vel[node*2+1];
  float bv = c0*W1[r] + c1*W1[64+r] + v0*W1[192+r] + v1*W1[256+r];
  A[gid] = (_Float16)(b1[r] + bv);
  A2[gid] = (_Float16)bv;
}

// ------------- rel fused v9: 2 i's per block, j-half split, packed-f16 -------
__global__ __launch_bounds__(256, 4) void rel_fused9(const float* __restrict__ coords,
    const _Float16* __restrict__ A, const _Float16* __restrict__ A2,
    const _Float16* __restrict__ W2T, const _Float16* __restrict__ Wd,
    const float* __restrict__ b2, unsigned short* __restrict__ relbf){
  const int tid = threadIdx.x;
  const int bid = blockIdx.x;            // 2048
  const int b  = bid >> 10;
  const int ia = ((bid >> 1) & 511) * 2; // rows ia, ia+1
  const int jh = bid & 1;
  const int w = tid>>6, l = tid&63, lc = l&15, lg = l>>4;
  const int nodea = (b<<10) + ia;
  float2 cia = *(const float2*)(coords + (size_t)nodea*2);
  float2 cib = *(const float2*)(coords + (size_t)nodea*2 + 2);

  union u4h { uint4 u; h2 h[4]; };
  u4h aA, aB, bA, bB, wA, wB;
  aA.u = *(const uint4*)(A + (size_t)nodea*64 + lg*8);
  aB.u = *(const uint4*)(A + (size_t)nodea*64 + 32 + lg*8);
  bA.u = *(const uint4*)(A + (size_t)(nodea+1)*64 + lg*8);
  bB.u = *(const uint4*)(A + (size_t)(nodea+1)*64 + 32 + lg*8);
  wA.u = *(const uint4*)(Wd + lg*8);
  wB.u = *(const uint4*)(Wd + 32 + lg*8);

  const f16x8 bf0 = *(const f16x8*)&W2T[lc*64 + lg*8];
  const f16x8 bf1 = *(const f16x8*)&W2T[lc*64 + 32 + lg*8];
  const float b2v = (lc<8) ? b2[lc] : 0.f;

  const h2 c2 = {(_Float16)0.0099735570f, (_Float16)0.0099735570f};
  const h2 c1 = {(_Float16)-0.0664904395f, (_Float16)-0.0664904395f};
  const h2 c0 = {(_Float16)0.3989422804f, (_Float16)0.3989422804f};
  const h2 ch = {(_Float16)0.5f, (_Float16)0.5f};

  const int jbase = jh*512 + w*128;
  const float* cb = coords + (size_t)((b<<10) + jbase + lc)*2;
  const _Float16* ab = A2 + (size_t)((b<<10) + jbase + lc)*64 + lg*8;
  unsigned short* oba = relbf + ((size_t)b<<23) + ((size_t)ia<<10)
                      + ((size_t)(lc&7)<<20) + (unsigned)(jbase + lg*4);

  for (int st=0; st<8; ++st){
    u4h t0, t1;
    t0.u = *(const uint4*)(ab + st*1024);
    t1.u = *(const uint4*)(ab + st*1024 + 32);
    float2 cj = *(const float2*)(cb + st*32);
    // ---- i_a ----
    {
      float dx = cia.x-cj.x, dy = cia.y-cj.y;
      _Float16 dh = (_Float16)sqrtf(fmaf(dx,dx,dy*dy));
      h2 d2 = {dh, dh};
      union { h2 h[4]; f16x8 v; } g0, g1;
      #pragma unroll
      for (int e=0;e<4;++e){
        h2 t = (aA.h[e] - t0.h[e]) + d2*wA.h[e];
        h2 u = t*t;
        h2 p = u*c2 + c1;
        p = u*p + c0;
        g0.h[e] = u*p + ch*t;
        h2 s = (aB.h[e] - t1.h[e]) + d2*wB.h[e];
        h2 v = s*s;
        h2 q = v*c2 + c1;
        q = v*q + c0;
        g1.h[e] = v*q + ch*s;
      }
      f32x4 z; z[0]=0.f; z[1]=0.f; z[2]=0.f; z[3]=0.f;
      z = mfma16h(g0.v, bf0, z);
      z = mfma16h(g1.v, bf1, z);
      if (lc < 8){
        unsigned short* op = oba + st*16;
        *(unsigned int*)op     = pack_bf16(z[0]+b2v, z[1]+b2v);
        *(unsigned int*)(op+2) = pack_bf16(z[2]+b2v, z[3]+b2v);
      }
    }
    // ---- i_b (same t0/t1/cj loads) ----
    {
      float dx = cib.x-cj.x, dy = cib.y-cj.y;
      _Float16 dh = (_Float16)sqrtf(fmaf(dx,dx,dy*dy));
      h2 d2 = {dh, dh};
      union { h2 h[4]; f16x8 v; } g0, g1;
      #pragma unroll
      for (int e=0;e<4;++e){
        h2 t = (bA.h[e] - t0.h[e]) + d2*wA.h[e];
        h2 u = t*t;
        h2 p = u*c2 + c1;
        p = u*p + c0;
        g0.h[e] = u*p + ch*t;
        h2 s = (bB.h[e] - t1.h[e]) + d2*wB.h[e];
        h2 v = s*s;
        h2 q = v*c2 + c1;
        q = v*q + c0;
        g1.h[e] = v*q + ch*s;
      }
      f32x4 z; z[0]=0.f; z[1]=0.f; z[2]=0.f; z[3]=0.f;
      z = mfma16h(g0.v, bf0, z);
      z = mfma16h(g1.v, bf1, z);
      if (lc < 8){
        unsigned short* op = oba + 1024 + st*16;
        *(unsigned int*)op     = pack_bf16(z[0]+b2v, z[1]+b2v);
        *(unsigned int*)(op+2) = pack_bf16(z[2]+b2v, z[3]+b2v);
      }
    }
  }
}

// ------------- attn v4: swapped-operand MFMA flash, 32-j tiles ----------------
__global__ __launch_bounds__(256) void attn_mfma4(
    const unsigned short* __restrict__ q, const unsigned short* __restrict__ kk,
    const unsigned short* __restrict__ vv, const unsigned short* __restrict__ relbf,
    unsigned short* __restrict__ out){
  int bh = blockIdx.x >> 6;
  int i0 = (blockIdx.x & 63) * 16;
  int tid = threadIdx.x;
  int w = tid>>6, l = tid&63, lc = l&15, lg = l>>4;

  __shared__ __align__(16) float accL[4][2][16][17];
  __shared__ float mL[4][16];
  __shared__ float lL[4][16];

  const unsigned short* qb = q + ((size_t)(bh<<10) + i0)*32;
  const unsigned short* kb = kk + ((size_t)bh<<15);
  const unsigned short* vb = vv + ((size_t)bh<<15);
  const unsigned short* relrow = relbf + ((size_t)bh<<20) + ((size_t)(i0+lc)<<10);

  s16x8 qf = *(const s16x8*)(qb + (size_t)lc*32 + lg*8);

  float m = -1e30f, lsum = 0.f;
  f32x4 acc0, acc1;
  acc0[0]=0.f; acc0[1]=0.f; acc0[2]=0.f; acc0[3]=0.f;
  acc1 = acc0;

  for (int t=0; t<8; ++t){
    const int jt = w*256 + t*32;
    s16x8 kf0 = *(const s16x8*)(kb + (size_t)(jt+lc)*32 + lg*8);
    s16x8 kf1 = *(const s16x8*)(kb + (size_t)(jt+16+lc)*32 + lg*8);
    f32x4 z; z[0]=0.f; z[1]=0.f; z[2]=0.f; z[3]=0.f;
    f32x4 s0 = mfma16(kf0, qf, z);
    f32x4 s1 = mfma16(kf1, qf, z);
    ushort4 rl0 = *(const ushort4*)(relrow + jt + lg*4);
    ushort4 rl1 = *(const ushort4*)(relrow + jt + 16 + lg*4);
    s0[0] += bf2f(rl0.x); s0[1] += bf2f(rl0.y);
    s0[2] += bf2f(rl0.z); s0[3] += bf2f(rl0.w);
    s1[0] += bf2f(rl1.x); s1[1] += bf2f(rl1.y);
    s1[2] += bf2f(rl1.z); s1[3] += bf2f(rl1.w);
    float mx = fmaxf(fmaxf(fmaxf(s0[0],s0[1]), fmaxf(s0[2],s0[3])),
                     fmaxf(fmaxf(s1[0],s1[1]), fmaxf(s1[2],s1[3])));
    mx = fmaxf(mx, __shfl_xor(mx,16));
    mx = fmaxf(mx, __shfl_xor(mx,32));
    float mn = fmaxf(m, mx);
    float scale = __expf(m - mn);
    m = mn;
    float p0 = __expf(s0[0]-mn), p1 = __expf(s0[1]-mn);
    float p2 = __expf(s0[2]-mn), p3 = __expf(s0[3]-mn);
    float p4 = __expf(s1[0]-mn), p5 = __expf(s1[1]-mn);
    float p6 = __expf(s1[2]-mn), p7 = __expf(s1[3]-mn);
    lsum = lsum*scale + ((p0+p1)+(p2+p3)) + ((p4+p5)+(p6+p7));
    acc0[0]*=scale; acc0[1]*=scale; acc0[2]*=scale; acc0[3]*=scale;
    acc1[0]*=scale; acc1[1]*=scale; acc1[2]*=scale; acc1[3]*=scale;
#if __has_builtin(__builtin_amdgcn_mfma_f32_16x16x16bf16_1k)
    union { unsigned int u[2]; s16x4 v; } pu0, pu1;
    pu0.u[0] = packtr(p0,p1); pu0.u[1] = packtr(p2,p3);
    pu1.u[0] = packtr(p4,p5); pu1.u[1] = packtr(p6,p7);
    const unsigned short* vp0 = vb + (size_t)(jt + lg*4)*32 + lc;
    const unsigned short* vp1 = vb + (size_t)(jt + 16 + lg*4)*32 + lc;
    s16x4 va0, va1, vb0, vb1;
    va0[0]=(short)vp0[0];  va0[1]=(short)vp0[32];  va0[2]=(short)vp0[64];  va0[3]=(short)vp0[96];
    vb0[0]=(short)vp0[16]; vb0[1]=(short)vp0[48];  vb0[2]=(short)vp0[80];  vb0[3]=(short)vp0[112];
    va1[0]=(short)vp1[0];  va1[1]=(short)vp1[32];  va1[2]=(short)vp1[64];  va1[3]=(short)vp1[96];
    vb1[0]=(short)vp1[16]; vb1[1]=(short)vp1[48];  vb1[2]=(short)vp1[80];  vb1[3]=(short)vp1[112];
    acc0 = __builtin_amdgcn_mfma_f32_16x16x16bf16_1k(va0, pu0.v, acc0, 0,0,0);
    acc1 = __builtin_amdgcn_mfma_f32_16x16x16bf16_1k(vb0, pu0.v, acc1, 0,0,0);
    acc0 = __builtin_amdgcn_mfma_f32_16x16x16bf16_1k(va1, pu1.v, acc0, 0,0,0);
    acc1 = __builtin_amdgcn_mfma_f32_16x16x16bf16_1k(vb1, pu1.v, acc1, 0,0,0);
#else
    {
      unsigned int dw0 = packtr(p0,p1), dw1 = packtr(p2,p3);
      int src0 = lc + (((lg*2)&3)<<4);
      int src1 = lc + (((lg*2+1)&3)<<4);
      unsigned int u0 = __shfl(dw0, src0), u1 = __shfl(dw1, src0);
      unsigned int u2 = __shfl(dw0, src1), u3 = __shfl(dw1, src1);
      if (lg >= 2){ u0=0; u1=0; u2=0; u3=0; }
      union { unsigned int u[4]; s16x8 v; } pb;
      pb.u[0]=u0; pb.u[1]=u1; pb.u[2]=u2; pb.u[3]=u3;
      s16x8 vf0, vf1;
      #pragma unroll
      for (int e=0;e<8;++e){
        int j = (jt + lg*8 + e) & 1023;
        vf0[e] = (short)vb[(size_t)j*32 + lc];
        vf1[e] = (short)vb[(size_t)j*32 + 16 + lc];
      }
      acc0 = mfma16(vf0, pb.v, acc0);
      acc1 = mfma16(vf1, pb.v, acc1);
    }
    {
      unsigned int dw0 = packtr(p4,p5), dw1 = packtr(p6,p7);
      int src0 = lc + (((lg*2)&3)<<4);
      int src1 = lc + (((lg*2+1)&3)<<4);
      unsigned int u0 = __shfl(dw0, src0), u1 = __shfl(dw1, src0);
      unsigned int u2 = __shfl(dw0, src1), u3 = __shfl(dw1, src1);
      if (lg >= 2){ u0=0; u1=0; u2=0; u3=0; }
      union { unsigned int u[4]; s16x8 v; } pb;
      pb.u[0]=u0; pb.u[1]=u1; pb.u[2]=u2; pb.u[3]=u3;
      s16x8 vf0, vf1;
      #pragma unroll
      for (int e=0;e<8;++e){
        int j = (jt + 16 + lg*8 + e) & 1023;
        vf0[e] = (short)vb[(size_t)j*32 + lc];
        vf1[e] = (short)vb[(size_t)j*32 + 16 + lc];
      }
      acc0 = mfma16(vf0, pb.v, acc0);
      acc1 = mfma16(vf1, pb.v, acc1);
    }
#endif
  }
  lsum += __shfl_xor(lsum, 16);
  lsum += __shfl_xor(lsum, 32);
  if (lg == 0){ mL[w][lc] = m; lL[w][lc] = lsum; }
  #pragma unroll
  for (int r=0;r<4;++r){
    accL[w][0][lg*4+r][lc] = acc0[r];
    accL[w][1][lg*4+r][lc] = acc1[r];
  }
  __syncthreads();
  int ii = tid & 15, dd = tid >> 4;
  float m0 = mL[0][ii], m1 = mL[1][ii], m2 = mL[2][ii], m3 = mL[3][ii];
  float ms = fmaxf(fmaxf(m0,m1), fmaxf(m2,m3));
  float e0 = __expf(m0-ms), e1 = __expf(m1-ms), e2 = __expf(m2-ms), e3 = __expf(m3-ms);
  float lt = lL[0][ii]*e0 + lL[1][ii]*e1 + lL[2][ii]*e2 + lL[3][ii]*e3;
  float a0 = accL[0][0][dd][ii]*e0 + accL[1][0][dd][ii]*e1
           + accL[2][0][dd][ii]*e2 + accL[3][0][dd][ii]*e3;
  float a1 = accL[0][1][dd][ii]*e0 + accL[1][1][dd][ii]*e1
           + accL[2][1][dd][ii]*e2 + accL[3][1][dd][ii]*e3;
  float inv = 1.0f/lt;
  int b = bh>>3, hh = bh&7;
  size_t ob2 = ((size_t)((b<<10)+i0+ii))*256 + hh*32;
  out[ob2 + dd]      = f2bf(a0*inv);
  out[ob2 + 16 + dd] = f2bf(a1*inv);
}

// ------------- MFMA GEMM v2: BK=64, reg-staged prefetch (issue-early) --------
// C[M,NC] = A[M,K] @ W[K,NC]; A bf16, WT bf16(NC,K).
// EPI: 0 none (bf16 out), 1 +bias+resid (f32 out), 2 gelu(+bias) (bf16 out)
template<int K, int NC, int EPI, int BM, int BNt>
__global__ __launch_bounds__(256) void gemm_mfma(
    const unsigned short* __restrict__ Aa, const unsigned short* __restrict__ WT,
    const float* __restrict__ bias, const float* __restrict__ resid,
    void* __restrict__ outv){
  constexpr int WMm = BM/2, WNn = BNt/2;
  constexpr int FM = WMm/16, FN = WNn/16;
  constexpr int LP = 72;                     // 64 k + 8 pad (bank-safe)
  constexpr int NIT = K/64;
  constexpr int AL = (BM==64)?2:1;           // s16x8 loads per thread (A)
  constexpr int BL = (BNt==64)?2:1;
  __shared__ __align__(16) unsigned short As[BM*LP];
  __shared__ __align__(16) unsigned short Bs[BNt*LP];
  const int tid = threadIdx.x;
  const int w = tid>>6, l = tid&63, lc = l&15, lg = l>>4;
  const int wm = w&1, wn = w>>1;
  const int n0 = blockIdx.x*BNt, m0 = blockIdx.y*BM;

  // per-thread staging coordinates
  const int arow = (BM==64) ? (tid>>2) : (tid>>3);
  const int acg  = (BM==64) ? (tid&3)  : (tid&7);
  const int brow = (BNt==64) ? (tid>>2) : (tid>>3);
  const int bcg  = (BNt==64) ? (tid&3)  : (tid&7);
  const unsigned short* ag = Aa + (size_t)(m0+arow)*K + ((BM==64)? acg*16 : acg*8);
  const unsigned short* bg = WT + (size_t)(n0+brow)*K + ((BNt==64)? bcg*16 : bcg*8);

  f32x4 acc[FM][FN];
  #pragma unroll
  for (int a=0;a<FM;++a)
    #pragma unroll
    for (int c=0;c<FN;++c){ acc[a][c][0]=0.f; acc[a][c][1]=0.f; acc[a][c][2]=0.f; acc[a][c][3]=0.f; }

  // prefetch tile 0
  s16x8 pa[AL], pb[BL];
  #pragma unroll
  for (int u=0;u<AL;++u) pa[u] = *(const s16x8*)(ag + u*8);
  #pragma unroll
  for (int u=0;u<BL;++u) pb[u] = *(const s16x8*)(bg + u*8);

  for (int it=0; it<NIT; ++it){
    __syncthreads();
    if constexpr (BM==64){
      *(s16x8*)&As[arow*LP + acg*16]     = pa[0];
      *(s16x8*)&As[arow*LP + acg*16 + 8] = pa[1];
    } else {
      *(s16x8*)&As[arow*LP + acg*8] = pa[0];
    }
    if constexpr (BNt==64){
      *(s16x8*)&Bs[brow*LP + bcg*16]     = pb[0];
      *(s16x8*)&Bs[brow*LP + bcg*16 + 8] = pb[1];
    } else {
      *(s16x8*)&Bs[brow*LP + bcg*8] = pb[0];
    }
    __syncthreads();
    // issue next tile's loads BEFORE compute (hide latency under MFMAs)
    if (it+1 < NIT){
      const unsigned short* agn = ag + (it+1)*64;
      const unsigned short* bgn = bg + (it+1)*64;
      #pragma unroll
      for (int u=0;u<AL;++u) pa[u] = *(const s16x8*)(agn + u*8);
      #pragma unroll
      for (int u=0;u<BL;++u) pb[u] = *(const s16x8*)(bgn + u*8);
    }
    #pragma unroll
    for (int kk=0; kk<2; ++kk){
      s16x8 af[FM], bv[FN];
      #pragma unroll
      for (int a=0;a<FM;++a) af[a] = *(const s16x8*)&As[(wm*WMm + a*16 + lc)*LP + kk*32 + lg*8];
      #pragma unroll
      for (int c=0;c<FN;++c) bv[c] = *(const s16x8*)&Bs[(wn*WNn + c*16 + lc)*LP + kk*32 + lg*8];
      #pragma unroll
      for (int a=0;a<FM;++a)
        #pragma unroll
        for (int c=0;c<FN;++c) acc[a][c] = mfma16(af[a], bv[c], acc[a][c]);
    }
  }
  #pragma unroll
  for (int a=0;a<FM;++a){
    #pragma unroll
    for (int c=0;c<FN;++c){
      int n = n0 + wn*WNn + c*16 + lc;
      float bvv = (EPI!=0) ? bias[n] : 0.f;
      #pragma unroll
      for (int r=0;r<4;++r){
        int m = m0 + wm*WMm + a*16 + lg*4 + r;
        float vv = acc[a][c][r];
        if constexpr (EPI==0){
          ((unsigned short*)outv)[(size_t)m*NC + n] = f2bf(vv);
        } else if constexpr (EPI==1){
          ((float*)outv)[(size_t)m*NC + n] = vv + bvv + resid[(size_t)m*NC + n];
        } else {
          ((unsigned short*)outv)[(size_t)m*NC + n] = f2bf(gelu_f(vv + bvv));
        }
      }
    }
  }
}

extern "C" void kernel_launch(void* const* d_in, const int* in_sizes, int n_in,
                              void* d_out, int out_size, void* d_ws, size_t ws_size,
                              hipStream_t stream){
  const float* x_in  = (const float*)d_in[0];
  const float* coords= (const float*)d_in[1];
  const float* vel   = (const float*)d_in[2];
  const float* ln1_g = (const float*)d_in[3];
  const float* ln1_b = (const float*)d_in[4];
  const float* Wqkv  = (const float*)d_in[5];
  const float* relW1 = (const float*)d_in[6];
  const float* relb1 = (const float*)d_in[7];
  const float* relW2 = (const float*)d_in[8];
  const float* relb2 = (const float*)d_in[9];
  const float* Wout  = (const float*)d_in[10];
  const float* bout  = (const float*)d_in[11];
  const float* ln2_g = (const float*)d_in[12];
  const float* ln2_b = (const float*)d_in[13];
  const float* Wf1   = (const float*)d_in[14];
  const float* bf1   = (const float*)d_in[15];
  const float* Wf2   = (const float*)d_in[16];
  const float* bf2   = (const float*)d_in[17];

  float* x = (float*)d_out;
  unsigned short* us = (unsigned short*)d_ws;
  unsigned short* hbf   = us;                    // 524288
  unsigned short* qkvbf = hbf   + 524288;        // 1572864
  unsigned short* qbf   = qkvbf + 1572864;       // 524288
  unsigned short* kbf   = qbf   + 524288;        // 524288
  unsigned short* vbf   = kbf   + 524288;        // 524288
  unsigned short* attbf = vbf   + 524288;        // 524288
  unsigned short* midbf = attbf + 524288;        // 2097152
  unsigned short* relbf = midbf + 2097152;       // 16777216
  unsigned short* WqkvT = relbf + 16777216;      // 393216
  unsigned short* WoutT = WqkvT + 393216;        // 131072
  unsigned short* Wf1T  = WoutT + 131072;        // 524288
  unsigned short* Wf2T  = Wf1T  + 524288;        // 524288
  _Float16* W2Th = (_Float16*)(Wf2T + 524288);   // 1024
  _Float16* Wdh  = W2Th + 1024;                  // 64
  _Float16* Ah   = Wdh + 64;                     // 131072
  _Float16* A2h  = Ah + 131072;                  // 131072
  float* sint  = (float*)(A2h + 131072);         // 16384
  float* cost  = sint + 16384;                   // 16384

  rope_table<<<64,256,0,stream>>>(sint,cost);
  wt_convert<<<dim3(24,8,2),256,0,stream>>>(Wqkv, WqkvT, 256, 768, 256, SCALEV);
  wt_convert<<<dim3(8,8,2),256,0,stream>>>(Wout, WoutT, 256, 256, 0, 1.0f);
  wt_convert<<<dim3(32,8,2),256,0,stream>>>(Wf1, Wf1T, 256, 1024, 0, 1.0f);
  wt_convert<<<dim3(8,32,2),256,0,stream>>>(Wf2, Wf2T, 1024, 256, 0, 1.0f);

  for (int l=0;l<2;++l){
    const float* xr = (l==0) ? x_in : x;   // residual source; x first written by att-GEMM l=0
    ln_kernel<<<2048,256,0,stream>>>(xr, ln1_g+l*256, ln1_b+l*256, hbf);
    gemm_mfma<256,768,0,64,64><<<dim3(12,32),256,0,stream>>>(
        hbf, WqkvT + (size_t)l*196608, nullptr, nullptr, qkvbf);
    rope_apply_bf<<<2048,256,0,stream>>>(qkvbf, sint, cost, qbf, kbf, vbf);
    rel_pre<<<513,256,0,stream>>>(coords, vel, relW1+l*320, relb1+l*64,
                                  relW2+l*512, Ah, A2h, W2Th, Wdh);
    rel_fused9<<<2048,256,0,stream>>>(coords, Ah, A2h, W2Th, Wdh,
                                      relb2+l*8, relbf);
    attn_mfma4<<<1024,256,0,stream>>>(qbf, kbf, vbf, relbf, attbf);
    gemm_mfma<256,256,1,32,32><<<dim3(8,64),256,0,stream>>>(
        attbf, WoutT + (size_t)l*65536, bout+l*256, xr, x);
    ln_kernel<<<2048,256,0,stream>>>(x, ln2_g+l*256, ln2_b+l*256, hbf);
    gemm_mfma<256,1024,2,64,64><<<dim3(16,32),256,0,stream>>>(
        hbf, Wf1T + (size_t)l*262144, bf1+l*1024, nullptr, midbf);
    gemm_mfma<1024,256,1,32,32><<<dim3(8,64),256,0,stream>>>(
        midbf, Wf2T + (size_t)l*262144, bf2+l*256, x, x);
  }
}

// Round 20
// 186.161 us; speedup vs baseline: 1.2652x; 1.0095x over previous
//
#include <hip/hip_runtime.h>
#include <math.h>

#define BN_ 2
#define NN 1024
#define DDIM 256
#define HH 8
#define HDIM 32
#define FFD 1024
#define EPSV 1e-5f
#define SCALEV 0.17677669529663687f

typedef __attribute__((ext_vector_type(8))) short s16x8;
typedef __attribute__((ext_vector_type(4))) short s16x4;
typedef __attribute__((ext_vector_type(4))) float f32x4;
typedef __attribute__((ext_vector_type(2))) _Float16 h2;
typedef __attribute__((ext_vector_type(8))) _Float16 f16x8;

__device__ __forceinline__ float gelu_f(float x){
  return 0.5f*x*(1.0f+erff(x*0.70710678118654752f));
}
__device__ __forceinline__ unsigned int pack_bf16(float lo, float hi){
  unsigned int ul = __float_as_uint(lo), uh = __float_as_uint(hi);
  ul += 0x7fff + ((ul>>16)&1);
  uh += 0x7fff + ((uh>>16)&1);
  return (ul>>16) | (uh & 0xffff0000u);
}
__device__ __forceinline__ unsigned short f2bf(float x){
  unsigned int u = __float_as_uint(x);
  u += 0x7fff + ((u>>16)&1);
  return (unsigned short)(u>>16);
}
__device__ __forceinline__ float bf2f(unsigned short u){
  return __uint_as_float(((unsigned int)u)<<16);
}
__device__ __forceinline__ unsigned int packtr(float lo, float hi){
  return __builtin_amdgcn_perm(__float_as_uint(hi), __float_as_uint(lo), 0x07060302u);
}
__device__ __forceinline__ f32x4 mfma16(s16x8 a, s16x8 b, f32x4 c){
  return __builtin_amdgcn_mfma_f32_16x16x32_bf16(a,b,c,0,0,0);
}
__device__ __forceinline__ f32x4 mfma16h(f16x8 a, f16x8 b, f32x4 c){
  return __builtin_amdgcn_mfma_f32_16x16x32_f16(a,b,c,0,0,0);
}

// ---------------- LayerNorm: f32 in, bf16 out --------------------------------
__global__ __launch_bounds__(256) void ln_kernel(const float* __restrict__ x,
    const float* __restrict__ g, const float* __restrict__ b,
    unsigned short* __restrict__ out){
  int row = blockIdx.x, tid = threadIdx.x;
  float val = x[(size_t)row*DDIM + tid];
  float s = val;
  #pragma unroll
  for (int o=32;o;o>>=1) s += __shfl_xor(s,o);
  __shared__ float sb[4], sb2[4];
  if ((tid&63)==0) sb[tid>>6]=s;
  __syncthreads();
  float mean = (sb[0]+sb[1]+sb[2]+sb[3]) * (1.0f/DDIM);
  float d = val-mean;
  float vs = d*d;
  #pragma unroll
  for (int o=32;o;o>>=1) vs += __shfl_xor(vs,o);
  if ((tid&63)==0) sb2[tid>>6]=vs;
  __syncthreads();
  float var = (sb2[0]+sb2[1]+sb2[2]+sb2[3]) * (1.0f/DDIM);
  out[(size_t)row*DDIM + tid] = f2bf(d*rsqrtf(var+EPSV)*g[tid]+b[tid]);
}

// ---------------- RoPE tables -------------------------------------------------
__global__ __launch_bounds__(256) void rope_table(float* __restrict__ sint, float* __restrict__ cost){
  int idx = blockIdx.x*256+threadIdx.x;   // 16384
  int i = idx >> 4, d = idx & 15;
  float freq = (float)i * powf(10000.0f, -(float)d/16.0f);
  sint[idx]=sinf(freq); cost[idx]=cosf(freq);
}

// ---------------- weight convert+transpose f32(K,NC) -> bf16 WT(NC,K) --------
__global__ __launch_bounds__(256) void wt_convert(const float* __restrict__ in,
    unsigned short* __restrict__ out, int K, int NC, int scaleCols, float scaleVal){
  __shared__ float tile[32][33];
  int tn0 = blockIdx.x*32;
  int tk0 = blockIdx.y*32;
  size_t loff = (size_t)blockIdx.z * K * NC;
  int t = threadIdx.x;
  int col = t & 31, rr = t >> 5;
  #pragma unroll
  for (int i=0;i<4;++i){
    int row = rr + i*8;
    tile[row][col] = in[loff + (size_t)(tk0+row)*NC + tn0+col];
  }
  __syncthreads();
  #pragma unroll
  for (int i=0;i<4;++i){
    int row = rr + i*8;
    int n = tn0 + row;
    float s = (n < scaleCols) ? scaleVal : 1.0f;
    out[loff + (size_t)n*K + tk0 + col] = f2bf(tile[col][row]*s);
  }
}

// ------------- rel precompute: per-node separable parts (fp16) + W2T (f16) ---
__global__ __launch_bounds__(256) void rel_pre(const float* __restrict__ coords,
    const float* __restrict__ vel, const float* __restrict__ W1,
    const float* __restrict__ b1, const float* __restrict__ W2,
    _Float16* __restrict__ A, _Float16* __restrict__ A2,
    _Float16* __restrict__ W2T, _Float16* __restrict__ Wd){
  if (blockIdx.x == 512){
    int t = threadIdx.x;
    #pragma unroll
    for (int e=0;e<4;++e){
      int idx = t*4+e;              // n*64 + k
      int n = idx>>6, kk = idx&63;
      W2T[idx] = (n<8) ? (_Float16)W2[kk*8+n] : (_Float16)0.f;
    }
    if (t < 64) Wd[t] = (_Float16)W1[128+t];
    return;
  }
  int gid = blockIdx.x*256 + threadIdx.x;  // 2048*64
  int node = gid >> 6, r = gid & 63;
  float c0 = coords[node*2], c1 = coords[node*2+1];
  float v0 = vel[node*2],    v1 = vel[node*2+1];
  float bv = c0*W1[r] + c1*W1[64+r] + v0*W1[192+r] + v1*W1[256+r];
  A[gid] = (_Float16)(b1[r] + bv);
  A2[gid] = (_Float16)bv;
}

// ------------- rel fused v9: 2 i's per block, j-half split, packed-f16 -------
__global__ __launch_bounds__(256, 4) void rel_fused9(const float* __restrict__ coords,
    const _Float16* __restrict__ A, const _Float16* __restrict__ A2,
    const _Float16* __restrict__ W2T, const _Float16* __restrict__ Wd,
    const float* __restrict__ b2, unsigned short* __restrict__ relbf){
  const int tid = threadIdx.x;
  const int bid = blockIdx.x;            // 2048
  const int b  = bid >> 10;
  const int ia = ((bid >> 1) & 511) * 2; // rows ia, ia+1
  const int jh = bid & 1;
  const int w = tid>>6, l = tid&63, lc = l&15, lg = l>>4;
  const int nodea = (b<<10) + ia;
  float2 cia = *(const float2*)(coords + (size_t)nodea*2);
  float2 cib = *(const float2*)(coords + (size_t)nodea*2 + 2);

  union u4h { uint4 u; h2 h[4]; };
  u4h aA, aB, bA, bB, wA, wB;
  aA.u = *(const uint4*)(A + (size_t)nodea*64 + lg*8);
  aB.u = *(const uint4*)(A + (size_t)nodea*64 + 32 + lg*8);
  bA.u = *(const uint4*)(A + (size_t)(nodea+1)*64 + lg*8);
  bB.u = *(const uint4*)(A + (size_t)(nodea+1)*64 + 32 + lg*8);
  wA.u = *(const uint4*)(Wd + lg*8);
  wB.u = *(const uint4*)(Wd + 32 + lg*8);

  const f16x8 bf0 = *(const f16x8*)&W2T[lc*64 + lg*8];
  const f16x8 bf1 = *(const f16x8*)&W2T[lc*64 + 32 + lg*8];
  const float b2v = (lc<8) ? b2[lc] : 0.f;

  const h2 c2 = {(_Float16)0.0099735570f, (_Float16)0.0099735570f};
  const h2 c1 = {(_Float16)-0.0664904395f, (_Float16)-0.0664904395f};
  const h2 c0 = {(_Float16)0.3989422804f, (_Float16)0.3989422804f};
  const h2 ch = {(_Float16)0.5f, (_Float16)0.5f};

  const int jbase = jh*512 + w*128;
  const float* cb = coords + (size_t)((b<<10) + jbase + lc)*2;
  const _Float16* ab = A2 + (size_t)((b<<10) + jbase + lc)*64 + lg*8;
  unsigned short* oba = relbf + ((size_t)b<<23) + ((size_t)ia<<10)
                      + ((size_t)(lc&7)<<20) + (unsigned)(jbase + lg*4);

  for (int st=0; st<8; ++st){
    u4h t0, t1;
    t0.u = *(const uint4*)(ab + st*1024);
    t1.u = *(const uint4*)(ab + st*1024 + 32);
    float2 cj = *(const float2*)(cb + st*32);
    // ---- i_a ----
    {
      float dx = cia.x-cj.x, dy = cia.y-cj.y;
      _Float16 dh = (_Float16)sqrtf(fmaf(dx,dx,dy*dy));
      h2 d2 = {dh, dh};
      union { h2 h[4]; f16x8 v; } g0, g1;
      #pragma unroll
      for (int e=0;e<4;++e){
        h2 t = (aA.h[e] - t0.h[e]) + d2*wA.h[e];
        h2 u = t*t;
        h2 p = u*c2 + c1;
        p = u*p + c0;
        g0.h[e] = u*p + ch*t;
        h2 s = (aB.h[e] - t1.h[e]) + d2*wB.h[e];
        h2 v = s*s;
        h2 q = v*c2 + c1;
        q = v*q + c0;
        g1.h[e] = v*q + ch*s;
      }
      f32x4 z; z[0]=0.f; z[1]=0.f; z[2]=0.f; z[3]=0.f;
      z = mfma16h(g0.v, bf0, z);
      z = mfma16h(g1.v, bf1, z);
      if (lc < 8){
        unsigned short* op = oba + st*16;
        *(unsigned int*)op     = pack_bf16(z[0]+b2v, z[1]+b2v);
        *(unsigned int*)(op+2) = pack_bf16(z[2]+b2v, z[3]+b2v);
      }
    }
    // ---- i_b (same t0/t1/cj loads) ----
    {
      float dx = cib.x-cj.x, dy = cib.y-cj.y;
      _Float16 dh = (_Float16)sqrtf(fmaf(dx,dx,dy*dy));
      h2 d2 = {dh, dh};
      union { h2 h[4]; f16x8 v; } g0, g1;
      #pragma unroll
      for (int e=0;e<4;++e){
        h2 t = (bA.h[e] - t0.h[e]) + d2*wA.h[e];
        h2 u = t*t;
        h2 p = u*c2 + c1;
        p = u*p + c0;
        g0.h[e] = u*p + ch*t;
        h2 s = (bB.h[e] - t1.h[e]) + d2*wB.h[e];
        h2 v = s*s;
        h2 q = v*c2 + c1;
        q = v*q + c0;
        g1.h[e] = v*q + ch*s;
      }
      f32x4 z; z[0]=0.f; z[1]=0.f; z[2]=0.f; z[3]=0.f;
      z = mfma16h(g0.v, bf0, z);
      z = mfma16h(g1.v, bf1, z);
      if (lc < 8){
        unsigned short* op = oba + 1024 + st*16;
        *(unsigned int*)op     = pack_bf16(z[0]+b2v, z[1]+b2v);
        *(unsigned int*)(op+2) = pack_bf16(z[2]+b2v, z[3]+b2v);
      }
    }
  }
}

// ------------- attn v4: swapped-operand MFMA flash, 32-j tiles ----------------
__global__ __launch_bounds__(256) void attn_mfma4(
    const unsigned short* __restrict__ q, const unsigned short* __restrict__ kk,
    const unsigned short* __restrict__ vv, const unsigned short* __restrict__ relbf,
    unsigned short* __restrict__ out){
  int bh = blockIdx.x >> 6;
  int i0 = (blockIdx.x & 63) * 16;
  int tid = threadIdx.x;
  int w = tid>>6, l = tid&63, lc = l&15, lg = l>>4;

  __shared__ __align__(16) float accL[4][2][16][17];
  __shared__ float mL[4][16];
  __shared__ float lL[4][16];

  const unsigned short* qb = q + ((size_t)(bh<<10) + i0)*32;
  const unsigned short* kb = kk + ((size_t)bh<<15);
  const unsigned short* vb = vv + ((size_t)bh<<15);
  const unsigned short* relrow = relbf + ((size_t)bh<<20) + ((size_t)(i0+lc)<<10);

  s16x8 qf = *(const s16x8*)(qb + (size_t)lc*32 + lg*8);

  float m = -1e30f, lsum = 0.f;
  f32x4 acc0, acc1;
  acc0[0]=0.f; acc0[1]=0.f; acc0[2]=0.f; acc0[3]=0.f;
  acc1 = acc0;

  for (int t=0; t<8; ++t){
    const int jt = w*256 + t*32;
    s16x8 kf0 = *(const s16x8*)(kb + (size_t)(jt+lc)*32 + lg*8);
    s16x8 kf1 = *(const s16x8*)(kb + (size_t)(jt+16+lc)*32 + lg*8);
    f32x4 z; z[0]=0.f; z[1]=0.f; z[2]=0.f; z[3]=0.f;
    f32x4 s0 = mfma16(kf0, qf, z);
    f32x4 s1 = mfma16(kf1, qf, z);
    ushort4 rl0 = *(const ushort4*)(relrow + jt + lg*4);
    ushort4 rl1 = *(const ushort4*)(relrow + jt + 16 + lg*4);
    s0[0] += bf2f(rl0.x); s0[1] += bf2f(rl0.y);
    s0[2] += bf2f(rl0.z); s0[3] += bf2f(rl0.w);
    s1[0] += bf2f(rl1.x); s1[1] += bf2f(rl1.y);
    s1[2] += bf2f(rl1.z); s1[3] += bf2f(rl1.w);
    float mx = fmaxf(fmaxf(fmaxf(s0[0],s0[1]), fmaxf(s0[2],s0[3])),
                     fmaxf(fmaxf(s1[0],s1[1]), fmaxf(s1[2],s1[3])));
    mx = fmaxf(mx, __shfl_xor(mx,16));
    mx = fmaxf(mx, __shfl_xor(mx,32));
    float mn = fmaxf(m, mx);
    float scale = __expf(m - mn);
    m = mn;
    float p0 = __expf(s0[0]-mn), p1 = __expf(s0[1]-mn);
    float p2 = __expf(s0[2]-mn), p3 = __expf(s0[3]-mn);
    float p4 = __expf(s1[0]-mn), p5 = __expf(s1[1]-mn);
    float p6 = __expf(s1[2]-mn), p7 = __expf(s1[3]-mn);
    lsum = lsum*scale + ((p0+p1)+(p2+p3)) + ((p4+p5)+(p6+p7));
    acc0[0]*=scale; acc0[1]*=scale; acc0[2]*=scale; acc0[3]*=scale;
    acc1[0]*=scale; acc1[1]*=scale; acc1[2]*=scale; acc1[3]*=scale;
#if __has_builtin(__builtin_amdgcn_mfma_f32_16x16x16bf16_1k)
    union { unsigned int u[2]; s16x4 v; } pu0, pu1;
    pu0.u[0] = packtr(p0,p1); pu0.u[1] = packtr(p2,p3);
    pu1.u[0] = packtr(p4,p5); pu1.u[1] = packtr(p6,p7);
    const unsigned short* vp0 = vb + (size_t)(jt + lg*4)*32 + lc;
    const unsigned short* vp1 = vb + (size_t)(jt + 16 + lg*4)*32 + lc;
    s16x4 va0, va1, vb0, vb1;
    va0[0]=(short)vp0[0];  va0[1]=(short)vp0[32];  va0[2]=(short)vp0[64];  va0[3]=(short)vp0[96];
    vb0[0]=(short)vp0[16]; vb0[1]=(short)vp0[48];  vb0[2]=(short)vp0[80];  vb0[3]=(short)vp0[112];
    va1[0]=(short)vp1[0];  va1[1]=(short)vp1[32];  va1[2]=(short)vp1[64];  va1[3]=(short)vp1[96];
    vb1[0]=(short)vp1[16]; vb1[1]=(short)vp1[48];  vb1[2]=(short)vp1[80];  vb1[3]=(short)vp1[112];
    acc0 = __builtin_amdgcn_mfma_f32_16x16x16bf16_1k(va0, pu0.v, acc0, 0,0,0);
    acc1 = __builtin_amdgcn_mfma_f32_16x16x16bf16_1k(vb0, pu0.v, acc1, 0,0,0);
    acc0 = __builtin_amdgcn_mfma_f32_16x16x16bf16_1k(va1, pu1.v, acc0, 0,0,0);
    acc1 = __builtin_amdgcn_mfma_f32_16x16x16bf16_1k(vb1, pu1.v, acc1, 0,0,0);
#else
    {
      unsigned int dw0 = packtr(p0,p1), dw1 = packtr(p2,p3);
      int src0 = lc + (((lg*2)&3)<<4);
      int src1 = lc + (((lg*2+1)&3)<<4);
      unsigned int u0 = __shfl(dw0, src0), u1 = __shfl(dw1, src0);
      unsigned int u2 = __shfl(dw0, src1), u3 = __shfl(dw1, src1);
      if (lg >= 2){ u0=0; u1=0; u2=0; u3=0; }
      union { unsigned int u[4]; s16x8 v; } pb;
      pb.u[0]=u0; pb.u[1]=u1; pb.u[2]=u2; pb.u[3]=u3;
      s16x8 vf0, vf1;
      #pragma unroll
      for (int e=0;e<8;++e){
        int j = (jt + lg*8 + e) & 1023;
        vf0[e] = (short)vb[(size_t)j*32 + lc];
        vf1[e] = (short)vb[(size_t)j*32 + 16 + lc];
      }
      acc0 = mfma16(vf0, pb.v, acc0);
      acc1 = mfma16(vf1, pb.v, acc1);
    }
    {
      unsigned int dw0 = packtr(p4,p5), dw1 = packtr(p6,p7);
      int src0 = lc + (((lg*2)&3)<<4);
      int src1 = lc + (((lg*2+1)&3)<<4);
      unsigned int u0 = __shfl(dw0, src0), u1 = __shfl(dw1, src0);
      unsigned int u2 = __shfl(dw0, src1), u3 = __shfl(dw1, src1);
      if (lg >= 2){ u0=0; u1=0; u2=0; u3=0; }
      union { unsigned int u[4]; s16x8 v; } pb;
      pb.u[0]=u0; pb.u[1]=u1; pb.u[2]=u2; pb.u[3]=u3;
      s16x8 vf0, vf1;
      #pragma unroll
      for (int e=0;e<8;++e){
        int j = (jt + 16 + lg*8 + e) & 1023;
        vf0[e] = (short)vb[(size_t)j*32 + lc];
        vf1[e] = (short)vb[(size_t)j*32 + 16 + lc];
      }
      acc0 = mfma16(vf0, pb.v, acc0);
      acc1 = mfma16(vf1, pb.v, acc1);
    }
#endif
  }
  lsum += __shfl_xor(lsum, 16);
  lsum += __shfl_xor(lsum, 32);
  if (lg == 0){ mL[w][lc] = m; lL[w][lc] = lsum; }
  #pragma unroll
  for (int r=0;r<4;++r){
    accL[w][0][lg*4+r][lc] = acc0[r];
    accL[w][1][lg*4+r][lc] = acc1[r];
  }
  __syncthreads();
  int ii = tid & 15, dd = tid >> 4;
  float m0 = mL[0][ii], m1 = mL[1][ii], m2 = mL[2][ii], m3 = mL[3][ii];
  float ms = fmaxf(fmaxf(m0,m1), fmaxf(m2,m3));
  float e0 = __expf(m0-ms), e1 = __expf(m1-ms), e2 = __expf(m2-ms), e3 = __expf(m3-ms);
  float lt = lL[0][ii]*e0 + lL[1][ii]*e1 + lL[2][ii]*e2 + lL[3][ii]*e3;
  float a0 = accL[0][0][dd][ii]*e0 + accL[1][0][dd][ii]*e1
           + accL[2][0][dd][ii]*e2 + accL[3][0][dd][ii]*e3;
  float a1 = accL[0][1][dd][ii]*e0 + accL[1][1][dd][ii]*e1
           + accL[2][1][dd][ii]*e2 + accL[3][1][dd][ii]*e3;
  float inv = 1.0f/lt;
  int b = bh>>3, hh = bh&7;
  size_t ob2 = ((size_t)((b<<10)+i0+ii))*256 + hh*32;
  out[ob2 + dd]      = f2bf(a0*inv);
  out[ob2 + 16 + dd] = f2bf(a1*inv);
}

// ------------- MFMA GEMM v2: BK=64, reg-staged prefetch (issue-early) --------
template<int K, int NC, int EPI, int BM, int BNt>
__global__ __launch_bounds__(256) void gemm_mfma(
    const unsigned short* __restrict__ Aa, const unsigned short* __restrict__ WT,
    const float* __restrict__ bias, const float* __restrict__ resid,
    void* __restrict__ outv){
  constexpr int WMm = BM/2, WNn = BNt/2;
  constexpr int FM = WMm/16, FN = WNn/16;
  constexpr int LP = 72;
  constexpr int NIT = K/64;
  constexpr int AL = (BM==64)?2:1;
  constexpr int BL = (BNt==64)?2:1;
  __shared__ __align__(16) unsigned short As[BM*LP];
  __shared__ __align__(16) unsigned short Bs[BNt*LP];
  const int tid = threadIdx.x;
  const int w = tid>>6, l = tid&63, lc = l&15, lg = l>>4;
  const int wm = w&1, wn = w>>1;
  const int n0 = blockIdx.x*BNt, m0 = blockIdx.y*BM;

  const int arow = (BM==64) ? (tid>>2) : (tid>>3);
  const int acg  = (BM==64) ? (tid&3)  : (tid&7);
  const int brow = (BNt==64) ? (tid>>2) : (tid>>3);
  const int bcg  = (BNt==64) ? (tid&3)  : (tid&7);
  const unsigned short* ag = Aa + (size_t)(m0+arow)*K + ((BM==64)? acg*16 : acg*8);
  const unsigned short* bg = WT + (size_t)(n0+brow)*K + ((BNt==64)? bcg*16 : bcg*8);

  f32x4 acc[FM][FN];
  #pragma unroll
  for (int a=0;a<FM;++a)
    #pragma unroll
    for (int c=0;c<FN;++c){ acc[a][c][0]=0.f; acc[a][c][1]=0.f; acc[a][c][2]=0.f; acc[a][c][3]=0.f; }

  s16x8 pa[AL], pb[BL];
  #pragma unroll
  for (int u=0;u<AL;++u) pa[u] = *(const s16x8*)(ag + u*8);
  #pragma unroll
  for (int u=0;u<BL;++u) pb[u] = *(const s16x8*)(bg + u*8);

  for (int it=0; it<NIT; ++it){
    __syncthreads();
    if constexpr (BM==64){
      *(s16x8*)&As[arow*LP + acg*16]     = pa[0];
      *(s16x8*)&As[arow*LP + acg*16 + 8] = pa[1];
    } else {
      *(s16x8*)&As[arow*LP + acg*8] = pa[0];
    }
    if constexpr (BNt==64){
      *(s16x8*)&Bs[brow*LP + bcg*16]     = pb[0];
      *(s16x8*)&Bs[brow*LP + bcg*16 + 8] = pb[1];
    } else {
      *(s16x8*)&Bs[brow*LP + bcg*8] = pb[0];
    }
    __syncthreads();
    if (it+1 < NIT){
      const unsigned short* agn = ag + (it+1)*64;
      const unsigned short* bgn = bg + (it+1)*64;
      #pragma unroll
      for (int u=0;u<AL;++u) pa[u] = *(const s16x8*)(agn + u*8);
      #pragma unroll
      for (int u=0;u<BL;++u) pb[u] = *(const s16x8*)(bgn + u*8);
    }
    #pragma unroll
    for (int kk=0; kk<2; ++kk){
      s16x8 af[FM], bv[FN];
      #pragma unroll
      for (int a=0;a<FM;++a) af[a] = *(const s16x8*)&As[(wm*WMm + a*16 + lc)*LP + kk*32 + lg*8];
      #pragma unroll
      for (int c=0;c<FN;++c) bv[c] = *(const s16x8*)&Bs[(wn*WNn + c*16 + lc)*LP + kk*32 + lg*8];
      #pragma unroll
      for (int a=0;a<FM;++a)
        #pragma unroll
        for (int c=0;c<FN;++c) acc[a][c] = mfma16(af[a], bv[c], acc[a][c]);
    }
  }
  #pragma unroll
  for (int a=0;a<FM;++a){
    #pragma unroll
    for (int c=0;c<FN;++c){
      int n = n0 + wn*WNn + c*16 + lc;
      float bvv = (EPI!=0) ? bias[n] : 0.f;
      #pragma unroll
      for (int r=0;r<4;++r){
        int m = m0 + wm*WMm + a*16 + lg*4 + r;
        float vv = acc[a][c][r];
        if constexpr (EPI==0){
          ((unsigned short*)outv)[(size_t)m*NC + n] = f2bf(vv);
        } else if constexpr (EPI==1){
          ((float*)outv)[(size_t)m*NC + n] = vv + bvv + resid[(size_t)m*NC + n];
        } else {
          ((unsigned short*)outv)[(size_t)m*NC + n] = f2bf(gelu_f(vv + bvv));
        }
      }
    }
  }
}

// ------------- qkv GEMM with fused RoPE epilogue (K=256, NC=768, 64x64) ------
// Writes q,k,v directly in (B,H,N,HD) bf16; pairs (d, d+16) live in the same
// lane (c=0/c=1), so RoPE is 4 VALU ops in-register on the f32 accumulators.
__global__ __launch_bounds__(256) void gemm_qkv(
    const unsigned short* __restrict__ Aa, const unsigned short* __restrict__ WT,
    const float* __restrict__ sint, const float* __restrict__ cost,
    unsigned short* __restrict__ qo, unsigned short* __restrict__ ko,
    unsigned short* __restrict__ vo){
  constexpr int K = 256, LP = 72, NIT = 4;
  __shared__ __align__(16) unsigned short As[64*LP];
  __shared__ __align__(16) unsigned short Bs[64*LP];
  const int tid = threadIdx.x;
  const int w = tid>>6, l = tid&63, lc = l&15, lg = l>>4;
  const int wm = w&1, wn = w>>1;
  const int n0 = blockIdx.x*64, m0 = blockIdx.y*64;

  const int arow = tid>>2, acg = tid&3;
  const unsigned short* ag = Aa + (size_t)(m0+arow)*K + acg*16;
  const unsigned short* bg = WT + (size_t)(n0+arow)*K + acg*16;

  f32x4 acc[2][2];
  #pragma unroll
  for (int a=0;a<2;++a)
    #pragma unroll
    for (int c=0;c<2;++c){ acc[a][c][0]=0.f; acc[a][c][1]=0.f; acc[a][c][2]=0.f; acc[a][c][3]=0.f; }

  s16x8 pa[2], pb[2];
  #pragma unroll
  for (int u=0;u<2;++u){ pa[u] = *(const s16x8*)(ag + u*8); pb[u] = *(const s16x8*)(bg + u*8); }

  for (int it=0; it<NIT; ++it){
    __syncthreads();
    *(s16x8*)&As[arow*LP + acg*16]     = pa[0];
    *(s16x8*)&As[arow*LP + acg*16 + 8] = pa[1];
    *(s16x8*)&Bs[arow*LP + acg*16]     = pb[0];
    *(s16x8*)&Bs[arow*LP + acg*16 + 8] = pb[1];
    __syncthreads();
    if (it+1 < NIT){
      const unsigned short* agn = ag + (it+1)*64;
      const unsigned short* bgn = bg + (it+1)*64;
      #pragma unroll
      for (int u=0;u<2;++u){ pa[u] = *(const s16x8*)(agn + u*8); pb[u] = *(const s16x8*)(bgn + u*8); }
    }
    #pragma unroll
    for (int kk=0; kk<2; ++kk){
      s16x8 af[2], bv[2];
      #pragma unroll
      for (int a=0;a<2;++a) af[a] = *(const s16x8*)&As[(wm*32 + a*16 + lc)*LP + kk*32 + lg*8];
      #pragma unroll
      for (int c=0;c<2;++c) bv[c] = *(const s16x8*)&Bs[(wn*32 + c*16 + lc)*LP + kk*32 + lg*8];
      #pragma unroll
      for (int a=0;a<2;++a)
        #pragma unroll
        for (int c=0;c<2;++c) acc[a][c] = mfma16(af[a], bv[c], acc[a][c]);
    }
  }
  // epilogue: section/head from the wave's 32-col band; RoPE for q/k
  const int nb = n0 + wn*32;
  const int sec = nb >> 8;                 // 0=q, 1=k, 2=v
  const int h = (nb >> 5) & 7;
  unsigned short* outp = (sec==0) ? qo : (sec==1) ? ko : vo;
  #pragma unroll
  for (int a=0;a<2;++a){
    #pragma unroll
    for (int r=0;r<4;++r){
      int m = m0 + wm*32 + a*16 + lg*4 + r;
      int b = m >> 10, i = m & 1023;
      size_t base = ((size_t)((b<<3)+h)*1024 + (size_t)i)*32;
      float v0 = acc[a][0][r], v1 = acc[a][1][r];
      if (sec == 2){
        outp[base + lc]      = f2bf(v0);
        outp[base + 16 + lc] = f2bf(v1);
      } else {
        float sv = sint[i*16+lc], cv = cost[i*16+lc];
        outp[base + lc]      = f2bf(v0*cv - v1*sv);
        outp[base + 16 + lc] = f2bf(v1*cv + v0*sv);
      }
    }
  }
}

extern "C" void kernel_launch(void* const* d_in, const int* in_sizes, int n_in,
                              void* d_out, int out_size, void* d_ws, size_t ws_size,
                              hipStream_t stream){
  const float* x_in  = (const float*)d_in[0];
  const float* coords= (const float*)d_in[1];
  const float* vel   = (const float*)d_in[2];
  const float* ln1_g = (const float*)d_in[3];
  const float* ln1_b = (const float*)d_in[4];
  const float* Wqkv  = (const float*)d_in[5];
  const float* relW1 = (const float*)d_in[6];
  const float* relb1 = (const float*)d_in[7];
  const float* relW2 = (const float*)d_in[8];
  const float* relb2 = (const float*)d_in[9];
  const float* Wout  = (const float*)d_in[10];
  const float* bout  = (const float*)d_in[11];
  const float* ln2_g = (const float*)d_in[12];
  const float* ln2_b = (const float*)d_in[13];
  const float* Wf1   = (const float*)d_in[14];
  const float* bf1   = (const float*)d_in[15];
  const float* Wf2   = (const float*)d_in[16];
  const float* bf2   = (const float*)d_in[17];

  float* x = (float*)d_out;
  unsigned short* us = (unsigned short*)d_ws;
  unsigned short* hbf   = us;                    // 524288
  unsigned short* qkvbf = hbf   + 524288;        // 1572864 (unused now)
  unsigned short* qbf   = qkvbf + 1572864;       // 524288
  unsigned short* kbf   = qbf   + 524288;        // 524288
  unsigned short* vbf   = kbf   + 524288;        // 524288
  unsigned short* attbf = vbf   + 524288;        // 524288
  unsigned short* midbf = attbf + 524288;        // 2097152
  unsigned short* relbf = midbf + 2097152;       // 16777216
  unsigned short* WqkvT = relbf + 16777216;      // 393216
  unsigned short* WoutT = WqkvT + 393216;        // 131072
  unsigned short* Wf1T  = WoutT + 131072;        // 524288
  unsigned short* Wf2T  = Wf1T  + 524288;        // 524288
  _Float16* W2Th = (_Float16*)(Wf2T + 524288);   // 1024
  _Float16* Wdh  = W2Th + 1024;                  // 64
  _Float16* Ah   = Wdh + 64;                     // 131072
  _Float16* A2h  = Ah + 131072;                  // 131072
  float* sint  = (float*)(A2h + 131072);         // 16384
  float* cost  = sint + 16384;                   // 16384

  rope_table<<<64,256,0,stream>>>(sint,cost);
  wt_convert<<<dim3(24,8,2),256,0,stream>>>(Wqkv, WqkvT, 256, 768, 256, SCALEV);
  wt_convert<<<dim3(8,8,2),256,0,stream>>>(Wout, WoutT, 256, 256, 0, 1.0f);
  wt_convert<<<dim3(32,8,2),256,0,stream>>>(Wf1, Wf1T, 256, 1024, 0, 1.0f);
  wt_convert<<<dim3(8,32,2),256,0,stream>>>(Wf2, Wf2T, 1024, 256, 0, 1.0f);

  for (int l=0;l<2;++l){
    const float* xr = (l==0) ? x_in : x;   // residual source; x first written by att-GEMM l=0
    ln_kernel<<<2048,256,0,stream>>>(xr, ln1_g+l*256, ln1_b+l*256, hbf);
    gemm_qkv<<<dim3(12,32),256,0,stream>>>(
        hbf, WqkvT + (size_t)l*196608, sint, cost, qbf, kbf, vbf);
    rel_pre<<<513,256,0,stream>>>(coords, vel, relW1+l*320, relb1+l*64,
                                  relW2+l*512, Ah, A2h, W2Th, Wdh);
    rel_fused9<<<2048,256,0,stream>>>(coords, Ah, A2h, W2Th, Wdh,
                                      relb2+l*8, relbf);
    attn_mfma4<<<1024,256,0,stream>>>(qbf, kbf, vbf, relbf, attbf);
    gemm_mfma<256,256,1,32,32><<<dim3(8,64),256,0,stream>>>(
        attbf, WoutT + (size_t)l*65536, bout+l*256, xr, x);
    ln_kernel<<<2048,256,0,stream>>>(x, ln2_g+l*256, ln2_b+l*256, hbf);
    gemm_mfma<256,1024,2,64,64><<<dim3(16,32),256,0,stream>>>(
        hbf, Wf1T + (size_t)l*262144, bf1+l*1024, nullptr, midbf);
    gemm_mfma<1024,256,1,32,32><<<dim3(8,64),256,0,stream>>>(
        midbf, Wf2T + (size_t)l*262144, bf2+l*256, x, x);
  }
}